// Round 1
// 403.993 us; speedup vs baseline: 1.0173x; 1.0173x over previous
//
#include <hip/hip_runtime.h>
#include <hip/hip_bf16.h>

typedef __hip_bfloat16 bf16;
typedef short bf16x8 __attribute__((ext_vector_type(8)));
typedef float f32x4 __attribute__((ext_vector_type(4)));

#define PTOT  65536   // b * h * w = 16 * 4096
#define NPOS  4096    // h * w
#define CIN   256
#define HID   512
#define HD    64

__device__ __forceinline__ float us2f(unsigned short u) {
    return __uint_as_float(((unsigned int)u) << 16);
}
__device__ __forceinline__ float ldf(const void* p, size_t i, bool bf) {
    return bf ? us2f(((const unsigned short*)p)[i]) : ((const float*)p)[i];
}
__device__ __forceinline__ unsigned short f2bs(float v) {
    __hip_bfloat16 h = __float2bfloat16(v);
    return *reinterpret_cast<unsigned short*>(&h);
}
// async global->LDS, 16 B per lane; lds dest must be wave-uniform base
__device__ __forceinline__ void gld16(const void* g, void* s) {
    __builtin_amdgcn_global_load_lds(
        (const __attribute__((address_space(1))) unsigned int*)g,
        (__attribute__((address_space(3))) unsigned int*)s, 16, 0, 0);
}

// ---------------------------------------------------------------- dtype detector
__global__ __launch_bounds__(256) void k_detect(const unsigned* __restrict__ x,
                                                int* __restrict__ flag) {
    int t = threadIdx.x;
    unsigned w = x[(size_t)t * 997];
    unsigned e7 = (w >> 8) & 0x7f;
    __shared__ int s[256];
    s[t] = (e7 >= 58 && e7 <= 66) ? 1 : 0;
    __syncthreads();
    for (int k = 128; k > 0; k >>= 1) { if (t < k) s[t] += s[t + k]; __syncthreads(); }
    if (t == 0) flag[0] = (s[0] >= 128) ? 1 : 0;
}

__global__ void k_relay(const int* __restrict__ src, int* __restrict__ dst) {
    dst[0] = src[0];
}

// ---------------------------------------------------------------- elementwise convert -> bf16
__global__ __launch_bounds__(256) void k_cvt(const void* __restrict__ src,
        unsigned short* __restrict__ dst, int n, const int* __restrict__ flag) {
    bool bf = flag[0] != 0;
    int i = blockIdx.x * 256 + threadIdx.x;
    if (i < n) dst[i] = f2bs(ldf(src, i, bf));
}

// ---------------------------------------------------------------- rmsnorm(x) -> xn bf16 [p][c] (c contiguous)
__global__ __launch_bounds__(256) void k_norm_xn(
        const void* __restrict__ x, const void* __restrict__ g,
        unsigned short* __restrict__ xn, const int* __restrict__ flag)
{
    bool bf = flag[0] != 0;
    __shared__ float xs[64][65];
    __shared__ float gS[256];
    __shared__ float sS[64];
    __shared__ float red[4][64];
    int t = threadIdx.x;
    int p0 = blockIdx.x * 64;
    int b = p0 >> 12;
    int posbase = p0 & 4095;
    gS[t] = ldf(g, t, bf);
    int pl = t & 63, cg = t >> 6;
    const size_t xbase = ((size_t)b * CIN) << 12;
    float ss = 0.f;
    for (int c = cg * 64; c < cg * 64 + 64; ++c) {
        float v = ldf(x, xbase + ((size_t)c << 12) + posbase + pl, bf);
        ss += v * v;
    }
    red[cg][pl] = ss;
    __syncthreads();
    if (t < 64) {
        float tot = red[0][t] + red[1][t] + red[2][t] + red[3][t];
        sS[t] = 16.0f / fmaxf(sqrtf(tot), 1e-12f);
    }
    for (int c0 = 0; c0 < 256; c0 += 64) {
        __syncthreads();
        #pragma unroll
        for (int r = 0; r < 16; ++r) {
            int c = c0 + r * 4 + cg;
            xs[r * 4 + cg][pl] = ldf(x, xbase + ((size_t)c << 12) + posbase + pl, bf);
        }
        __syncthreads();
        int pr = t >> 2, c4 = (t & 3) * 16;
        float sc = sS[pr];
        unsigned short tmp[16];
        #pragma unroll
        for (int j = 0; j < 16; ++j)
            tmp[j] = f2bs(xs[c4 + j][pr] * sc * gS[c0 + c4 + j]);
        unsigned short* dst = &xn[(size_t)(p0 + pr) * 256 + c0 + c4];
        *(uint4*)dst = ((uint4*)tmp)[0];
        *(uint4*)(dst + 8) = ((uint4*)tmp)[1];
    }
}

// ---------------------------------------------------------------- MFMA GEMM: C[m][n] = Am[m][k] · Bm[n][k]^T
// Am: [M][KTOT] bf16 rows k-contig; Bm: [N][KTOT] bf16 rows k-contig; C: [M][OSTRIDE] bf16
template<int KTOT, bool BIAS, int OSTRIDE>
__global__ __launch_bounds__(256) void k_mfma(
        const bf16* __restrict__ Am, const bf16* __restrict__ Bm,
        const void* __restrict__ bias, bf16* __restrict__ C,
        const int* __restrict__ flag)
{
    __shared__ __align__(16) unsigned short As[128 * 32];
    __shared__ __align__(16) unsigned short Bs[128 * 32];
    const int tid = threadIdx.x;
    const int wv = tid >> 6, lane = tid & 63;
    const int quad = lane >> 4, l16 = lane & 15;
    const int wm = wv >> 1, wn = wv & 1;
    const int m0 = blockIdx.y * 128, n0 = blockIdx.x * 128;
    f32x4 acc[4][4] = {};
    const bf16* gA = Am + (size_t)(m0 + (tid >> 2)) * KTOT + (tid & 3) * 8;
    const bf16* gB = Bm + (size_t)(n0 + (tid >> 2)) * KTOT + (tid & 3) * 8;
    unsigned short* lA = As + wv * 512;
    unsigned short* lB = Bs + wv * 512;
    for (int k0 = 0; k0 < KTOT; k0 += 32) {
        gld16(gA + k0, lA);
        gld16(gA + (size_t)64 * KTOT + k0, lA + 2048);
        gld16(gB + k0, lB);
        gld16(gB + (size_t)64 * KTOT + k0, lB + 2048);
        __syncthreads();
        bf16x8 bfr[4];
        #pragma unroll
        for (int j = 0; j < 4; ++j)
            bfr[j] = *(const bf16x8*)&Bs[(wn * 64 + j * 16 + l16) * 32 + quad * 8];
        #pragma unroll
        for (int i = 0; i < 4; ++i) {
            bf16x8 af = *(const bf16x8*)&As[(wm * 64 + i * 16 + l16) * 32 + quad * 8];
            #pragma unroll
            for (int j = 0; j < 4; ++j)
                acc[i][j] = __builtin_amdgcn_mfma_f32_16x16x32_bf16(af, bfr[j], acc[i][j], 0, 0, 0);
        }
        __syncthreads();
    }
    bool bf = BIAS ? (flag[0] != 0) : false;
    #pragma unroll
    for (int i = 0; i < 4; ++i) {
        int row = m0 + wm * 64 + i * 16 + quad * 4;
        #pragma unroll
        for (int r = 0; r < 4; ++r) {
            float bv = BIAS ? ldf(bias, row + r, bf) : 0.0f;
            #pragma unroll
            for (int j = 0; j < 4; ++j) {
                int col = n0 + wn * 64 + j * 16 + l16;
                C[(size_t)(row + r) * OSTRIDE + col] = __float2bfloat16(acc[i][j][r] + bv);
            }
        }
    }
}

// ---------------------------------------------------------------- fused Q GEMM + q-softmax + context apply
// GEMM1: Q[128 pos][128 ch (=2 heads)] = xn[pos][256] · wq[ch][256]^T
// epilogue: per-(pos,head) softmax over the 64 head channels (one wave's 64-col half),
//           LDS transpose, GEMM2 vs ct[e][d] -> oat_pe[pos][HID]
__global__ __launch_bounds__(256) void k_qapply(
        const bf16* __restrict__ xn, const bf16* __restrict__ wq,
        const unsigned short* __restrict__ ct_bf,
        unsigned short* __restrict__ oat_pe)
{
    // union: GEMM1 staging As/Bs (16K shorts) overlaps As2 (17408 shorts);
    // ctS (9216 shorts) is disjoint so it can stage during GEMM1.
    __shared__ __align__(16) unsigned short smem[128 * 136 + 2 * 64 * 72];
    unsigned short* As  = smem;              // [128][32]  GEMM1 staging
    unsigned short* Bs  = smem + 8192;       // [128][32]
    unsigned short* As2 = smem;              // [128][136] qsm (bank-safe: 2-way only)
    unsigned short* ctS = smem + 17408;      // [2][64][72]
    const int tid = threadIdx.x;
    const int wv = tid >> 6, lane = tid & 63;
    const int quad = lane >> 4, l16 = lane & 15;
    const int wm = wv >> 1, wn = wv & 1;
    const int n0 = blockIdx.x * 128;         // out-channel tile = heads {n0/64, n0/64+1}
    const int m0 = blockIdx.y * 128;         // position tile (within one batch: 4096%128==0)
    const int b = m0 >> 12;

    // stage ct for both heads (disjoint LDS region; overlaps GEMM1 latency)
    {
        int hh = tid >> 7, tt = tid & 127;
        int bh = (b << 3) + (n0 >> 6) + hh;
        int e = tt >> 1, d0 = (tt & 1) * 32;
        const unsigned short* src = ct_bf + (size_t)bh * 4096 + e * 64 + d0;
        unsigned short* dst = ctS + hh * 4608 + e * 72 + d0;
        *(uint4*)dst        = *(const uint4*)src;
        *(uint4*)(dst + 8)  = *(const uint4*)(src + 8);
        *(uint4*)(dst + 16) = *(const uint4*)(src + 16);
        *(uint4*)(dst + 24) = *(const uint4*)(src + 24);
    }

    f32x4 acc[4][4] = {};
    const bf16* gA = xn + (size_t)(m0 + (tid >> 2)) * CIN + (tid & 3) * 8;
    const bf16* gB = wq + (size_t)(n0 + (tid >> 2)) * CIN + (tid & 3) * 8;
    unsigned short* lA = As + wv * 512;
    unsigned short* lB = Bs + wv * 512;
    for (int k0 = 0; k0 < CIN; k0 += 32) {
        gld16(gA + k0, lA);
        gld16(gA + (size_t)64 * CIN + k0, lA + 2048);
        gld16(gB + k0, lB);
        gld16(gB + (size_t)64 * CIN + k0, lB + 2048);
        __syncthreads();
        bf16x8 bfr[4];
        #pragma unroll
        for (int j = 0; j < 4; ++j)
            bfr[j] = *(const bf16x8*)&Bs[(wn * 64 + j * 16 + l16) * 32 + quad * 8];
        #pragma unroll
        for (int i = 0; i < 4; ++i) {
            bf16x8 af = *(const bf16x8*)&As[(wm * 64 + i * 16 + l16) * 32 + quad * 8];
            #pragma unroll
            for (int j = 0; j < 4; ++j)
                acc[i][j] = __builtin_amdgcn_mfma_f32_16x16x32_bf16(af, bfr[j], acc[i][j], 0, 0, 0);
        }
        __syncthreads();
    }

    // in-register softmax over each wave's 64-col half (= head wn), rows wm*64..wm*64+63.
    // row values live in j (4 regs) x l16 (16 lanes, same quad group) -> shfl_xor<16 stays in group.
    #pragma unroll
    for (int i = 0; i < 4; ++i) {
        #pragma unroll
        for (int r = 0; r < 4; ++r) {
            float m = fmaxf(fmaxf(acc[i][0][r], acc[i][1][r]),
                            fmaxf(acc[i][2][r], acc[i][3][r]));
            #pragma unroll
            for (int s = 1; s < 16; s <<= 1)
                m = fmaxf(m, __shfl_xor(m, s));
            float ev[4];
            float sum = 0.f;
            #pragma unroll
            for (int j = 0; j < 4; ++j) { ev[j] = expf(acc[i][j][r] - m); sum += ev[j]; }
            #pragma unroll
            for (int s = 1; s < 16; s <<= 1)
                sum += __shfl_xor(sum, s);
            float inv = 0.125f / sum;   // softmax * HEAD_DIM^-0.5
            int row = wm * 64 + i * 16 + quad * 4 + r;
            #pragma unroll
            for (int j = 0; j < 4; ++j)
                As2[row * 136 + wn * 64 + j * 16 + l16] = f2bs(ev[j] * inv);
        }
    }
    __syncthreads();

    // GEMM2: out[p][e] = sum_d qsm[p][d] * ct[e][d]   (k = 64 -> 2 MFMA k-steps)
    f32x4 acc2[4][4] = {};
    #pragma unroll
    for (int kk = 0; kk < 2; ++kk) {
        bf16x8 bfr[4];
        #pragma unroll
        for (int j = 0; j < 4; ++j)
            bfr[j] = *(const bf16x8*)&ctS[wn * 4608 + (j * 16 + l16) * 72 + kk * 32 + quad * 8];
        #pragma unroll
        for (int i = 0; i < 4; ++i) {
            bf16x8 af = *(const bf16x8*)&As2[(wm * 64 + i * 16 + l16) * 136 + wn * 64 + kk * 32 + quad * 8];
            #pragma unroll
            for (int j = 0; j < 4; ++j)
                acc2[i][j] = __builtin_amdgcn_mfma_f32_16x16x32_bf16(af, bfr[j], acc2[i][j], 0, 0, 0);
        }
    }
    #pragma unroll
    for (int i = 0; i < 4; ++i) {
        #pragma unroll
        for (int r = 0; r < 4; ++r) {
            int prow = wm * 64 + i * 16 + quad * 4 + r;
            unsigned short* obase = oat_pe + (size_t)(m0 + prow) * HID + n0 + wn * 64;
            #pragma unroll
            for (int j = 0; j < 4; ++j)
                obase[j * 16 + l16] = f2bs(acc2[i][j][r]);
        }
    }
}

// ---------------------------------------------------------------- k row stats (max, 1/sumexp) over n=4100
__global__ __launch_bounds__(256) void k_kstats(
        const bf16* __restrict__ kv, const void* __restrict__ memkv,
        float* __restrict__ rowmax, float* __restrict__ rowinv,
        const int* __restrict__ flag)
{
    bool bf = flag[0] != 0;
    int r = blockIdx.x;                 // b*512 + h*64 + d
    int b = r >> 9, hd = r & 511;
    const unsigned short* krow = (const unsigned short*)kv + (size_t)hd * PTOT + b * NPOS;
    int t = threadIdx.x;
    float vals[16];
    float m = -1e30f;
    #pragma unroll
    for (int i = 0; i < 16; ++i) {
        vals[i] = us2f(krow[t + (i << 8)]);
        m = fmaxf(m, vals[i]);
    }
    float mv = (t < 4) ? ldf(memkv, hd * 4 + t, bf) : -1e30f;
    m = fmaxf(m, mv);
    __shared__ float red[256];
    red[t] = m; __syncthreads();
    for (int s = 128; s > 0; s >>= 1) {
        if (t < s) red[t] = fmaxf(red[t], red[t + s]);
        __syncthreads();
    }
    float M = red[0]; __syncthreads();
    float sum = 0.f;
    #pragma unroll
    for (int i = 0; i < 16; ++i) sum += expf(vals[i] - M);
    if (t < 4) sum += expf(mv - M);
    red[t] = sum; __syncthreads();
    for (int s = 128; s > 0; s >>= 1) {
        if (t < s) red[t] += red[t + s];
        __syncthreads();
    }
    if (t == 0) { rowmax[r] = M; rowinv[r] = 1.0f / red[0]; }
}

// ---------------------------------------------------------------- context via MFMA (validated R5)
__global__ __launch_bounds__(256) void k_context_mfma(
        const bf16* __restrict__ kv, const void* __restrict__ memkv,
        const float* __restrict__ rowmax, const float* __restrict__ rowinv,
        float* __restrict__ ctpart, const int* __restrict__ flag)
{
    bool bf = flag[0] != 0;
    int bh = blockIdx.x, chunk = blockIdx.y;
    int b = bh >> 3, h = bh & 7;
    __shared__ __align__(16) unsigned short As[4][64 * 32];
    __shared__ __align__(16) unsigned short Bs[4][64 * 32];
    __shared__ float rmS[64], riS[64];
    const int tid = threadIdx.x;
    if (tid < 64) {
        rmS[tid] = rowmax[(b << 9) + (h << 6) + tid];
        riS[tid] = rowinv[(b << 9) + (h << 6) + tid];
    }
    __syncthreads();
    const int wv = tid >> 6, lane = tid & 63;
    const int quad = lane >> 4, l16 = lane & 15;
    const int wm = wv >> 1, wn = wv & 1;
    const int krow = tid >> 2, kseg = tid & 3;
    const float rm = rmS[krow], ri = riS[krow];
    const unsigned short* kbase = (const unsigned short*)kv + (size_t)(h * HD) * PTOT + b * NPOS + chunk * 1024;
    const unsigned short* vbase = (const unsigned short*)kv + (size_t)(HID + h * HD) * PTOT + b * NPOS + chunk * 1024;
    f32x4 acc[2][2] = {};
    for (int s = 0; s < 8; ++s) {
        int nb = s * 128;
        #pragma unroll
        for (int kk = 0; kk < 4; ++kk) {
            uint4 u = *(const uint4*)(kbase + (size_t)krow * PTOT + nb + kk * 32 + kseg * 8);
            unsigned short out[8];
            const unsigned short* us = (const unsigned short*)&u;
            #pragma unroll
            for (int e = 0; e < 8; ++e)
                out[e] = f2bs(expf(us2f(us[e]) - rm) * ri);
            *(uint4*)&As[kk][krow * 32 + kseg * 8] = *(uint4*)out;
        }
        #pragma unroll
        for (int kk = 0; kk < 4; ++kk)
            gld16(vbase + (size_t)(wv * 16 + (lane >> 2)) * PTOT + nb + kk * 32 + (lane & 3) * 8,
                  &Bs[kk][wv * 512]);
        __syncthreads();
        #pragma unroll
        for (int kk = 0; kk < 4; ++kk) {
            bf16x8 bfr[2];
            #pragma unroll
            for (int j = 0; j < 2; ++j)
                bfr[j] = *(const bf16x8*)&Bs[kk][(wn * 32 + j * 16 + l16) * 32 + quad * 8];
            #pragma unroll
            for (int i = 0; i < 2; ++i) {
                bf16x8 af = *(const bf16x8*)&As[kk][(wm * 32 + i * 16 + l16) * 32 + quad * 8];
                #pragma unroll
                for (int j = 0; j < 2; ++j)
                    acc[i][j] = __builtin_amdgcn_mfma_f32_16x16x32_bf16(af, bfr[j], acc[i][j], 0, 0, 0);
            }
        }
        __syncthreads();
    }
    if (chunk == 0) {
        float mv[2][4];
        #pragma unroll
        for (int j = 0; j < 2; ++j) {
            int e = wn * 32 + j * 16 + l16;
            #pragma unroll
            for (int mm = 0; mm < 4; ++mm)
                mv[j][mm] = ldf(memkv, 2048 + ((h << 6) + e) * 4 + mm, bf);
        }
        #pragma unroll
        for (int i = 0; i < 2; ++i) {
            #pragma unroll
            for (int r = 0; r < 4; ++r) {
                int d = wm * 32 + i * 16 + quad * 4 + r;
                #pragma unroll
                for (int mm = 0; mm < 4; ++mm) {
                    float kw = expf(ldf(memkv, ((h << 6) + d) * 4 + mm, bf) - rmS[d]) * riS[d];
                    #pragma unroll
                    for (int j = 0; j < 2; ++j)
                        acc[i][j][r] = fmaf(kw, mv[j][mm], acc[i][j][r]);
                }
            }
        }
    }
    float* outp = ctpart + (size_t)(chunk * 128 + bh) * 4096;
    #pragma unroll
    for (int i = 0; i < 2; ++i) {
        #pragma unroll
        for (int r = 0; r < 4; ++r) {
            int d = wm * 32 + i * 16 + quad * 4 + r;
            #pragma unroll
            for (int j = 0; j < 2; ++j) {
                int e = wn * 32 + j * 16 + l16;
                outp[d * 64 + e] = acc[i][j][r];
            }
        }
    }
}

// ---------------------------------------------------------------- sum ctpart chunks -> ct_bf [bh][e][d] bf16 (transposed)
__global__ __launch_bounds__(256) void k_ctsum(
        const float* __restrict__ ctpart, unsigned short* __restrict__ ct_bf)
{
    int bh = blockIdx.x, t = threadIdx.x;
    int i0 = t * 16;
    int e = i0 >> 6, d0 = i0 & 63;
    unsigned short tmp[16];
    #pragma unroll
    for (int j = 0; j < 16; ++j) {
        int d = d0 + j;
        float s = 0.f;
        #pragma unroll
        for (int c = 0; c < 4; ++c)
            s += ctpart[(size_t)(c * 128 + bh) * 4096 + d * 64 + e];
        tmp[j] = f2bs(s);
    }
    unsigned short* dst = ct_bf + (size_t)bh * 4096 + i0;
    *(uint4*)dst = ((uint4*)tmp)[0];
    *(uint4*)(dst + 8) = ((uint4*)tmp)[1];
}

// ---------------------------------------------------------------- rmsnorm(pre bf16) -> d_out [b][c][pos]
template<bool BF>
__device__ __forceinline__ void rmsout_body(const unsigned short* pre, const void* g, void* out) {
    int p = blockIdx.x * 256 + threadIdx.x;
    int b = p >> 12, pos = p & 4095;
    float ss = 0.f;
    for (int c = 0; c < CIN; ++c) { float v = us2f(pre[(size_t)c * PTOT + p]); ss += v * v; }
    float scale = 16.0f / fmaxf(sqrtf(ss), 1e-12f);
    for (int c = 0; c < CIN; ++c) {
        float v = us2f(pre[(size_t)c * PTOT + p]) * scale * (BF ? us2f(((const unsigned short*)g)[c]) : ((const float*)g)[c]);
        size_t oi = ((size_t)(b * CIN + c) << 12) + pos;
        if (BF) ((unsigned short*)out)[oi] = f2bs(v);
        else    ((float*)out)[oi] = v;
    }
}
__global__ __launch_bounds__(256) void k_rmsnorm_out(
        const unsigned short* __restrict__ pre, const void* __restrict__ g,
        void* __restrict__ out, const int* __restrict__ flag)
{
    if (flag[0]) rmsout_body<true>(pre, g, out);
    else         rmsout_body<false>(pre, g, out);
}

extern "C" void kernel_launch(void* const* d_in, const int* in_sizes, int n_in,
                              void* d_out, int out_size, void* d_ws, size_t ws_size,
                              hipStream_t stream) {
    const void* x     = d_in[0];
    const void* g_in  = d_in[1];
    const void* w_qkv = d_in[2];
    const void* memkv = d_in[3];
    const void* w_out = d_in[4];
    const void* b_out = d_in[5];
    const void* g_out = d_in[6];

    // ---- workspace: peak 128 MiB ----
    char* ws = (char*)d_ws;
    bf16*           kv     = (bf16*)ws;                        // [1024][65536] bf16: K 0..511, V 512..1023
    unsigned short* oat_pe = (unsigned short*)(ws + 67108864); // [65536][512] bf16, over dead V
    unsigned short* pre    = (unsigned short*)ws;              // [256][65536] bf16, over dead K
    int*            flagB  = (int*)(ws + 50331648);            // dead zone at relay time

    // ---- scratch in d_out (fp32 out = 67 MB; layout validated R3-R5) ----
    char* ob = (char*)d_out;
    float*          ctpart = (float*)ob;                        // 8 MiB  [4][128][64][64]
    float*          rowmax = (float*)(ob + 8388608);            // 32 KiB
    float*          rowinv = (float*)(ob + 8421376);            // 32 KiB
    int*            flagA  = (int*)(ob + 8454144);              // 4 B
    unsigned short* wq_b   = (unsigned short*)(ob + 9437184);   // 768 KiB
    unsigned short* wout_b = (unsigned short*)(ob + 10485760);  // 256 KiB
    unsigned short* ct_bf  = (unsigned short*)(ob + 11010048);  // 1 MiB [128][64 e][64 d]
    unsigned short* xn     = (unsigned short*)(ob + 12582912);  // [65536][256] bf16 = 32 MiB

    k_detect<<<1, 256, 0, stream>>>((const unsigned*)x, flagA);

    k_cvt<<<1536, 256, 0, stream>>>(w_qkv, wq_b, 1536 * 256, flagA);
    k_cvt<<<512, 256, 0, stream>>>(w_out, wout_b, 256 * 512, flagA);

    k_norm_xn<<<1024, 256, 0, stream>>>(x, g_in, xn, flagA);

    // K/V = w_qkv rows 512..1535: C[1024][PTOT]
    dim3 gkv(512, 8);
    k_mfma<CIN, false, PTOT><<<gkv, 256, 0, stream>>>(
        (const bf16*)(wq_b + (size_t)512 * CIN), (const bf16*)xn, nullptr, kv, flagA);

    k_kstats<<<8192, 256, 0, stream>>>(kv, memkv, rowmax, rowinv, flagA);

    dim3 gctx(128, 4);
    k_context_mfma<<<gctx, 256, 0, stream>>>(kv, memkv, rowmax, rowinv, ctpart, flagA);

    k_ctsum<<<128, 256, 0, stream>>>(ctpart, ct_bf);

    // fused: Q GEMM (A = xn rows, B = w_qkv rows 0..511) + q-softmax + ct apply -> oat_pe[p][512]
    dim3 gqa(4, 512);
    k_qapply<<<gqa, 256, 0, stream>>>(
        (const bf16*)xn, (const bf16*)wq_b, ct_bf, oat_pe);

    // pre[256][PTOT] = w_out[256][512] · oat_pe[p][512]^T + b_out
    dim3 go(512, 2);
    k_mfma<HID, true, PTOT><<<go, 256, 0, stream>>>(
        (const bf16*)wout_b, (const bf16*)oat_pe, b_out, (bf16*)pre, flagA);

    k_relay<<<1, 1, 0, stream>>>(flagA, flagB);

    k_rmsnorm_out<<<256, 256, 0, stream>>>(pre, g_out, d_out, flagB);
}

// Round 2
// 393.696 us; speedup vs baseline: 1.0439x; 1.0262x over previous
//
#include <hip/hip_runtime.h>
#include <hip/hip_bf16.h>

typedef __hip_bfloat16 bf16;
typedef short bf16x8 __attribute__((ext_vector_type(8)));
typedef float f32x4 __attribute__((ext_vector_type(4)));

#define PTOT  65536   // b * h * w = 16 * 4096
#define NPOS  4096    // h * w
#define CIN   256
#define HID   512
#define HD    64

__device__ __forceinline__ float us2f(unsigned short u) {
    return __uint_as_float(((unsigned int)u) << 16);
}
__device__ __forceinline__ float ldf(const void* p, size_t i, bool bf) {
    return bf ? us2f(((const unsigned short*)p)[i]) : ((const float*)p)[i];
}
__device__ __forceinline__ unsigned short f2bs(float v) {
    __hip_bfloat16 h = __float2bfloat16(v);
    return *reinterpret_cast<unsigned short*>(&h);
}
// async global->LDS, 16 B per lane; lds dest must be wave-uniform base
__device__ __forceinline__ void gld16(const void* g, void* s) {
    __builtin_amdgcn_global_load_lds(
        (const __attribute__((address_space(1))) unsigned int*)g,
        (__attribute__((address_space(3))) unsigned int*)s, 16, 0, 0);
}

// ---------------------------------------------------------------- dtype detector
__global__ __launch_bounds__(256) void k_detect(const unsigned* __restrict__ x,
                                                int* __restrict__ flag) {
    int t = threadIdx.x;
    unsigned w = x[(size_t)t * 997];
    unsigned e7 = (w >> 8) & 0x7f;
    __shared__ int s[256];
    s[t] = (e7 >= 58 && e7 <= 66) ? 1 : 0;
    __syncthreads();
    for (int k = 128; k > 0; k >>= 1) { if (t < k) s[t] += s[t + k]; __syncthreads(); }
    if (t == 0) flag[0] = (s[0] >= 128) ? 1 : 0;
}

__global__ void k_relay(const int* __restrict__ src, int* __restrict__ dst) {
    dst[0] = src[0];
}

// ---------------------------------------------------------------- elementwise convert -> bf16
__global__ __launch_bounds__(256) void k_cvt(const void* __restrict__ src,
        unsigned short* __restrict__ dst, int n, const int* __restrict__ flag) {
    bool bf = flag[0] != 0;
    int i = blockIdx.x * 256 + threadIdx.x;
    if (i < n) dst[i] = f2bs(ldf(src, i, bf));
}

// ---------------------------------------------------------------- rmsnorm(x) -> xn bf16 [p][c] (c contiguous)
__global__ __launch_bounds__(256) void k_norm_xn(
        const void* __restrict__ x, const void* __restrict__ g,
        unsigned short* __restrict__ xn, const int* __restrict__ flag)
{
    bool bf = flag[0] != 0;
    __shared__ float xs[64][65];
    __shared__ float gS[256];
    __shared__ float sS[64];
    __shared__ float red[4][64];
    int t = threadIdx.x;
    int p0 = blockIdx.x * 64;
    int b = p0 >> 12;
    int posbase = p0 & 4095;
    gS[t] = ldf(g, t, bf);
    int pl = t & 63, cg = t >> 6;
    const size_t xbase = ((size_t)b * CIN) << 12;
    float ss = 0.f;
    for (int c = cg * 64; c < cg * 64 + 64; ++c) {
        float v = ldf(x, xbase + ((size_t)c << 12) + posbase + pl, bf);
        ss += v * v;
    }
    red[cg][pl] = ss;
    __syncthreads();
    if (t < 64) {
        float tot = red[0][t] + red[1][t] + red[2][t] + red[3][t];
        sS[t] = 16.0f / fmaxf(sqrtf(tot), 1e-12f);
    }
    for (int c0 = 0; c0 < 256; c0 += 64) {
        __syncthreads();
        #pragma unroll
        for (int r = 0; r < 16; ++r) {
            int c = c0 + r * 4 + cg;
            xs[r * 4 + cg][pl] = ldf(x, xbase + ((size_t)c << 12) + posbase + pl, bf);
        }
        __syncthreads();
        int pr = t >> 2, c4 = (t & 3) * 16;
        float sc = sS[pr];
        unsigned short tmp[16];
        #pragma unroll
        for (int j = 0; j < 16; ++j)
            tmp[j] = f2bs(xs[c4 + j][pr] * sc * gS[c0 + c4 + j]);
        unsigned short* dst = &xn[(size_t)(p0 + pr) * 256 + c0 + c4];
        *(uint4*)dst = ((uint4*)tmp)[0];
        *(uint4*)(dst + 8) = ((uint4*)tmp)[1];
    }
}

// ---------------------------------------------------------------- MFMA GEMM: C[m][n] = Am[m][k] · Bm[n][k]^T
// Am: [M][KTOT] bf16 rows k-contig; Bm: [N][KTOT] bf16 rows k-contig; C: [M][OSTRIDE] bf16
template<int KTOT, bool BIAS, int OSTRIDE>
__global__ __launch_bounds__(256) void k_mfma(
        const bf16* __restrict__ Am, const bf16* __restrict__ Bm,
        const void* __restrict__ bias, bf16* __restrict__ C,
        const int* __restrict__ flag)
{
    __shared__ __align__(16) unsigned short As[128 * 32];
    __shared__ __align__(16) unsigned short Bs[128 * 32];
    const int tid = threadIdx.x;
    const int wv = tid >> 6, lane = tid & 63;
    const int quad = lane >> 4, l16 = lane & 15;
    const int wm = wv >> 1, wn = wv & 1;
    const int m0 = blockIdx.y * 128, n0 = blockIdx.x * 128;
    f32x4 acc[4][4] = {};
    const bf16* gA = Am + (size_t)(m0 + (tid >> 2)) * KTOT + (tid & 3) * 8;
    const bf16* gB = Bm + (size_t)(n0 + (tid >> 2)) * KTOT + (tid & 3) * 8;
    unsigned short* lA = As + wv * 512;
    unsigned short* lB = Bs + wv * 512;
    for (int k0 = 0; k0 < KTOT; k0 += 32) {
        gld16(gA + k0, lA);
        gld16(gA + (size_t)64 * KTOT + k0, lA + 2048);
        gld16(gB + k0, lB);
        gld16(gB + (size_t)64 * KTOT + k0, lB + 2048);
        __syncthreads();
        bf16x8 bfr[4];
        #pragma unroll
        for (int j = 0; j < 4; ++j)
            bfr[j] = *(const bf16x8*)&Bs[(wn * 64 + j * 16 + l16) * 32 + quad * 8];
        #pragma unroll
        for (int i = 0; i < 4; ++i) {
            bf16x8 af = *(const bf16x8*)&As[(wm * 64 + i * 16 + l16) * 32 + quad * 8];
            #pragma unroll
            for (int j = 0; j < 4; ++j)
                acc[i][j] = __builtin_amdgcn_mfma_f32_16x16x32_bf16(af, bfr[j], acc[i][j], 0, 0, 0);
        }
        __syncthreads();
    }
    bool bf = BIAS ? (flag[0] != 0) : false;
    #pragma unroll
    for (int i = 0; i < 4; ++i) {
        int row = m0 + wm * 64 + i * 16 + quad * 4;
        #pragma unroll
        for (int r = 0; r < 4; ++r) {
            float bv = BIAS ? ldf(bias, row + r, bf) : 0.0f;
            #pragma unroll
            for (int j = 0; j < 4; ++j) {
                int col = n0 + wn * 64 + j * 16 + l16;
                C[(size_t)(row + r) * OSTRIDE + col] = __float2bfloat16(acc[i][j][r] + bv);
            }
        }
    }
}

// ---------------------------------------------------------------- KV GEMM, A-resident pipelined
// C[1024][PTOT] = Am[1024][256] · Bm[PTOT][256]^T
// One block per (m-tile 128 ch, chunk 2048 pos). A in LDS once + hoisted to regs;
// B streamed in 64-pos full-K slices, double-buffered, counted vmcnt (T4).
// LDS layout XOR-swizzled (T2): 16B slot ps = ks ^ (row&7); staged via pre-swizzled
// global source (gld16 dest stays linear), read with matching XOR.
__global__ __launch_bounds__(512) void k_kvgemm(
        const bf16* __restrict__ Am, const bf16* __restrict__ Bm,
        bf16* __restrict__ C)
{
    __shared__ __align__(16) unsigned short As[128 * 256];      // 64 KiB
    __shared__ __align__(16) unsigned short Bs[2][64 * 256];    // 64 KiB
    const int t = threadIdx.x;
    const int w = t >> 6, lane = t & 63;
    const int quad = lane >> 4, l16 = lane & 15;
    const int wm = w >> 1, wn = w & 1;               // 4 x 2 waves over 128m x 64n
    // swizzle: 8 m-blocks of a chunk -> same XCD (assumes round-robin blockIdx%8)
    const int p = blockIdx.x;
    const int xcd = p & 7, slot = p >> 3;
    const int chunk = xcd * 4 + (slot & 3);          // 0..31
    const int mt = slot >> 2;                        // 0..7
    const int m0 = mt * 128;
    const size_t cbase = (size_t)chunk * 2048;

    const int srow = t >> 5;                         // 0..15 per 16-row round
    const int sks  = (t & 31) ^ (srow & 7);          // pre-swizzled source slot

    // stage A (8 rounds) + B0 + B1 (4 rounds each)
    #pragma unroll
    for (int q = 0; q < 8; ++q)
        gld16(Am + (size_t)(m0 + q * 16 + srow) * 256 + sks * 8,
              (char*)As + q * 8192 + w * 1024);
    #pragma unroll
    for (int q = 0; q < 4; ++q)
        gld16(Bm + (cbase + q * 16 + srow) * 256 + sks * 8,
              (char*)Bs[0] + q * 8192 + w * 1024);
    #pragma unroll
    for (int q = 0; q < 4; ++q)
        gld16(Bm + (cbase + 64 + q * 16 + srow) * 256 + sks * 8,
              (char*)Bs[1] + q * 8192 + w * 1024);

    asm volatile("s_waitcnt vmcnt(8)" ::: "memory");  // A landed; B0,B1 in flight
    __builtin_amdgcn_s_barrier();
    asm volatile("" ::: "memory");

    // hoist A fragments to registers (As never rewritten)
    bf16x8 af[2][8];
    #pragma unroll
    for (int i = 0; i < 2; ++i) {
        int row = wm * 32 + i * 16 + l16;
        #pragma unroll
        for (int kk = 0; kk < 8; ++kk)
            af[i][kk] = *(const bf16x8*)((const char*)As + row * 512 +
                         (((kk * 4 + quad) ^ (row & 7)) << 4));
    }

    for (int s = 0; s < 32; ++s) {
        if (s > 0) {
            asm volatile("" ::: "memory");
            __builtin_amdgcn_s_barrier();            // prev compute done: buf free
            asm volatile("" ::: "memory");
            if (s + 1 < 32) {
                #pragma unroll
                for (int q = 0; q < 4; ++q)
                    gld16(Bm + (cbase + (size_t)(s + 1) * 64 + q * 16 + srow) * 256 + sks * 8,
                          (char*)Bs[(s + 1) & 1] + q * 8192 + w * 1024);
            }
        }
        // counted waits: need B(s) done; newer in flight = B(s+1) gld (4) + stores (16)
        if (s == 0)      asm volatile("s_waitcnt vmcnt(4)"  ::: "memory");
        else if (s < 31) asm volatile("s_waitcnt vmcnt(20)" ::: "memory");
        else             asm volatile("s_waitcnt vmcnt(16)" ::: "memory");
        __builtin_amdgcn_s_barrier();
        asm volatile("" ::: "memory");

        const unsigned short* Bbuf = Bs[s & 1];
        f32x4 acc[2][2] = {};
        #pragma unroll
        for (int kk = 0; kk < 8; ++kk) {
            bf16x8 bfr[2];
            #pragma unroll
            for (int j = 0; j < 2; ++j) {
                int row = wn * 32 + j * 16 + l16;
                bfr[j] = *(const bf16x8*)((const char*)Bbuf + row * 512 +
                          (((kk * 4 + quad) ^ (row & 7)) << 4));
            }
            #pragma unroll
            for (int i = 0; i < 2; ++i)
                #pragma unroll
                for (int j = 0; j < 2; ++j)
                    acc[i][j] = __builtin_amdgcn_mfma_f32_16x16x32_bf16(af[i][kk], bfr[j], acc[i][j], 0, 0, 0);
        }
        #pragma unroll
        for (int i = 0; i < 2; ++i) {
            #pragma unroll
            for (int r = 0; r < 4; ++r) {
                int row = m0 + wm * 32 + i * 16 + quad * 4 + r;
                size_t col = cbase + (size_t)s * 64 + wn * 32;
                #pragma unroll
                for (int j = 0; j < 2; ++j)
                    C[(size_t)row * PTOT + col + j * 16 + l16] = __float2bfloat16(acc[i][j][r]);
            }
        }
    }
}

// ---------------------------------------------------------------- fused Q GEMM + q-softmax + context apply
__global__ __launch_bounds__(256) void k_qapply(
        const bf16* __restrict__ xn, const bf16* __restrict__ wq,
        const unsigned short* __restrict__ ct_bf,
        unsigned short* __restrict__ oat_pe)
{
    __shared__ __align__(16) unsigned short smem[128 * 136 + 2 * 64 * 72];
    unsigned short* As  = smem;              // [128][32]  GEMM1 staging
    unsigned short* Bs  = smem + 8192;       // [128][32]
    unsigned short* As2 = smem;              // [128][136] qsm (bank-safe: 2-way only)
    unsigned short* ctS = smem + 17408;      // [2][64][72]
    const int tid = threadIdx.x;
    const int wv = tid >> 6, lane = tid & 63;
    const int quad = lane >> 4, l16 = lane & 15;
    const int wm = wv >> 1, wn = wv & 1;
    const int n0 = blockIdx.x * 128;
    const int m0 = blockIdx.y * 128;
    const int b = m0 >> 12;

    {
        int hh = tid >> 7, tt = tid & 127;
        int bh = (b << 3) + (n0 >> 6) + hh;
        int e = tt >> 1, d0 = (tt & 1) * 32;
        const unsigned short* src = ct_bf + (size_t)bh * 4096 + e * 64 + d0;
        unsigned short* dst = ctS + hh * 4608 + e * 72 + d0;
        *(uint4*)dst        = *(const uint4*)src;
        *(uint4*)(dst + 8)  = *(const uint4*)(src + 8);
        *(uint4*)(dst + 16) = *(const uint4*)(src + 16);
        *(uint4*)(dst + 24) = *(const uint4*)(src + 24);
    }

    f32x4 acc[4][4] = {};
    const bf16* gA = xn + (size_t)(m0 + (tid >> 2)) * CIN + (tid & 3) * 8;
    const bf16* gB = wq + (size_t)(n0 + (tid >> 2)) * CIN + (tid & 3) * 8;
    unsigned short* lA = As + wv * 512;
    unsigned short* lB = Bs + wv * 512;
    for (int k0 = 0; k0 < CIN; k0 += 32) {
        gld16(gA + k0, lA);
        gld16(gA + (size_t)64 * CIN + k0, lA + 2048);
        gld16(gB + k0, lB);
        gld16(gB + (size_t)64 * CIN + k0, lB + 2048);
        __syncthreads();
        bf16x8 bfr[4];
        #pragma unroll
        for (int j = 0; j < 4; ++j)
            bfr[j] = *(const bf16x8*)&Bs[(wn * 64 + j * 16 + l16) * 32 + quad * 8];
        #pragma unroll
        for (int i = 0; i < 4; ++i) {
            bf16x8 af = *(const bf16x8*)&As[(wm * 64 + i * 16 + l16) * 32 + quad * 8];
            #pragma unroll
            for (int j = 0; j < 4; ++j)
                acc[i][j] = __builtin_amdgcn_mfma_f32_16x16x32_bf16(af, bfr[j], acc[i][j], 0, 0, 0);
        }
        __syncthreads();
    }

    #pragma unroll
    for (int i = 0; i < 4; ++i) {
        #pragma unroll
        for (int r = 0; r < 4; ++r) {
            float m = fmaxf(fmaxf(acc[i][0][r], acc[i][1][r]),
                            fmaxf(acc[i][2][r], acc[i][3][r]));
            #pragma unroll
            for (int s = 1; s < 16; s <<= 1)
                m = fmaxf(m, __shfl_xor(m, s));
            float ev[4];
            float sum = 0.f;
            #pragma unroll
            for (int j = 0; j < 4; ++j) { ev[j] = expf(acc[i][j][r] - m); sum += ev[j]; }
            #pragma unroll
            for (int s = 1; s < 16; s <<= 1)
                sum += __shfl_xor(sum, s);
            float inv = 0.125f / sum;
            int row = wm * 64 + i * 16 + quad * 4 + r;
            #pragma unroll
            for (int j = 0; j < 4; ++j)
                As2[row * 136 + wn * 64 + j * 16 + l16] = f2bs(ev[j] * inv);
        }
    }
    __syncthreads();

    f32x4 acc2[4][4] = {};
    #pragma unroll
    for (int kk = 0; kk < 2; ++kk) {
        bf16x8 bfr[4];
        #pragma unroll
        for (int j = 0; j < 4; ++j)
            bfr[j] = *(const bf16x8*)&ctS[wn * 4608 + (j * 16 + l16) * 72 + kk * 32 + quad * 8];
        #pragma unroll
        for (int i = 0; i < 4; ++i) {
            bf16x8 af = *(const bf16x8*)&As2[(wm * 64 + i * 16 + l16) * 136 + wn * 64 + kk * 32 + quad * 8];
            #pragma unroll
            for (int j = 0; j < 4; ++j)
                acc2[i][j] = __builtin_amdgcn_mfma_f32_16x16x32_bf16(af, bfr[j], acc2[i][j], 0, 0, 0);
        }
    }
    #pragma unroll
    for (int i = 0; i < 4; ++i) {
        #pragma unroll
        for (int r = 0; r < 4; ++r) {
            int prow = wm * 64 + i * 16 + quad * 4 + r;
            unsigned short* obase = oat_pe + (size_t)(m0 + prow) * HID + n0 + wn * 64;
            #pragma unroll
            for (int j = 0; j < 4; ++j)
                obase[j * 16 + l16] = f2bs(acc2[i][j][r]);
        }
    }
}

// ---------------------------------------------------------------- k row stats (max, 1/sumexp) over n=4100
__global__ __launch_bounds__(256) void k_kstats(
        const bf16* __restrict__ kv, const void* __restrict__ memkv,
        float* __restrict__ rowmax, float* __restrict__ rowinv,
        const int* __restrict__ flag)
{
    bool bf = flag[0] != 0;
    int r = blockIdx.x;                 // b*512 + h*64 + d
    int b = r >> 9, hd = r & 511;
    const unsigned short* krow = (const unsigned short*)kv + (size_t)hd * PTOT + b * NPOS;
    int t = threadIdx.x;
    float vals[16];
    float m = -1e30f;
    #pragma unroll
    for (int i = 0; i < 16; ++i) {
        vals[i] = us2f(krow[t + (i << 8)]);
        m = fmaxf(m, vals[i]);
    }
    float mv = (t < 4) ? ldf(memkv, hd * 4 + t, bf) : -1e30f;
    m = fmaxf(m, mv);
    __shared__ float red[256];
    red[t] = m; __syncthreads();
    for (int s = 128; s > 0; s >>= 1) {
        if (t < s) red[t] = fmaxf(red[t], red[t + s]);
        __syncthreads();
    }
    float M = red[0]; __syncthreads();
    float sum = 0.f;
    #pragma unroll
    for (int i = 0; i < 16; ++i) sum += expf(vals[i] - M);
    if (t < 4) sum += expf(mv - M);
    red[t] = sum; __syncthreads();
    for (int s = 128; s > 0; s >>= 1) {
        if (t < s) red[t] += red[t + s];
        __syncthreads();
    }
    if (t == 0) { rowmax[r] = M; rowinv[r] = 1.0f / red[0]; }
}

// ---------------------------------------------------------------- context via MFMA (validated R5)
__global__ __launch_bounds__(256) void k_context_mfma(
        const bf16* __restrict__ kv, const void* __restrict__ memkv,
        const float* __restrict__ rowmax, const float* __restrict__ rowinv,
        float* __restrict__ ctpart, const int* __restrict__ flag)
{
    bool bf = flag[0] != 0;
    int bh = blockIdx.x, chunk = blockIdx.y;
    int b = bh >> 3, h = bh & 7;
    __shared__ __align__(16) unsigned short As[4][64 * 32];
    __shared__ __align__(16) unsigned short Bs[4][64 * 32];
    __shared__ float rmS[64], riS[64];
    const int tid = threadIdx.x;
    if (tid < 64) {
        rmS[tid] = rowmax[(b << 9) + (h << 6) + tid];
        riS[tid] = rowinv[(b << 9) + (h << 6) + tid];
    }
    __syncthreads();
    const int wv = tid >> 6, lane = tid & 63;
    const int quad = lane >> 4, l16 = lane & 15;
    const int wm = wv >> 1, wn = wv & 1;
    const int krow = tid >> 2, kseg = tid & 3;
    const float rm = rmS[krow], ri = riS[krow];
    const unsigned short* kbase = (const unsigned short*)kv + (size_t)(h * HD) * PTOT + b * NPOS + chunk * 1024;
    const unsigned short* vbase = (const unsigned short*)kv + (size_t)(HID + h * HD) * PTOT + b * NPOS + chunk * 1024;
    f32x4 acc[2][2] = {};
    for (int s = 0; s < 8; ++s) {
        int nb = s * 128;
        #pragma unroll
        for (int kk = 0; kk < 4; ++kk) {
            uint4 u = *(const uint4*)(kbase + (size_t)krow * PTOT + nb + kk * 32 + kseg * 8);
            unsigned short out[8];
            const unsigned short* us = (const unsigned short*)&u;
            #pragma unroll
            for (int e = 0; e < 8; ++e)
                out[e] = f2bs(expf(us2f(us[e]) - rm) * ri);
            *(uint4*)&As[kk][krow * 32 + kseg * 8] = *(uint4*)out;
        }
        #pragma unroll
        for (int kk = 0; kk < 4; ++kk)
            gld16(vbase + (size_t)(wv * 16 + (lane >> 2)) * PTOT + nb + kk * 32 + (lane & 3) * 8,
                  &Bs[kk][wv * 512]);
        __syncthreads();
        #pragma unroll
        for (int kk = 0; kk < 4; ++kk) {
            bf16x8 bfr[2];
            #pragma unroll
            for (int j = 0; j < 2; ++j)
                bfr[j] = *(const bf16x8*)&Bs[kk][(wn * 32 + j * 16 + l16) * 32 + quad * 8];
            #pragma unroll
            for (int i = 0; i < 2; ++i) {
                bf16x8 af = *(const bf16x8*)&As[kk][(wm * 32 + i * 16 + l16) * 32 + quad * 8];
                #pragma unroll
                for (int j = 0; j < 2; ++j)
                    acc[i][j] = __builtin_amdgcn_mfma_f32_16x16x32_bf16(af, bfr[j], acc[i][j], 0, 0, 0);
            }
        }
        __syncthreads();
    }
    if (chunk == 0) {
        float mv[2][4];
        #pragma unroll
        for (int j = 0; j < 2; ++j) {
            int e = wn * 32 + j * 16 + l16;
            #pragma unroll
            for (int mm = 0; mm < 4; ++mm)
                mv[j][mm] = ldf(memkv, 2048 + ((h << 6) + e) * 4 + mm, bf);
        }
        #pragma unroll
        for (int i = 0; i < 2; ++i) {
            #pragma unroll
            for (int r = 0; r < 4; ++r) {
                int d = wm * 32 + i * 16 + quad * 4 + r;
                #pragma unroll
                for (int mm = 0; mm < 4; ++mm) {
                    float kw = expf(ldf(memkv, ((h << 6) + d) * 4 + mm, bf) - rmS[d]) * riS[d];
                    #pragma unroll
                    for (int j = 0; j < 2; ++j)
                        acc[i][j][r] = fmaf(kw, mv[j][mm], acc[i][j][r]);
                }
            }
        }
    }
    float* outp = ctpart + (size_t)(chunk * 128 + bh) * 4096;
    #pragma unroll
    for (int i = 0; i < 2; ++i) {
        #pragma unroll
        for (int r = 0; r < 4; ++r) {
            int d = wm * 32 + i * 16 + quad * 4 + r;
            #pragma unroll
            for (int j = 0; j < 2; ++j) {
                int e = wn * 32 + j * 16 + l16;
                outp[d * 64 + e] = acc[i][j][r];
            }
        }
    }
}

// ---------------------------------------------------------------- sum ctpart chunks -> ct_bf [bh][e][d] bf16 (transposed)
__global__ __launch_bounds__(256) void k_ctsum(
        const float* __restrict__ ctpart, unsigned short* __restrict__ ct_bf)
{
    int bh = blockIdx.x, t = threadIdx.x;
    int i0 = t * 16;
    int e = i0 >> 6, d0 = i0 & 63;
    unsigned short tmp[16];
    #pragma unroll
    for (int j = 0; j < 16; ++j) {
        int d = d0 + j;
        float s = 0.f;
        #pragma unroll
        for (int c = 0; c < 4; ++c)
            s += ctpart[(size_t)(c * 128 + bh) * 4096 + d * 64 + e];
        tmp[j] = f2bs(s);
    }
    unsigned short* dst = ct_bf + (size_t)bh * 4096 + i0;
    *(uint4*)dst = ((uint4*)tmp)[0];
    *(uint4*)(dst + 8) = ((uint4*)tmp)[1];
}

// ---------------------------------------------------------------- rmsnorm(pre bf16) -> d_out [b][c][pos]
template<bool BF>
__device__ __forceinline__ void rmsout_body(const unsigned short* pre, const void* g, void* out) {
    int p = blockIdx.x * 256 + threadIdx.x;
    int b = p >> 12, pos = p & 4095;
    float ss = 0.f;
    for (int c = 0; c < CIN; ++c) { float v = us2f(pre[(size_t)c * PTOT + p]); ss += v * v; }
    float scale = 16.0f / fmaxf(sqrtf(ss), 1e-12f);
    for (int c = 0; c < CIN; ++c) {
        float v = us2f(pre[(size_t)c * PTOT + p]) * scale * (BF ? us2f(((const unsigned short*)g)[c]) : ((const float*)g)[c]);
        size_t oi = ((size_t)(b * CIN + c) << 12) + pos;
        if (BF) ((unsigned short*)out)[oi] = f2bs(v);
        else    ((float*)out)[oi] = v;
    }
}
__global__ __launch_bounds__(256) void k_rmsnorm_out(
        const unsigned short* __restrict__ pre, const void* __restrict__ g,
        void* __restrict__ out, const int* __restrict__ flag)
{
    if (flag[0]) rmsout_body<true>(pre, g, out);
    else         rmsout_body<false>(pre, g, out);
}

extern "C" void kernel_launch(void* const* d_in, const int* in_sizes, int n_in,
                              void* d_out, int out_size, void* d_ws, size_t ws_size,
                              hipStream_t stream) {
    const void* x     = d_in[0];
    const void* g_in  = d_in[1];
    const void* w_qkv = d_in[2];
    const void* memkv = d_in[3];
    const void* w_out = d_in[4];
    const void* b_out = d_in[5];
    const void* g_out = d_in[6];

    // ---- workspace: peak 128 MiB ----
    char* ws = (char*)d_ws;
    bf16*           kv     = (bf16*)ws;                        // [1024][65536] bf16: K 0..511, V 512..1023
    unsigned short* oat_pe = (unsigned short*)(ws + 67108864); // [65536][512] bf16, over dead V
    unsigned short* pre    = (unsigned short*)ws;              // [256][65536] bf16, over dead K
    int*            flagB  = (int*)(ws + 50331648);            // dead zone at relay time

    // ---- scratch in d_out (fp32 out = 67 MB; layout validated R3-R5) ----
    char* ob = (char*)d_out;
    float*          ctpart = (float*)ob;                        // 8 MiB  [4][128][64][64]
    float*          rowmax = (float*)(ob + 8388608);            // 32 KiB
    float*          rowinv = (float*)(ob + 8421376);            // 32 KiB
    int*            flagA  = (int*)(ob + 8454144);              // 4 B
    unsigned short* wq_b   = (unsigned short*)(ob + 9437184);   // 768 KiB
    unsigned short* wout_b = (unsigned short*)(ob + 10485760);  // 256 KiB
    unsigned short* ct_bf  = (unsigned short*)(ob + 11010048);  // 1 MiB [128][64 e][64 d]
    unsigned short* xn     = (unsigned short*)(ob + 12582912);  // [65536][256] bf16 = 32 MiB

    k_detect<<<1, 256, 0, stream>>>((const unsigned*)x, flagA);

    k_cvt<<<1536, 256, 0, stream>>>(w_qkv, wq_b, 1536 * 256, flagA);
    k_cvt<<<512, 256, 0, stream>>>(w_out, wout_b, 256 * 512, flagA);

    k_norm_xn<<<1024, 256, 0, stream>>>(x, g_in, xn, flagA);

    // K/V = w_qkv rows 512..1535: C[1024][PTOT], A-resident pipelined kernel
    k_kvgemm<<<256, 512, 0, stream>>>(
        (const bf16*)(wq_b + (size_t)512 * CIN), (const bf16*)xn, kv);

    k_kstats<<<8192, 256, 0, stream>>>(kv, memkv, rowmax, rowinv, flagA);

    dim3 gctx(128, 4);
    k_context_mfma<<<gctx, 256, 0, stream>>>(kv, memkv, rowmax, rowinv, ctpart, flagA);

    k_ctsum<<<128, 256, 0, stream>>>(ctpart, ct_bf);

    // fused: Q GEMM (A = xn rows, B = w_qkv rows 0..511) + q-softmax + ct apply -> oat_pe[p][512]
    dim3 gqa(4, 512);
    k_qapply<<<gqa, 256, 0, stream>>>(
        (const bf16*)xn, (const bf16*)wq_b, ct_bf, oat_pe);

    // pre[256][PTOT] = w_out[256][512] · oat_pe[p][512]^T + b_out
    dim3 go(512, 2);
    k_mfma<HID, true, PTOT><<<go, 256, 0, stream>>>(
        (const bf16*)wout_b, (const bf16*)oat_pe, b_out, (bf16*)pre, flagA);

    k_relay<<<1, 1, 0, stream>>>(flagA, flagB);

    k_rmsnorm_out<<<256, 256, 0, stream>>>(pre, g_out, d_out, flagB);
}

// Round 3
// 351.347 us; speedup vs baseline: 1.1698x; 1.1205x over previous
//
#include <hip/hip_runtime.h>
#include <hip/hip_bf16.h>

typedef __hip_bfloat16 bf16;
typedef short bf16x8 __attribute__((ext_vector_type(8)));
typedef float f32x4 __attribute__((ext_vector_type(4)));

#define PTOT  65536   // b * h * w = 16 * 4096
#define NPOS  4096    // h * w
#define CIN   256
#define HID   512
#define HD    64

__device__ __forceinline__ float us2f(unsigned short u) {
    return __uint_as_float(((unsigned int)u) << 16);
}
__device__ __forceinline__ float ldf(const void* p, size_t i, bool bf) {
    return bf ? us2f(((const unsigned short*)p)[i]) : ((const float*)p)[i];
}
__device__ __forceinline__ unsigned short f2bs(float v) {
    __hip_bfloat16 h = __float2bfloat16(v);
    return *reinterpret_cast<unsigned short*>(&h);
}
// async global->LDS, 16 B per lane; lds dest must be wave-uniform base
__device__ __forceinline__ void gld16(const void* g, void* s) {
    __builtin_amdgcn_global_load_lds(
        (const __attribute__((address_space(1))) unsigned int*)g,
        (__attribute__((address_space(3))) unsigned int*)s, 16, 0, 0);
}

// ---------------------------------------------------------------- dtype detector
__global__ __launch_bounds__(256) void k_detect(const unsigned* __restrict__ x,
                                                int* __restrict__ flag) {
    int t = threadIdx.x;
    unsigned w = x[(size_t)t * 997];
    unsigned e7 = (w >> 8) & 0x7f;
    __shared__ int s[256];
    s[t] = (e7 >= 58 && e7 <= 66) ? 1 : 0;
    __syncthreads();
    for (int k = 128; k > 0; k >>= 1) { if (t < k) s[t] += s[t + k]; __syncthreads(); }
    if (t == 0) flag[0] = (s[0] >= 128) ? 1 : 0;
}

__global__ void k_relay(const int* __restrict__ src, int* __restrict__ dst) {
    dst[0] = src[0];
}

// ---------------------------------------------------------------- elementwise convert -> bf16
__global__ __launch_bounds__(256) void k_cvt(const void* __restrict__ src,
        unsigned short* __restrict__ dst, int n, const int* __restrict__ flag) {
    bool bf = flag[0] != 0;
    int i = blockIdx.x * 256 + threadIdx.x;
    if (i < n) dst[i] = f2bs(ldf(src, i, bf));
}

// ---------------------------------------------------------------- rmsnorm(x) -> xn bf16 [p][c] (c contiguous)
// Single-pass, vectorized. Block = 64 positions. LDS transpose with chunked
// swizzle: addr(c,pos) = (c>>6)*4304 + (c&63)*67 + pos (floats).
// chunk stride 4304 % 32 == 16, row stride 67 % 32 == 3 -> both the staging
// writes and the transposed reads are exactly 2-way bank-aliased (free, m136).
template<bool BF>
__device__ __forceinline__ void norm_xn_body(const void* __restrict__ x,
        const void* __restrict__ g, unsigned short* __restrict__ xn,
        float* __restrict__ smem)
{
    float* xs   = smem;            // 4 * 4304 floats
    float* gS   = smem + 17216;    // 256
    float* red2 = smem + 17472;    // [16][64]
    float* sS   = smem + 18496;    // 64
    const int t = threadIdx.x;
    const int p0 = blockIdx.x * 64;
    const int b = p0 >> 12;
    const int posbase = p0 & 4095;
    gS[t] = ldf(g, t, BF);
    __syncthreads();
    const int pl4 = (t & 15) * 4;
    const int crow = t >> 4;                 // 0..15
    const size_t xbase = ((size_t)b * CIN) << 12;
    float ssq[4] = {0.f, 0.f, 0.f, 0.f};
    #pragma unroll
    for (int rr = 0; rr < 16; ++rr) {
        int c = rr * 16 + crow;
        float v[4];
        if (BF) {
            ushort4 u = *(const ushort4*)((const unsigned short*)x + xbase +
                                          ((size_t)c << 12) + posbase + pl4);
            v[0] = us2f(u.x); v[1] = us2f(u.y); v[2] = us2f(u.z); v[3] = us2f(u.w);
        } else {
            float4 f = *(const float4*)((const float*)x + xbase +
                                        ((size_t)c << 12) + posbase + pl4);
            v[0] = f.x; v[1] = f.y; v[2] = f.z; v[3] = f.w;
        }
        float gv = gS[c];
        float* row = xs + (c >> 6) * 4304 + (c & 63) * 67;
        #pragma unroll
        for (int e = 0; e < 4; ++e) {
            ssq[e] += v[e] * v[e];
            row[pl4 + e] = v[e] * gv;
        }
    }
    #pragma unroll
    for (int e = 0; e < 4; ++e) red2[crow * 64 + pl4 + e] = ssq[e];
    __syncthreads();
    if (t < 64) {
        float tot = 0.f;
        #pragma unroll
        for (int j = 0; j < 16; ++j) tot += red2[j * 64 + t];
        sS[t] = 16.0f / fmaxf(sqrtf(tot), 1e-12f);
    }
    __syncthreads();
    const int pr = t >> 2, c0 = (t & 3) * 64;
    const float sc = sS[pr];
    const float* base = xs + (t & 3) * 4304 + pr;
    unsigned short* dst = &xn[(size_t)(p0 + pr) * 256 + c0];
    #pragma unroll
    for (int q = 0; q < 4; ++q) {
        unsigned short tmp[16];
        #pragma unroll
        for (int j = 0; j < 16; ++j)
            tmp[j] = f2bs(base[(q * 16 + j) * 67] * sc);
        *(uint4*)(dst + q * 16)     = ((uint4*)tmp)[0];
        *(uint4*)(dst + q * 16 + 8) = ((uint4*)tmp)[1];
    }
}
__global__ __launch_bounds__(256) void k_norm_xn(
        const void* __restrict__ x, const void* __restrict__ g,
        unsigned short* __restrict__ xn, const int* __restrict__ flag)
{
    __shared__ float smem[18560];
    if (flag[0]) norm_xn_body<true>(x, g, xn, smem);
    else         norm_xn_body<false>(x, g, xn, smem);
}

// ---------------------------------------------------------------- MFMA GEMM: C[m][n] = Am[m][k] · Bm[n][k]^T
// Am: [M][KTOT] bf16 rows k-contig; Bm: [N][KTOT] bf16 rows k-contig; C: [M][OSTRIDE] bf16
template<int KTOT, bool BIAS, int OSTRIDE>
__global__ __launch_bounds__(256) void k_mfma(
        const bf16* __restrict__ Am, const bf16* __restrict__ Bm,
        const void* __restrict__ bias, bf16* __restrict__ C,
        const int* __restrict__ flag)
{
    __shared__ __align__(16) unsigned short As[128 * 32];
    __shared__ __align__(16) unsigned short Bs[128 * 32];
    const int tid = threadIdx.x;
    const int wv = tid >> 6, lane = tid & 63;
    const int quad = lane >> 4, l16 = lane & 15;
    const int wm = wv >> 1, wn = wv & 1;
    const int m0 = blockIdx.y * 128, n0 = blockIdx.x * 128;
    f32x4 acc[4][4] = {};
    const bf16* gA = Am + (size_t)(m0 + (tid >> 2)) * KTOT + (tid & 3) * 8;
    const bf16* gB = Bm + (size_t)(n0 + (tid >> 2)) * KTOT + (tid & 3) * 8;
    unsigned short* lA = As + wv * 512;
    unsigned short* lB = Bs + wv * 512;
    for (int k0 = 0; k0 < KTOT; k0 += 32) {
        gld16(gA + k0, lA);
        gld16(gA + (size_t)64 * KTOT + k0, lA + 2048);
        gld16(gB + k0, lB);
        gld16(gB + (size_t)64 * KTOT + k0, lB + 2048);
        __syncthreads();
        bf16x8 bfr[4];
        #pragma unroll
        for (int j = 0; j < 4; ++j)
            bfr[j] = *(const bf16x8*)&Bs[(wn * 64 + j * 16 + l16) * 32 + quad * 8];
        #pragma unroll
        for (int i = 0; i < 4; ++i) {
            bf16x8 af = *(const bf16x8*)&As[(wm * 64 + i * 16 + l16) * 32 + quad * 8];
            #pragma unroll
            for (int j = 0; j < 4; ++j)
                acc[i][j] = __builtin_amdgcn_mfma_f32_16x16x32_bf16(af, bfr[j], acc[i][j], 0, 0, 0);
        }
        __syncthreads();
    }
    bool bf = BIAS ? (flag[0] != 0) : false;
    #pragma unroll
    for (int i = 0; i < 4; ++i) {
        int row = m0 + wm * 64 + i * 16 + quad * 4;
        #pragma unroll
        for (int r = 0; r < 4; ++r) {
            float bv = BIAS ? ldf(bias, row + r, bf) : 0.0f;
            #pragma unroll
            for (int j = 0; j < 4; ++j) {
                int col = n0 + wn * 64 + j * 16 + l16;
                C[(size_t)(row + r) * OSTRIDE + col] = __float2bfloat16(acc[i][j][r] + bv);
            }
        }
    }
}

// ---------------------------------------------------------------- KV GEMM, A-resident pipelined
__global__ __launch_bounds__(512) void k_kvgemm(
        const bf16* __restrict__ Am, const bf16* __restrict__ Bm,
        bf16* __restrict__ C)
{
    __shared__ __align__(16) unsigned short As[128 * 256];      // 64 KiB
    __shared__ __align__(16) unsigned short Bs[2][64 * 256];    // 64 KiB
    const int t = threadIdx.x;
    const int w = t >> 6, lane = t & 63;
    const int quad = lane >> 4, l16 = lane & 15;
    const int wm = w >> 1, wn = w & 1;               // 4 x 2 waves over 128m x 64n
    const int p = blockIdx.x;
    const int xcd = p & 7, slot = p >> 3;
    const int chunk = xcd * 4 + (slot & 3);          // 0..31
    const int mt = slot >> 2;                        // 0..7
    const int m0 = mt * 128;
    const size_t cbase = (size_t)chunk * 2048;

    const int srow = t >> 5;                         // 0..15 per 16-row round
    const int sks  = (t & 31) ^ (srow & 7);          // pre-swizzled source slot

    #pragma unroll
    for (int q = 0; q < 8; ++q)
        gld16(Am + (size_t)(m0 + q * 16 + srow) * 256 + sks * 8,
              (char*)As + q * 8192 + w * 1024);
    #pragma unroll
    for (int q = 0; q < 4; ++q)
        gld16(Bm + (cbase + q * 16 + srow) * 256 + sks * 8,
              (char*)Bs[0] + q * 8192 + w * 1024);
    #pragma unroll
    for (int q = 0; q < 4; ++q)
        gld16(Bm + (cbase + 64 + q * 16 + srow) * 256 + sks * 8,
              (char*)Bs[1] + q * 8192 + w * 1024);

    asm volatile("s_waitcnt vmcnt(8)" ::: "memory");
    __builtin_amdgcn_s_barrier();
    asm volatile("" ::: "memory");

    bf16x8 af[2][8];
    #pragma unroll
    for (int i = 0; i < 2; ++i) {
        int row = wm * 32 + i * 16 + l16;
        #pragma unroll
        for (int kk = 0; kk < 8; ++kk)
            af[i][kk] = *(const bf16x8*)((const char*)As + row * 512 +
                         (((kk * 4 + quad) ^ (row & 7)) << 4));
    }

    for (int s = 0; s < 32; ++s) {
        if (s > 0) {
            asm volatile("" ::: "memory");
            __builtin_amdgcn_s_barrier();
            asm volatile("" ::: "memory");
            if (s + 1 < 32) {
                #pragma unroll
                for (int q = 0; q < 4; ++q)
                    gld16(Bm + (cbase + (size_t)(s + 1) * 64 + q * 16 + srow) * 256 + sks * 8,
                          (char*)Bs[(s + 1) & 1] + q * 8192 + w * 1024);
            }
        }
        if (s == 0)      asm volatile("s_waitcnt vmcnt(4)"  ::: "memory");
        else if (s < 31) asm volatile("s_waitcnt vmcnt(20)" ::: "memory");
        else             asm volatile("s_waitcnt vmcnt(16)" ::: "memory");
        __builtin_amdgcn_s_barrier();
        asm volatile("" ::: "memory");

        const unsigned short* Bbuf = Bs[s & 1];
        f32x4 acc[2][2] = {};
        #pragma unroll
        for (int kk = 0; kk < 8; ++kk) {
            bf16x8 bfr[2];
            #pragma unroll
            for (int j = 0; j < 2; ++j) {
                int row = wn * 32 + j * 16 + l16;
                bfr[j] = *(const bf16x8*)((const char*)Bbuf + row * 512 +
                          (((kk * 4 + quad) ^ (row & 7)) << 4));
            }
            #pragma unroll
            for (int i = 0; i < 2; ++i)
                #pragma unroll
                for (int j = 0; j < 2; ++j)
                    acc[i][j] = __builtin_amdgcn_mfma_f32_16x16x32_bf16(af[i][kk], bfr[j], acc[i][j], 0, 0, 0);
        }
        #pragma unroll
        for (int i = 0; i < 2; ++i) {
            #pragma unroll
            for (int r = 0; r < 4; ++r) {
                int row = m0 + wm * 32 + i * 16 + quad * 4 + r;
                size_t col = cbase + (size_t)s * 64 + wn * 32;
                #pragma unroll
                for (int j = 0; j < 2; ++j)
                    C[(size_t)row * PTOT + col + j * 16 + l16] = __float2bfloat16(acc[i][j][r]);
            }
        }
    }
}

// ---------------------------------------------------------------- fused Q GEMM + q-softmax + context apply
__global__ __launch_bounds__(256) void k_qapply(
        const bf16* __restrict__ xn, const bf16* __restrict__ wq,
        const unsigned short* __restrict__ ct_bf,
        unsigned short* __restrict__ oat_pe)
{
    __shared__ __align__(16) unsigned short smem[128 * 136 + 2 * 64 * 72];
    unsigned short* As  = smem;              // [128][32]  GEMM1 staging
    unsigned short* Bs  = smem + 8192;       // [128][32]
    unsigned short* As2 = smem;              // [128][136] qsm (bank-safe: 2-way only)
    unsigned short* ctS = smem + 17408;      // [2][64][72]
    const int tid = threadIdx.x;
    const int wv = tid >> 6, lane = tid & 63;
    const int quad = lane >> 4, l16 = lane & 15;
    const int wm = wv >> 1, wn = wv & 1;
    const int n0 = blockIdx.x * 128;
    const int m0 = blockIdx.y * 128;
    const int b = m0 >> 12;

    {
        int hh = tid >> 7, tt = tid & 127;
        int bh = (b << 3) + (n0 >> 6) + hh;
        int e = tt >> 1, d0 = (tt & 1) * 32;
        const unsigned short* src = ct_bf + (size_t)bh * 4096 + e * 64 + d0;
        unsigned short* dst = ctS + hh * 4608 + e * 72 + d0;
        *(uint4*)dst        = *(const uint4*)src;
        *(uint4*)(dst + 8)  = *(const uint4*)(src + 8);
        *(uint4*)(dst + 16) = *(const uint4*)(src + 16);
        *(uint4*)(dst + 24) = *(const uint4*)(src + 24);
    }

    f32x4 acc[4][4] = {};
    const bf16* gA = xn + (size_t)(m0 + (tid >> 2)) * CIN + (tid & 3) * 8;
    const bf16* gB = wq + (size_t)(n0 + (tid >> 2)) * CIN + (tid & 3) * 8;
    unsigned short* lA = As + wv * 512;
    unsigned short* lB = Bs + wv * 512;
    for (int k0 = 0; k0 < CIN; k0 += 32) {
        gld16(gA + k0, lA);
        gld16(gA + (size_t)64 * CIN + k0, lA + 2048);
        gld16(gB + k0, lB);
        gld16(gB + (size_t)64 * CIN + k0, lB + 2048);
        __syncthreads();
        bf16x8 bfr[4];
        #pragma unroll
        for (int j = 0; j < 4; ++j)
            bfr[j] = *(const bf16x8*)&Bs[(wn * 64 + j * 16 + l16) * 32 + quad * 8];
        #pragma unroll
        for (int i = 0; i < 4; ++i) {
            bf16x8 af = *(const bf16x8*)&As[(wm * 64 + i * 16 + l16) * 32 + quad * 8];
            #pragma unroll
            for (int j = 0; j < 4; ++j)
                acc[i][j] = __builtin_amdgcn_mfma_f32_16x16x32_bf16(af, bfr[j], acc[i][j], 0, 0, 0);
        }
        __syncthreads();
    }

    #pragma unroll
    for (int i = 0; i < 4; ++i) {
        #pragma unroll
        for (int r = 0; r < 4; ++r) {
            float m = fmaxf(fmaxf(acc[i][0][r], acc[i][1][r]),
                            fmaxf(acc[i][2][r], acc[i][3][r]));
            #pragma unroll
            for (int s = 1; s < 16; s <<= 1)
                m = fmaxf(m, __shfl_xor(m, s));
            float ev[4];
            float sum = 0.f;
            #pragma unroll
            for (int j = 0; j < 4; ++j) { ev[j] = expf(acc[i][j][r] - m); sum += ev[j]; }
            #pragma unroll
            for (int s = 1; s < 16; s <<= 1)
                sum += __shfl_xor(sum, s);
            float inv = 0.125f / sum;
            int row = wm * 64 + i * 16 + quad * 4 + r;
            #pragma unroll
            for (int j = 0; j < 4; ++j)
                As2[row * 136 + wn * 64 + j * 16 + l16] = f2bs(ev[j] * inv);
        }
    }
    __syncthreads();

    f32x4 acc2[4][4] = {};
    #pragma unroll
    for (int kk = 0; kk < 2; ++kk) {
        bf16x8 bfr[4];
        #pragma unroll
        for (int j = 0; j < 4; ++j)
            bfr[j] = *(const bf16x8*)&ctS[wn * 4608 + (j * 16 + l16) * 72 + kk * 32 + quad * 8];
        #pragma unroll
        for (int i = 0; i < 4; ++i) {
            bf16x8 af = *(const bf16x8*)&As2[(wm * 64 + i * 16 + l16) * 136 + wn * 64 + kk * 32 + quad * 8];
            #pragma unroll
            for (int j = 0; j < 4; ++j)
                acc2[i][j] = __builtin_amdgcn_mfma_f32_16x16x32_bf16(af, bfr[j], acc2[i][j], 0, 0, 0);
        }
    }
    #pragma unroll
    for (int i = 0; i < 4; ++i) {
        #pragma unroll
        for (int r = 0; r < 4; ++r) {
            int prow = wm * 64 + i * 16 + quad * 4 + r;
            unsigned short* obase = oat_pe + (size_t)(m0 + prow) * HID + n0 + wn * 64;
            #pragma unroll
            for (int j = 0; j < 4; ++j)
                obase[j * 16 + l16] = f2bs(acc2[i][j][r]);
        }
    }
}

// ---------------------------------------------------------------- k row stats (max, 1/sumexp) over n=4100
__global__ __launch_bounds__(256) void k_kstats(
        const bf16* __restrict__ kv, const void* __restrict__ memkv,
        float* __restrict__ rowmax, float* __restrict__ rowinv,
        const int* __restrict__ flag)
{
    bool bf = flag[0] != 0;
    int r = blockIdx.x;                 // b*512 + h*64 + d
    int b = r >> 9, hd = r & 511;
    const unsigned short* krow = (const unsigned short*)kv + (size_t)hd * PTOT + b * NPOS;
    int t = threadIdx.x;
    float vals[16];
    float m = -1e30f;
    #pragma unroll
    for (int i = 0; i < 16; ++i) {
        vals[i] = us2f(krow[t + (i << 8)]);
        m = fmaxf(m, vals[i]);
    }
    float mv = (t < 4) ? ldf(memkv, hd * 4 + t, bf) : -1e30f;
    m = fmaxf(m, mv);
    __shared__ float red[256];
    red[t] = m; __syncthreads();
    for (int s = 128; s > 0; s >>= 1) {
        if (t < s) red[t] = fmaxf(red[t], red[t + s]);
        __syncthreads();
    }
    float M = red[0]; __syncthreads();
    float sum = 0.f;
    #pragma unroll
    for (int i = 0; i < 16; ++i) sum += expf(vals[i] - M);
    if (t < 4) sum += expf(mv - M);
    red[t] = sum; __syncthreads();
    for (int s = 128; s > 0; s >>= 1) {
        if (t < s) red[t] += red[t + s];
        __syncthreads();
    }
    if (t == 0) { rowmax[r] = M; rowinv[r] = 1.0f / red[0]; }
}

// ---------------------------------------------------------------- context via MFMA (validated R5)
__global__ __launch_bounds__(256) void k_context_mfma(
        const bf16* __restrict__ kv, const void* __restrict__ memkv,
        const float* __restrict__ rowmax, const float* __restrict__ rowinv,
        float* __restrict__ ctpart, const int* __restrict__ flag)
{
    bool bf = flag[0] != 0;
    int bh = blockIdx.x, chunk = blockIdx.y;
    int b = bh >> 3, h = bh & 7;
    __shared__ __align__(16) unsigned short As[4][64 * 32];
    __shared__ __align__(16) unsigned short Bs[4][64 * 32];
    __shared__ float rmS[64], riS[64];
    const int tid = threadIdx.x;
    if (tid < 64) {
        rmS[tid] = rowmax[(b << 9) + (h << 6) + tid];
        riS[tid] = rowinv[(b << 9) + (h << 6) + tid];
    }
    __syncthreads();
    const int wv = tid >> 6, lane = tid & 63;
    const int quad = lane >> 4, l16 = lane & 15;
    const int wm = wv >> 1, wn = wv & 1;
    const int krow = tid >> 2, kseg = tid & 3;
    const float rm = rmS[krow], ri = riS[krow];
    const unsigned short* kbase = (const unsigned short*)kv + (size_t)(h * HD) * PTOT + b * NPOS + chunk * 1024;
    const unsigned short* vbase = (const unsigned short*)kv + (size_t)(HID + h * HD) * PTOT + b * NPOS + chunk * 1024;
    f32x4 acc[2][2] = {};
    for (int s = 0; s < 8; ++s) {
        int nb = s * 128;
        #pragma unroll
        for (int kk = 0; kk < 4; ++kk) {
            uint4 u = *(const uint4*)(kbase + (size_t)krow * PTOT + nb + kk * 32 + kseg * 8);
            unsigned short out[8];
            const unsigned short* us = (const unsigned short*)&u;
            #pragma unroll
            for (int e = 0; e < 8; ++e)
                out[e] = f2bs(expf(us2f(us[e]) - rm) * ri);
            *(uint4*)&As[kk][krow * 32 + kseg * 8] = *(uint4*)out;
        }
        #pragma unroll
        for (int kk = 0; kk < 4; ++kk)
            gld16(vbase + (size_t)(wv * 16 + (lane >> 2)) * PTOT + nb + kk * 32 + (lane & 3) * 8,
                  &Bs[kk][wv * 512]);
        __syncthreads();
        #pragma unroll
        for (int kk = 0; kk < 4; ++kk) {
            bf16x8 bfr[2];
            #pragma unroll
            for (int j = 0; j < 2; ++j)
                bfr[j] = *(const bf16x8*)&Bs[kk][(wn * 32 + j * 16 + l16) * 32 + quad * 8];
            #pragma unroll
            for (int i = 0; i < 2; ++i) {
                bf16x8 af = *(const bf16x8*)&As[kk][(wm * 32 + i * 16 + l16) * 32 + quad * 8];
                #pragma unroll
                for (int j = 0; j < 2; ++j)
                    acc[i][j] = __builtin_amdgcn_mfma_f32_16x16x32_bf16(af, bfr[j], acc[i][j], 0, 0, 0);
            }
        }
        __syncthreads();
    }
    if (chunk == 0) {
        float mv[2][4];
        #pragma unroll
        for (int j = 0; j < 2; ++j) {
            int e = wn * 32 + j * 16 + l16;
            #pragma unroll
            for (int mm = 0; mm < 4; ++mm)
                mv[j][mm] = ldf(memkv, 2048 + ((h << 6) + e) * 4 + mm, bf);
        }
        #pragma unroll
        for (int i = 0; i < 2; ++i) {
            #pragma unroll
            for (int r = 0; r < 4; ++r) {
                int d = wm * 32 + i * 16 + quad * 4 + r;
                #pragma unroll
                for (int mm = 0; mm < 4; ++mm) {
                    float kw = expf(ldf(memkv, ((h << 6) + d) * 4 + mm, bf) - rmS[d]) * riS[d];
                    #pragma unroll
                    for (int j = 0; j < 2; ++j)
                        acc[i][j][r] = fmaf(kw, mv[j][mm], acc[i][j][r]);
                }
            }
        }
    }
    float* outp = ctpart + (size_t)(chunk * 128 + bh) * 4096;
    #pragma unroll
    for (int i = 0; i < 2; ++i) {
        #pragma unroll
        for (int r = 0; r < 4; ++r) {
            int d = wm * 32 + i * 16 + quad * 4 + r;
            #pragma unroll
            for (int j = 0; j < 2; ++j) {
                int e = wn * 32 + j * 16 + l16;
                outp[d * 64 + e] = acc[i][j][r];
            }
        }
    }
}

// ---------------------------------------------------------------- sum ctpart chunks -> ct_bf [bh][e][d] bf16 (transposed)
__global__ __launch_bounds__(256) void k_ctsum(
        const float* __restrict__ ctpart, unsigned short* __restrict__ ct_bf)
{
    int bh = blockIdx.x, t = threadIdx.x;
    int i0 = t * 16;
    int e = i0 >> 6, d0 = i0 & 63;
    unsigned short tmp[16];
    #pragma unroll
    for (int j = 0; j < 16; ++j) {
        int d = d0 + j;
        float s = 0.f;
        #pragma unroll
        for (int c = 0; c < 4; ++c)
            s += ctpart[(size_t)(c * 128 + bh) * 4096 + d * 64 + e];
        tmp[j] = f2bs(s);
    }
    unsigned short* dst = ct_bf + (size_t)bh * 4096 + i0;
    *(uint4*)dst = ((uint4*)tmp)[0];
    *(uint4*)(dst + 8) = ((uint4*)tmp)[1];
}

// ---------------------------------------------------------------- rmsnorm(pre bf16) -> d_out [b][c][pos]
// Vectorized single-sweep: block = 64 positions, ushort4 loads cached in regs,
// cross-channel LDS reduce, float4/ushort4 stores. No transpose needed
// (pre and out share [c][pos] layout).
template<bool BF>
__device__ __forceinline__ void rmsout_body(const unsigned short* __restrict__ pre,
        const void* __restrict__ g, void* __restrict__ out, float* __restrict__ smem)
{
    float* gS   = smem;          // 256
    float* red2 = smem + 256;    // [16][64]
    float* sS   = smem + 1280;   // 64
    const int t = threadIdx.x;
    const int p0 = blockIdx.x * 64;
    const int b = p0 >> 12;
    const int posbase = p0 & 4095;
    gS[t] = ldf(g, t, BF);
    const int pl4 = (t & 15) * 4;
    const int crow = t >> 4;                 // 0..15
    const unsigned short* pbase = pre + p0 + pl4;
    ushort4 u[16];
    float ssq[4] = {0.f, 0.f, 0.f, 0.f};
    #pragma unroll
    for (int rr = 0; rr < 16; ++rr) {
        int c = rr * 16 + crow;
        u[rr] = *(const ushort4*)(pbase + (size_t)c * PTOT);
        float v0 = us2f(u[rr].x), v1 = us2f(u[rr].y), v2 = us2f(u[rr].z), v3 = us2f(u[rr].w);
        ssq[0] += v0 * v0; ssq[1] += v1 * v1; ssq[2] += v2 * v2; ssq[3] += v3 * v3;
    }
    #pragma unroll
    for (int e = 0; e < 4; ++e) red2[crow * 64 + pl4 + e] = ssq[e];
    __syncthreads();
    if (t < 64) {
        float tot = 0.f;
        #pragma unroll
        for (int j = 0; j < 16; ++j) tot += red2[j * 64 + t];
        sS[t] = 16.0f / fmaxf(sqrtf(tot), 1e-12f);
    }
    __syncthreads();
    const float s0 = sS[pl4], s1 = sS[pl4 + 1], s2 = sS[pl4 + 2], s3 = sS[pl4 + 3];
    #pragma unroll
    for (int rr = 0; rr < 16; ++rr) {
        int c = rr * 16 + crow;
        float gv = gS[c];
        float v0 = us2f(u[rr].x) * s0 * gv;
        float v1 = us2f(u[rr].y) * s1 * gv;
        float v2 = us2f(u[rr].z) * s2 * gv;
        float v3 = us2f(u[rr].w) * s3 * gv;
        size_t oi = ((size_t)(b * CIN + c) << 12) + posbase + pl4;
        if (BF) {
            ushort4 o;
            o.x = f2bs(v0); o.y = f2bs(v1); o.z = f2bs(v2); o.w = f2bs(v3);
            *(ushort4*)((unsigned short*)out + oi) = o;
        } else {
            float4 o; o.x = v0; o.y = v1; o.z = v2; o.w = v3;
            *(float4*)((float*)out + oi) = o;
        }
    }
}
__global__ __launch_bounds__(256) void k_rmsnorm_out(
        const unsigned short* __restrict__ pre, const void* __restrict__ g,
        void* __restrict__ out, const int* __restrict__ flag)
{
    __shared__ float smem[1344];
    if (flag[0]) rmsout_body<true>(pre, g, out, smem);
    else         rmsout_body<false>(pre, g, out, smem);
}

extern "C" void kernel_launch(void* const* d_in, const int* in_sizes, int n_in,
                              void* d_out, int out_size, void* d_ws, size_t ws_size,
                              hipStream_t stream) {
    const void* x     = d_in[0];
    const void* g_in  = d_in[1];
    const void* w_qkv = d_in[2];
    const void* memkv = d_in[3];
    const void* w_out = d_in[4];
    const void* b_out = d_in[5];
    const void* g_out = d_in[6];

    // ---- workspace: peak 128 MiB ----
    char* ws = (char*)d_ws;
    bf16*           kv     = (bf16*)ws;                        // [1024][65536] bf16: K 0..511, V 512..1023
    unsigned short* oat_pe = (unsigned short*)(ws + 67108864); // [65536][512] bf16, over dead V
    unsigned short* pre    = (unsigned short*)ws;              // [256][65536] bf16, over dead K
    int*            flagB  = (int*)(ws + 50331648);            // dead zone at relay time

    // ---- scratch in d_out (fp32 out = 67 MB; layout validated R3-R5) ----
    char* ob = (char*)d_out;
    float*          ctpart = (float*)ob;                        // 8 MiB  [4][128][64][64]
    float*          rowmax = (float*)(ob + 8388608);            // 32 KiB
    float*          rowinv = (float*)(ob + 8421376);            // 32 KiB
    int*            flagA  = (int*)(ob + 8454144);              // 4 B
    unsigned short* wq_b   = (unsigned short*)(ob + 9437184);   // 768 KiB
    unsigned short* wout_b = (unsigned short*)(ob + 10485760);  // 256 KiB
    unsigned short* ct_bf  = (unsigned short*)(ob + 11010048);  // 1 MiB [128][64 e][64 d]
    unsigned short* xn     = (unsigned short*)(ob + 12582912);  // [65536][256] bf16 = 32 MiB

    k_detect<<<1, 256, 0, stream>>>((const unsigned*)x, flagA);

    k_cvt<<<1536, 256, 0, stream>>>(w_qkv, wq_b, 1536 * 256, flagA);
    k_cvt<<<512, 256, 0, stream>>>(w_out, wout_b, 256 * 512, flagA);

    k_norm_xn<<<1024, 256, 0, stream>>>(x, g_in, xn, flagA);

    // K/V = w_qkv rows 512..1535: C[1024][PTOT], A-resident pipelined kernel
    k_kvgemm<<<256, 512, 0, stream>>>(
        (const bf16*)(wq_b + (size_t)512 * CIN), (const bf16*)xn, kv);

    k_kstats<<<8192, 256, 0, stream>>>(kv, memkv, rowmax, rowinv, flagA);

    dim3 gctx(128, 4);
    k_context_mfma<<<gctx, 256, 0, stream>>>(kv, memkv, rowmax, rowinv, ctpart, flagA);

    k_ctsum<<<128, 256, 0, stream>>>(ctpart, ct_bf);

    // fused: Q GEMM (A = xn rows, B = w_qkv rows 0..511) + q-softmax + ct apply -> oat_pe[p][512]
    dim3 gqa(4, 512);
    k_qapply<<<gqa, 256, 0, stream>>>(
        (const bf16*)xn, (const bf16*)wq_b, ct_bf, oat_pe);

    // pre[256][PTOT] = w_out[256][512] · oat_pe[p][512]^T + b_out
    dim3 go(512, 2);
    k_mfma<HID, true, PTOT><<<go, 256, 0, stream>>>(
        (const bf16*)wout_b, (const bf16*)oat_pe, b_out, (bf16*)pre, flagA);

    k_relay<<<1, 1, 0, stream>>>(flagA, flagB);

    k_rmsnorm_out<<<1024, 256, 0, stream>>>(pre, g_out, d_out, flagB);
}

// Round 4
// 350.029 us; speedup vs baseline: 1.1742x; 1.0038x over previous
//
#include <hip/hip_runtime.h>
#include <hip/hip_bf16.h>

typedef __hip_bfloat16 bf16;
typedef short bf16x8 __attribute__((ext_vector_type(8)));
typedef float f32x4 __attribute__((ext_vector_type(4)));

#define PTOT  65536   // b * h * w = 16 * 4096
#define NPOS  4096    // h * w
#define CIN   256
#define HID   512
#define HD    64

__device__ __forceinline__ float us2f(unsigned short u) {
    return __uint_as_float(((unsigned int)u) << 16);
}
__device__ __forceinline__ float ldf(const void* p, size_t i, bool bf) {
    return bf ? us2f(((const unsigned short*)p)[i]) : ((const float*)p)[i];
}
__device__ __forceinline__ unsigned short f2bs(float v) {
    __hip_bfloat16 h = __float2bfloat16(v);
    return *reinterpret_cast<unsigned short*>(&h);
}
// async global->LDS, 16 B per lane; lds dest must be wave-uniform base
__device__ __forceinline__ void gld16(const void* g, void* s) {
    __builtin_amdgcn_global_load_lds(
        (const __attribute__((address_space(1))) unsigned int*)g,
        (__attribute__((address_space(3))) unsigned int*)s, 16, 0, 0);
}

// ---------------------------------------------------------------- dtype detector
__global__ __launch_bounds__(256) void k_detect(const unsigned* __restrict__ x,
                                                int* __restrict__ flag) {
    int t = threadIdx.x;
    unsigned w = x[(size_t)t * 997];
    unsigned e7 = (w >> 8) & 0x7f;
    __shared__ int s[256];
    s[t] = (e7 >= 58 && e7 <= 66) ? 1 : 0;
    __syncthreads();
    for (int k = 128; k > 0; k >>= 1) { if (t < k) s[t] += s[t + k]; __syncthreads(); }
    if (t == 0) flag[0] = (s[0] >= 128) ? 1 : 0;
}

__global__ void k_relay(const int* __restrict__ src, int* __restrict__ dst) {
    dst[0] = src[0];
}

// ---------------------------------------------------------------- elementwise convert -> bf16
__global__ __launch_bounds__(256) void k_cvt(const void* __restrict__ src,
        unsigned short* __restrict__ dst, int n, const int* __restrict__ flag) {
    bool bf = flag[0] != 0;
    int i = blockIdx.x * 256 + threadIdx.x;
    if (i < n) dst[i] = f2bs(ldf(src, i, bf));
}

// ---------------------------------------------------------------- rmsnorm(x) -> xn bf16 [p][c] (c contiguous)
template<bool BF>
__device__ __forceinline__ void norm_xn_body(const void* __restrict__ x,
        const void* __restrict__ g, unsigned short* __restrict__ xn,
        float* __restrict__ smem)
{
    float* xs   = smem;            // 4 * 4304 floats
    float* gS   = smem + 17216;    // 256
    float* red2 = smem + 17472;    // [16][64]
    float* sS   = smem + 18496;    // 64
    const int t = threadIdx.x;
    const int p0 = blockIdx.x * 64;
    const int b = p0 >> 12;
    const int posbase = p0 & 4095;
    gS[t] = ldf(g, t, BF);
    __syncthreads();
    const int pl4 = (t & 15) * 4;
    const int crow = t >> 4;                 // 0..15
    const size_t xbase = ((size_t)b * CIN) << 12;
    float ssq[4] = {0.f, 0.f, 0.f, 0.f};
    #pragma unroll
    for (int rr = 0; rr < 16; ++rr) {
        int c = rr * 16 + crow;
        float v[4];
        if (BF) {
            ushort4 u = *(const ushort4*)((const unsigned short*)x + xbase +
                                          ((size_t)c << 12) + posbase + pl4);
            v[0] = us2f(u.x); v[1] = us2f(u.y); v[2] = us2f(u.z); v[3] = us2f(u.w);
        } else {
            float4 f = *(const float4*)((const float*)x + xbase +
                                        ((size_t)c << 12) + posbase + pl4);
            v[0] = f.x; v[1] = f.y; v[2] = f.z; v[3] = f.w;
        }
        float gv = gS[c];
        float* row = xs + (c >> 6) * 4304 + (c & 63) * 67;
        #pragma unroll
        for (int e = 0; e < 4; ++e) {
            ssq[e] += v[e] * v[e];
            row[pl4 + e] = v[e] * gv;
        }
    }
    #pragma unroll
    for (int e = 0; e < 4; ++e) red2[crow * 64 + pl4 + e] = ssq[e];
    __syncthreads();
    if (t < 64) {
        float tot = 0.f;
        #pragma unroll
        for (int j = 0; j < 16; ++j) tot += red2[j * 64 + t];
        sS[t] = 16.0f / fmaxf(sqrtf(tot), 1e-12f);
    }
    __syncthreads();
    const int pr = t >> 2, c0 = (t & 3) * 64;
    const float sc = sS[pr];
    const float* base = xs + (t & 3) * 4304 + pr;
    unsigned short* dst = &xn[(size_t)(p0 + pr) * 256 + c0];
    #pragma unroll
    for (int q = 0; q < 4; ++q) {
        unsigned short tmp[16];
        #pragma unroll
        for (int j = 0; j < 16; ++j)
            tmp[j] = f2bs(base[(q * 16 + j) * 67] * sc);
        *(uint4*)(dst + q * 16)     = ((uint4*)tmp)[0];
        *(uint4*)(dst + q * 16 + 8) = ((uint4*)tmp)[1];
    }
}
__global__ __launch_bounds__(256) void k_norm_xn(
        const void* __restrict__ x, const void* __restrict__ g,
        unsigned short* __restrict__ xn, const int* __restrict__ flag)
{
    __shared__ float smem[18560];
    if (flag[0]) norm_xn_body<true>(x, g, xn, smem);
    else         norm_xn_body<false>(x, g, xn, smem);
}

// ---------------------------------------------------------------- MFMA GEMM: C[m][n] = Am[m][k] · Bm[n][k]^T
template<int KTOT, bool BIAS, int OSTRIDE>
__global__ __launch_bounds__(256) void k_mfma(
        const bf16* __restrict__ Am, const bf16* __restrict__ Bm,
        const void* __restrict__ bias, bf16* __restrict__ C,
        const int* __restrict__ flag)
{
    __shared__ __align__(16) unsigned short As[128 * 32];
    __shared__ __align__(16) unsigned short Bs[128 * 32];
    const int tid = threadIdx.x;
    const int wv = tid >> 6, lane = tid & 63;
    const int quad = lane >> 4, l16 = lane & 15;
    const int wm = wv >> 1, wn = wv & 1;
    const int m0 = blockIdx.y * 128, n0 = blockIdx.x * 128;
    f32x4 acc[4][4] = {};
    const bf16* gA = Am + (size_t)(m0 + (tid >> 2)) * KTOT + (tid & 3) * 8;
    const bf16* gB = Bm + (size_t)(n0 + (tid >> 2)) * KTOT + (tid & 3) * 8;
    unsigned short* lA = As + wv * 512;
    unsigned short* lB = Bs + wv * 512;
    for (int k0 = 0; k0 < KTOT; k0 += 32) {
        gld16(gA + k0, lA);
        gld16(gA + (size_t)64 * KTOT + k0, lA + 2048);
        gld16(gB + k0, lB);
        gld16(gB + (size_t)64 * KTOT + k0, lB + 2048);
        __syncthreads();
        bf16x8 bfr[4];
        #pragma unroll
        for (int j = 0; j < 4; ++j)
            bfr[j] = *(const bf16x8*)&Bs[(wn * 64 + j * 16 + l16) * 32 + quad * 8];
        #pragma unroll
        for (int i = 0; i < 4; ++i) {
            bf16x8 af = *(const bf16x8*)&As[(wm * 64 + i * 16 + l16) * 32 + quad * 8];
            #pragma unroll
            for (int j = 0; j < 4; ++j)
                acc[i][j] = __builtin_amdgcn_mfma_f32_16x16x32_bf16(af, bfr[j], acc[i][j], 0, 0, 0);
        }
        __syncthreads();
    }
    bool bf = BIAS ? (flag[0] != 0) : false;
    #pragma unroll
    for (int i = 0; i < 4; ++i) {
        int row = m0 + wm * 64 + i * 16 + quad * 4;
        #pragma unroll
        for (int r = 0; r < 4; ++r) {
            float bv = BIAS ? ldf(bias, row + r, bf) : 0.0f;
            #pragma unroll
            for (int j = 0; j < 4; ++j) {
                int col = n0 + wn * 64 + j * 16 + l16;
                C[(size_t)(row + r) * OSTRIDE + col] = __float2bfloat16(acc[i][j][r] + bv);
            }
        }
    }
}

// ---------------------------------------------------------------- KV GEMM, A-resident pipelined
__global__ __launch_bounds__(512) void k_kvgemm(
        const bf16* __restrict__ Am, const bf16* __restrict__ Bm,
        bf16* __restrict__ C)
{
    __shared__ __align__(16) unsigned short As[128 * 256];      // 64 KiB
    __shared__ __align__(16) unsigned short Bs[2][64 * 256];    // 64 KiB
    const int t = threadIdx.x;
    const int w = t >> 6, lane = t & 63;
    const int quad = lane >> 4, l16 = lane & 15;
    const int wm = w >> 1, wn = w & 1;               // 4 x 2 waves over 128m x 64n
    const int p = blockIdx.x;
    const int xcd = p & 7, slot = p >> 3;
    const int chunk = xcd * 4 + (slot & 3);          // 0..31
    const int mt = slot >> 2;                        // 0..7
    const int m0 = mt * 128;
    const size_t cbase = (size_t)chunk * 2048;

    const int srow = t >> 5;                         // 0..15 per 16-row round
    const int sks  = (t & 31) ^ (srow & 7);          // pre-swizzled source slot

    #pragma unroll
    for (int q = 0; q < 8; ++q)
        gld16(Am + (size_t)(m0 + q * 16 + srow) * 256 + sks * 8,
              (char*)As + q * 8192 + w * 1024);
    #pragma unroll
    for (int q = 0; q < 4; ++q)
        gld16(Bm + (cbase + q * 16 + srow) * 256 + sks * 8,
              (char*)Bs[0] + q * 8192 + w * 1024);
    #pragma unroll
    for (int q = 0; q < 4; ++q)
        gld16(Bm + (cbase + 64 + q * 16 + srow) * 256 + sks * 8,
              (char*)Bs[1] + q * 8192 + w * 1024);

    asm volatile("s_waitcnt vmcnt(8)" ::: "memory");
    __builtin_amdgcn_s_barrier();
    asm volatile("" ::: "memory");

    bf16x8 af[2][8];
    #pragma unroll
    for (int i = 0; i < 2; ++i) {
        int row = wm * 32 + i * 16 + l16;
        #pragma unroll
        for (int kk = 0; kk < 8; ++kk)
            af[i][kk] = *(const bf16x8*)((const char*)As + row * 512 +
                         (((kk * 4 + quad) ^ (row & 7)) << 4));
    }

    for (int s = 0; s < 32; ++s) {
        if (s > 0) {
            asm volatile("" ::: "memory");
            __builtin_amdgcn_s_barrier();
            asm volatile("" ::: "memory");
            if (s + 1 < 32) {
                #pragma unroll
                for (int q = 0; q < 4; ++q)
                    gld16(Bm + (cbase + (size_t)(s + 1) * 64 + q * 16 + srow) * 256 + sks * 8,
                          (char*)Bs[(s + 1) & 1] + q * 8192 + w * 1024);
            }
        }
        if (s == 0)      asm volatile("s_waitcnt vmcnt(4)"  ::: "memory");
        else if (s < 31) asm volatile("s_waitcnt vmcnt(20)" ::: "memory");
        else             asm volatile("s_waitcnt vmcnt(16)" ::: "memory");
        __builtin_amdgcn_s_barrier();
        asm volatile("" ::: "memory");

        const unsigned short* Bbuf = Bs[s & 1];
        f32x4 acc[2][2] = {};
        #pragma unroll
        for (int kk = 0; kk < 8; ++kk) {
            bf16x8 bfr[2];
            #pragma unroll
            for (int j = 0; j < 2; ++j) {
                int row = wn * 32 + j * 16 + l16;
                bfr[j] = *(const bf16x8*)((const char*)Bbuf + row * 512 +
                          (((kk * 4 + quad) ^ (row & 7)) << 4));
            }
            #pragma unroll
            for (int i = 0; i < 2; ++i)
                #pragma unroll
                for (int j = 0; j < 2; ++j)
                    acc[i][j] = __builtin_amdgcn_mfma_f32_16x16x32_bf16(af[i][kk], bfr[j], acc[i][j], 0, 0, 0);
        }
        #pragma unroll
        for (int i = 0; i < 2; ++i) {
            #pragma unroll
            for (int r = 0; r < 4; ++r) {
                int row = m0 + wm * 32 + i * 16 + quad * 4 + r;
                size_t col = cbase + (size_t)s * 64 + wn * 32;
                #pragma unroll
                for (int j = 0; j < 2; ++j)
                    C[(size_t)row * PTOT + col + j * 16 + l16] = __float2bfloat16(acc[i][j][r]);
            }
        }
    }
}

// ---------------------------------------------------------------- fused Q GEMM + q-softmax + context apply (v2)
// Block = 128 Q-channels (2 heads, A-resident from wq) x 1024 positions,
// streamed as 16 x 64-pos slices, double-buffered, counted vmcnt.
// Per slice: GEMM1 -> S32 LDS -> per-thread serial softmax -> qsm bf16 -> PV vs ctS.
__global__ __launch_bounds__(512) void k_qapply(
        const bf16* __restrict__ xn, const bf16* __restrict__ wq,
        const unsigned short* __restrict__ ct_bf,
        unsigned short* __restrict__ oat_pe)
{
    __shared__ __align__(16) char smem[147456];
    unsigned short* As  = (unsigned short*)smem;            // [128][256] wq (reused by S32/qsm)
    unsigned short* Bs  = (unsigned short*)(smem + 65536);  // [2][64][256] xn dbuf
    unsigned short* ctS = (unsigned short*)(smem + 131072); // [2][64*64] e-XOR-swizzled
    float*          S32 = (float*)smem;                     // [64][132] f32 scores
    unsigned short* qsm = (unsigned short*)(smem + 33792);  // [64][136] bf16 softmaxed
    const int t = threadIdx.x;
    const int w = t >> 6, lane = t & 63;
    const int quad = lane >> 4, l16 = lane & 15;
    const int wm = w >> 1, wn = w & 1;                      // GEMM1: 4 ch-quadrants x 2 pos-halves
    const int ct4 = blockIdx.x & 3;                         // ch tile (2 heads)
    const int chunk = blockIdx.x >> 2;                      // 0..63 pos chunk
    const int n0 = ct4 * 128;
    const size_t P0 = (size_t)chunk * 1024;
    const int b = (int)(P0 >> 12);
    const int srow = t >> 5, sks = (t & 31) ^ (srow & 7);

    // ---- prologue staging: wq(8) ct(2) B0(4) B1(4) ----
    #pragma unroll
    for (int q = 0; q < 8; ++q)
        gld16(wq + (size_t)(n0 + q * 16 + srow) * 256 + sks * 8,
              smem + q * 8192 + w * 1024);
    #pragma unroll
    for (int k = 0; k < 2; ++k) {
        int u = k * 512 + t;
        int hh = u >> 9, e = (u >> 3) & 63, slot = u & 7;
        gld16(ct_bf + (size_t)(b * 8 + ct4 * 2 + hh) * 4096 + e * 64 + ((slot ^ (e & 7)) * 8),
              (char*)ctS + k * 8192 + w * 1024);
    }
    #pragma unroll
    for (int q = 0; q < 4; ++q)
        gld16(xn + (P0 + q * 16 + srow) * 256 + sks * 8,
              (char*)Bs + q * 8192 + w * 1024);
    #pragma unroll
    for (int q = 0; q < 4; ++q)
        gld16(xn + (P0 + 64 + q * 16 + srow) * 256 + sks * 8,
              (char*)Bs + 32768 + q * 8192 + w * 1024);

    asm volatile("s_waitcnt vmcnt(10)" ::: "memory");   // wq landed; ct/B0/B1 in flight
    __builtin_amdgcn_s_barrier();
    asm volatile("" ::: "memory");

    // hoist wq fragments (As region is reused for S32/qsm afterwards)
    bf16x8 af[2][8];
    #pragma unroll
    for (int i = 0; i < 2; ++i) {
        int row = wm * 32 + i * 16 + l16;
        #pragma unroll
        for (int kk = 0; kk < 8; ++kk)
            af[i][kk] = *(const bf16x8*)((const char*)As + row * 512 +
                         (((kk * 4 + quad) ^ (row & 7)) << 4));
    }

    // softmax thread mapping: 4 threads per (pos, head) row
    const int smrow = t >> 2, smseg = t & 3;
    const int smpos = smrow >> 1, smhead = smrow & 1;
    // PV wave mapping: 2 heads x 2x2 quadrants
    const int hh = w >> 2, pm = (w >> 1) & 1, pn = w & 1;

    for (int s = 0; s < 16; ++s) {
        if (s > 0 && s + 1 < 16) {
            #pragma unroll
            for (int q = 0; q < 4; ++q)
                gld16(xn + (P0 + (size_t)(s + 1) * 64 + q * 16 + srow) * 256 + sks * 8,
                      (char*)Bs + ((s + 1) & 1) * 32768 + q * 8192 + w * 1024);
        }
        // wait for slice s data; keep newer loads + stores in flight
        if (s == 0)      asm volatile("s_waitcnt vmcnt(4)"  ::: "memory");
        else if (s < 15) asm volatile("s_waitcnt vmcnt(20)" ::: "memory");
        else             asm volatile("s_waitcnt vmcnt(16)" ::: "memory");
        __builtin_amdgcn_s_barrier();
        asm volatile("" ::: "memory");

        // ---- GEMM1: S[128 ch][64 pos] ----
        const char* Bbuf = (const char*)Bs + (s & 1) * 32768;
        f32x4 acc[2][2] = {};
        #pragma unroll
        for (int kk = 0; kk < 8; ++kk) {
            bf16x8 bfr[2];
            #pragma unroll
            for (int j = 0; j < 2; ++j) {
                int row = wn * 32 + j * 16 + l16;
                bfr[j] = *(const bf16x8*)(Bbuf + row * 512 +
                          (((kk * 4 + quad) ^ (row & 7)) << 4));
            }
            #pragma unroll
            for (int i = 0; i < 2; ++i)
                #pragma unroll
                for (int j = 0; j < 2; ++j)
                    acc[i][j] = __builtin_amdgcn_mfma_f32_16x16x32_bf16(af[i][kk], bfr[j], acc[i][j], 0, 0, 0);
        }
        // dump S to LDS f32 [pos][132]
        #pragma unroll
        for (int i = 0; i < 2; ++i)
            #pragma unroll
            for (int j = 0; j < 2; ++j) {
                int pos = wn * 32 + j * 16 + l16;
                int chb = wm * 32 + i * 16 + quad * 4;
                #pragma unroll
                for (int r = 0; r < 4; ++r)
                    S32[pos * 132 + chb + r] = acc[i][j][r];
            }
        asm volatile("s_waitcnt lgkmcnt(0)" ::: "memory");
        __builtin_amdgcn_s_barrier();
        asm volatile("" ::: "memory");

        // ---- per-thread serial softmax over 64 ch (4 threads/row, 16 ch each) ----
        {
            const float* srp = S32 + smpos * 132 + smhead * 64 + smseg * 16;
            f32x4 v[4];
            #pragma unroll
            for (int q = 0; q < 4; ++q) v[q] = *(const f32x4*)(srp + q * 4);
            float m = v[0][0];
            #pragma unroll
            for (int q = 0; q < 4; ++q)
                #pragma unroll
                for (int e = 0; e < 4; ++e) m = fmaxf(m, v[q][e]);
            m = fmaxf(m, __shfl_xor(m, 1));
            m = fmaxf(m, __shfl_xor(m, 2));
            float ev[16], sum = 0.f;
            #pragma unroll
            for (int q = 0; q < 4; ++q)
                #pragma unroll
                for (int e = 0; e < 4; ++e) {
                    float x = expf(v[q][e] - m);
                    ev[q * 4 + e] = x; sum += x;
                }
            sum += __shfl_xor(sum, 1);
            sum += __shfl_xor(sum, 2);
            float inv = 0.125f / sum;
            unsigned short tmp[16];
            #pragma unroll
            for (int q = 0; q < 16; ++q) tmp[q] = f2bs(ev[q] * inv);
            unsigned short* dq = qsm + smpos * 136 + smhead * 64 + smseg * 16;
            *(uint4*)dq       = ((uint4*)tmp)[0];
            *(uint4*)(dq + 8) = ((uint4*)tmp)[1];
        }
        asm volatile("s_waitcnt lgkmcnt(0)" ::: "memory");
        __builtin_amdgcn_s_barrier();
        asm volatile("" ::: "memory");

        // ---- PV: out[64 pos][64 e] per head ----
        f32x4 acc2[2][2] = {};
        #pragma unroll
        for (int kk = 0; kk < 2; ++kk) {
            bf16x8 a2[2], b2[2];
            #pragma unroll
            for (int i = 0; i < 2; ++i)
                a2[i] = *(const bf16x8*)&qsm[(pm * 32 + i * 16 + l16) * 136 +
                                             hh * 64 + kk * 32 + quad * 8];
            #pragma unroll
            for (int j = 0; j < 2; ++j) {
                int e = pn * 32 + j * 16 + l16;
                b2[j] = *(const bf16x8*)&ctS[hh * 4096 + e * 64 +
                         (((kk * 4 + quad) ^ (e & 7)) * 8)];
            }
            #pragma unroll
            for (int i = 0; i < 2; ++i)
                #pragma unroll
                for (int j = 0; j < 2; ++j)
                    acc2[i][j] = __builtin_amdgcn_mfma_f32_16x16x32_bf16(a2[i], b2[j], acc2[i][j], 0, 0, 0);
        }
        #pragma unroll
        for (int i = 0; i < 2; ++i) {
            #pragma unroll
            for (int r = 0; r < 4; ++r) {
                size_t prow = P0 + (size_t)s * 64 + pm * 32 + i * 16 + quad * 4 + r;
                unsigned short* obase = oat_pe + prow * HID + n0 + hh * 64 + pn * 32;
                #pragma unroll
                for (int j = 0; j < 2; ++j)
                    obase[j * 16 + l16] = f2bs(acc2[i][j][r]);
            }
        }
    }
}

// ---------------------------------------------------------------- k row stats (max, 1/sumexp) over n=4100
__global__ __launch_bounds__(256) void k_kstats(
        const bf16* __restrict__ kv, const void* __restrict__ memkv,
        float* __restrict__ rowmax, float* __restrict__ rowinv,
        const int* __restrict__ flag)
{
    bool bf = flag[0] != 0;
    int r = blockIdx.x;                 // b*512 + h*64 + d
    int b = r >> 9, hd = r & 511;
    const unsigned short* krow = (const unsigned short*)kv + (size_t)hd * PTOT + b * NPOS;
    int t = threadIdx.x;
    float vals[16];
    float m = -1e30f;
    #pragma unroll
    for (int i = 0; i < 16; ++i) {
        vals[i] = us2f(krow[t + (i << 8)]);
        m = fmaxf(m, vals[i]);
    }
    float mv = (t < 4) ? ldf(memkv, hd * 4 + t, bf) : -1e30f;
    m = fmaxf(m, mv);
    __shared__ float red[256];
    red[t] = m; __syncthreads();
    for (int s = 128; s > 0; s >>= 1) {
        if (t < s) red[t] = fmaxf(red[t], red[t + s]);
        __syncthreads();
    }
    float M = red[0]; __syncthreads();
    float sum = 0.f;
    #pragma unroll
    for (int i = 0; i < 16; ++i) sum += expf(vals[i] - M);
    if (t < 4) sum += expf(mv - M);
    red[t] = sum; __syncthreads();
    for (int s = 128; s > 0; s >>= 1) {
        if (t < s) red[t] += red[t + s];
        __syncthreads();
    }
    if (t == 0) { rowmax[r] = M; rowinv[r] = 1.0f / red[0]; }
}

// ---------------------------------------------------------------- context via MFMA (validated R5)
__global__ __launch_bounds__(256) void k_context_mfma(
        const bf16* __restrict__ kv, const void* __restrict__ memkv,
        const float* __restrict__ rowmax, const float* __restrict__ rowinv,
        float* __restrict__ ctpart, const int* __restrict__ flag)
{
    bool bf = flag[0] != 0;
    int bh = blockIdx.x, chunk = blockIdx.y;
    int b = bh >> 3, h = bh & 7;
    __shared__ __align__(16) unsigned short As[4][64 * 32];
    __shared__ __align__(16) unsigned short Bs[4][64 * 32];
    __shared__ float rmS[64], riS[64];
    const int tid = threadIdx.x;
    if (tid < 64) {
        rmS[tid] = rowmax[(b << 9) + (h << 6) + tid];
        riS[tid] = rowinv[(b << 9) + (h << 6) + tid];
    }
    __syncthreads();
    const int wv = tid >> 6, lane = tid & 63;
    const int quad = lane >> 4, l16 = lane & 15;
    const int wm = wv >> 1, wn = wv & 1;
    const int krow = tid >> 2, kseg = tid & 3;
    const float rm = rmS[krow], ri = riS[krow];
    const unsigned short* kbase = (const unsigned short*)kv + (size_t)(h * HD) * PTOT + b * NPOS + chunk * 1024;
    const unsigned short* vbase = (const unsigned short*)kv + (size_t)(HID + h * HD) * PTOT + b * NPOS + chunk * 1024;
    f32x4 acc[2][2] = {};
    for (int s = 0; s < 8; ++s) {
        int nb = s * 128;
        #pragma unroll
        for (int kk = 0; kk < 4; ++kk) {
            uint4 u = *(const uint4*)(kbase + (size_t)krow * PTOT + nb + kk * 32 + kseg * 8);
            unsigned short out[8];
            const unsigned short* us = (const unsigned short*)&u;
            #pragma unroll
            for (int e = 0; e < 8; ++e)
                out[e] = f2bs(expf(us2f(us[e]) - rm) * ri);
            *(uint4*)&As[kk][krow * 32 + kseg * 8] = *(uint4*)out;
        }
        #pragma unroll
        for (int kk = 0; kk < 4; ++kk)
            gld16(vbase + (size_t)(wv * 16 + (lane >> 2)) * PTOT + nb + kk * 32 + (lane & 3) * 8,
                  &Bs[kk][wv * 512]);
        __syncthreads();
        #pragma unroll
        for (int kk = 0; kk < 4; ++kk) {
            bf16x8 bfr[2];
            #pragma unroll
            for (int j = 0; j < 2; ++j)
                bfr[j] = *(const bf16x8*)&Bs[kk][(wn * 32 + j * 16 + l16) * 32 + quad * 8];
            #pragma unroll
            for (int i = 0; i < 2; ++i) {
                bf16x8 af = *(const bf16x8*)&As[kk][(wm * 32 + i * 16 + l16) * 32 + quad * 8];
                #pragma unroll
                for (int j = 0; j < 2; ++j)
                    acc[i][j] = __builtin_amdgcn_mfma_f32_16x16x32_bf16(af, bfr[j], acc[i][j], 0, 0, 0);
            }
        }
        __syncthreads();
    }
    if (chunk == 0) {
        float mv[2][4];
        #pragma unroll
        for (int j = 0; j < 2; ++j) {
            int e = wn * 32 + j * 16 + l16;
            #pragma unroll
            for (int mm = 0; mm < 4; ++mm)
                mv[j][mm] = ldf(memkv, 2048 + ((h << 6) + e) * 4 + mm, bf);
        }
        #pragma unroll
        for (int i = 0; i < 2; ++i) {
            #pragma unroll
            for (int r = 0; r < 4; ++r) {
                int d = wm * 32 + i * 16 + quad * 4 + r;
                #pragma unroll
                for (int mm = 0; mm < 4; ++mm) {
                    float kw = expf(ldf(memkv, ((h << 6) + d) * 4 + mm, bf) - rmS[d]) * riS[d];
                    #pragma unroll
                    for (int j = 0; j < 2; ++j)
                        acc[i][j][r] = fmaf(kw, mv[j][mm], acc[i][j][r]);
                }
            }
        }
    }
    float* outp = ctpart + (size_t)(chunk * 128 + bh) * 4096;
    #pragma unroll
    for (int i = 0; i < 2; ++i) {
        #pragma unroll
        for (int r = 0; r < 4; ++r) {
            int d = wm * 32 + i * 16 + quad * 4 + r;
            #pragma unroll
            for (int j = 0; j < 2; ++j) {
                int e = wn * 32 + j * 16 + l16;
                outp[d * 64 + e] = acc[i][j][r];
            }
        }
    }
}

// ---------------------------------------------------------------- sum ctpart chunks -> ct_bf [bh][e][d] bf16 (transposed)
__global__ __launch_bounds__(256) void k_ctsum(
        const float* __restrict__ ctpart, unsigned short* __restrict__ ct_bf)
{
    int bh = blockIdx.x, t = threadIdx.x;
    int i0 = t * 16;
    int e = i0 >> 6, d0 = i0 & 63;
    unsigned short tmp[16];
    #pragma unroll
    for (int j = 0; j < 16; ++j) {
        int d = d0 + j;
        float s = 0.f;
        #pragma unroll
        for (int c = 0; c < 4; ++c)
            s += ctpart[(size_t)(c * 128 + bh) * 4096 + d * 64 + e];
        tmp[j] = f2bs(s);
    }
    unsigned short* dst = ct_bf + (size_t)bh * 4096 + i0;
    *(uint4*)dst = ((uint4*)tmp)[0];
    *(uint4*)(dst + 8) = ((uint4*)tmp)[1];
}

// ---------------------------------------------------------------- rmsnorm(pre bf16) -> d_out [b][c][pos]
template<bool BF>
__device__ __forceinline__ void rmsout_body(const unsigned short* __restrict__ pre,
        const void* __restrict__ g, void* __restrict__ out, float* __restrict__ smem)
{
    float* gS   = smem;          // 256
    float* red2 = smem + 256;    // [16][64]
    float* sS   = smem + 1280;   // 64
    const int t = threadIdx.x;
    const int p0 = blockIdx.x * 64;
    const int b = p0 >> 12;
    const int posbase = p0 & 4095;
    gS[t] = ldf(g, t, BF);
    const int pl4 = (t & 15) * 4;
    const int crow = t >> 4;                 // 0..15
    const unsigned short* pbase = pre + p0 + pl4;
    ushort4 u[16];
    float ssq[4] = {0.f, 0.f, 0.f, 0.f};
    #pragma unroll
    for (int rr = 0; rr < 16; ++rr) {
        int c = rr * 16 + crow;
        u[rr] = *(const ushort4*)(pbase + (size_t)c * PTOT);
        float v0 = us2f(u[rr].x), v1 = us2f(u[rr].y), v2 = us2f(u[rr].z), v3 = us2f(u[rr].w);
        ssq[0] += v0 * v0; ssq[1] += v1 * v1; ssq[2] += v2 * v2; ssq[3] += v3 * v3;
    }
    #pragma unroll
    for (int e = 0; e < 4; ++e) red2[crow * 64 + pl4 + e] = ssq[e];
    __syncthreads();
    if (t < 64) {
        float tot = 0.f;
        #pragma unroll
        for (int j = 0; j < 16; ++j) tot += red2[j * 64 + t];
        sS[t] = 16.0f / fmaxf(sqrtf(tot), 1e-12f);
    }
    __syncthreads();
    const float s0 = sS[pl4], s1 = sS[pl4 + 1], s2 = sS[pl4 + 2], s3 = sS[pl4 + 3];
    #pragma unroll
    for (int rr = 0; rr < 16; ++rr) {
        int c = rr * 16 + crow;
        float gv = gS[c];
        float v0 = us2f(u[rr].x) * s0 * gv;
        float v1 = us2f(u[rr].y) * s1 * gv;
        float v2 = us2f(u[rr].z) * s2 * gv;
        float v3 = us2f(u[rr].w) * s3 * gv;
        size_t oi = ((size_t)(b * CIN + c) << 12) + posbase + pl4;
        if (BF) {
            ushort4 o;
            o.x = f2bs(v0); o.y = f2bs(v1); o.z = f2bs(v2); o.w = f2bs(v3);
            *(ushort4*)((unsigned short*)out + oi) = o;
        } else {
            float4 o; o.x = v0; o.y = v1; o.z = v2; o.w = v3;
            *(float4*)((float*)out + oi) = o;
        }
    }
}
__global__ __launch_bounds__(256) void k_rmsnorm_out(
        const unsigned short* __restrict__ pre, const void* __restrict__ g,
        void* __restrict__ out, const int* __restrict__ flag)
{
    __shared__ float smem[1344];
    if (flag[0]) rmsout_body<true>(pre, g, out, smem);
    else         rmsout_body<false>(pre, g, out, smem);
}

extern "C" void kernel_launch(void* const* d_in, const int* in_sizes, int n_in,
                              void* d_out, int out_size, void* d_ws, size_t ws_size,
                              hipStream_t stream) {
    const void* x     = d_in[0];
    const void* g_in  = d_in[1];
    const void* w_qkv = d_in[2];
    const void* memkv = d_in[3];
    const void* w_out = d_in[4];
    const void* b_out = d_in[5];
    const void* g_out = d_in[6];

    // ---- workspace: peak 128 MiB ----
    char* ws = (char*)d_ws;
    bf16*           kv     = (bf16*)ws;                        // [1024][65536] bf16: K 0..511, V 512..1023
    unsigned short* oat_pe = (unsigned short*)(ws + 67108864); // [65536][512] bf16, over dead V
    unsigned short* pre    = (unsigned short*)ws;              // [256][65536] bf16, over dead K
    int*            flagB  = (int*)(ws + 50331648);            // dead zone at relay time

    // ---- scratch in d_out (fp32 out = 67 MB; layout validated R3-R5) ----
    char* ob = (char*)d_out;
    float*          ctpart = (float*)ob;                        // 8 MiB  [4][128][64][64]
    float*          rowmax = (float*)(ob + 8388608);            // 32 KiB
    float*          rowinv = (float*)(ob + 8421376);            // 32 KiB
    int*            flagA  = (int*)(ob + 8454144);              // 4 B
    unsigned short* wq_b   = (unsigned short*)(ob + 9437184);   // 768 KiB
    unsigned short* wout_b = (unsigned short*)(ob + 10485760);  // 256 KiB
    unsigned short* ct_bf  = (unsigned short*)(ob + 11010048);  // 1 MiB [128][64 e][64 d]
    unsigned short* xn     = (unsigned short*)(ob + 12582912);  // [65536][256] bf16 = 32 MiB

    k_detect<<<1, 256, 0, stream>>>((const unsigned*)x, flagA);

    k_cvt<<<1536, 256, 0, stream>>>(w_qkv, wq_b, 1536 * 256, flagA);
    k_cvt<<<512, 256, 0, stream>>>(w_out, wout_b, 256 * 512, flagA);

    k_norm_xn<<<1024, 256, 0, stream>>>(x, g_in, xn, flagA);

    // K/V = w_qkv rows 512..1535: C[1024][PTOT], A-resident pipelined kernel
    k_kvgemm<<<256, 512, 0, stream>>>(
        (const bf16*)(wq_b + (size_t)512 * CIN), (const bf16*)xn, kv);

    k_kstats<<<8192, 256, 0, stream>>>(kv, memkv, rowmax, rowinv, flagA);

    dim3 gctx(128, 4);
    k_context_mfma<<<gctx, 256, 0, stream>>>(kv, memkv, rowmax, rowinv, ctpart, flagA);

    k_ctsum<<<128, 256, 0, stream>>>(ctpart, ct_bf);

    // fused: Q GEMM + q-softmax + ct apply -> oat_pe[p][512]  (kvgemm-style pipeline)
    k_qapply<<<256, 512, 0, stream>>>(
        (const bf16*)xn, (const bf16*)wq_b, ct_bf, oat_pe);

    // pre[256][PTOT] = w_out[256][512] · oat_pe[p][512]^T + b_out
    dim3 go(512, 2);
    k_mfma<HID, true, PTOT><<<go, 256, 0, stream>>>(
        (const bf16*)wout_b, (const bf16*)oat_pe, b_out, (bf16*)pre, flagA);

    k_relay<<<1, 1, 0, stream>>>(flagA, flagB);

    k_rmsnorm_out<<<1024, 256, 0, stream>>>(pre, g_out, d_out, flagB);
}

// Round 5
// 336.679 us; speedup vs baseline: 1.2207x; 1.0396x over previous
//
#include <hip/hip_runtime.h>
#include <hip/hip_bf16.h>

typedef __hip_bfloat16 bf16;
typedef short bf16x8 __attribute__((ext_vector_type(8)));
typedef float f32x4 __attribute__((ext_vector_type(4)));

#define PTOT  65536   // b * h * w = 16 * 4096
#define NPOS  4096    // h * w
#define CIN   256
#define HID   512
#define HD    64

__device__ __forceinline__ float us2f(unsigned short u) {
    return __uint_as_float(((unsigned int)u) << 16);
}
__device__ __forceinline__ float ldf(const void* p, size_t i, bool bf) {
    return bf ? us2f(((const unsigned short*)p)[i]) : ((const float*)p)[i];
}
__device__ __forceinline__ unsigned short f2bs(float v) {
    __hip_bfloat16 h = __float2bfloat16(v);
    return *reinterpret_cast<unsigned short*>(&h);
}
// async global->LDS, 16 B per lane; lds dest must be wave-uniform base
__device__ __forceinline__ void gld16(const void* g, void* s) {
    __builtin_amdgcn_global_load_lds(
        (const __attribute__((address_space(1))) unsigned int*)g,
        (__attribute__((address_space(3))) unsigned int*)s, 16, 0, 0);
}

// ---------------------------------------------------------------- dtype detector
__global__ __launch_bounds__(256) void k_detect(const unsigned* __restrict__ x,
                                                int* __restrict__ flag) {
    int t = threadIdx.x;
    unsigned w = x[(size_t)t * 997];
    unsigned e7 = (w >> 8) & 0x7f;
    __shared__ int s[256];
    s[t] = (e7 >= 58 && e7 <= 66) ? 1 : 0;
    __syncthreads();
    for (int k = 128; k > 0; k >>= 1) { if (t < k) s[t] += s[t + k]; __syncthreads(); }
    if (t == 0) flag[0] = (s[0] >= 128) ? 1 : 0;
}

__global__ void k_relay(const int* __restrict__ src, int* __restrict__ dst) {
    dst[0] = src[0];
}

// ---------------------------------------------------------------- elementwise convert -> bf16
__global__ __launch_bounds__(256) void k_cvt(const void* __restrict__ src,
        unsigned short* __restrict__ dst, int n, const int* __restrict__ flag) {
    bool bf = flag[0] != 0;
    int i = blockIdx.x * 256 + threadIdx.x;
    if (i < n) dst[i] = f2bs(ldf(src, i, bf));
}

// ---------------------------------------------------------------- rmsnorm(x) -> xn bf16 [p][c] (c contiguous)
template<bool BF>
__device__ __forceinline__ void norm_xn_body(const void* __restrict__ x,
        const void* __restrict__ g, unsigned short* __restrict__ xn,
        float* __restrict__ smem)
{
    float* xs   = smem;            // 4 * 4304 floats
    float* gS   = smem + 17216;    // 256
    float* red2 = smem + 17472;    // [16][64]
    float* sS   = smem + 18496;    // 64
    const int t = threadIdx.x;
    const int p0 = blockIdx.x * 64;
    const int b = p0 >> 12;
    const int posbase = p0 & 4095;
    gS[t] = ldf(g, t, BF);
    __syncthreads();
    const int pl4 = (t & 15) * 4;
    const int crow = t >> 4;                 // 0..15
    const size_t xbase = ((size_t)b * CIN) << 12;
    float ssq[4] = {0.f, 0.f, 0.f, 0.f};
    #pragma unroll
    for (int rr = 0; rr < 16; ++rr) {
        int c = rr * 16 + crow;
        float v[4];
        if (BF) {
            ushort4 u = *(const ushort4*)((const unsigned short*)x + xbase +
                                          ((size_t)c << 12) + posbase + pl4);
            v[0] = us2f(u.x); v[1] = us2f(u.y); v[2] = us2f(u.z); v[3] = us2f(u.w);
        } else {
            float4 f = *(const float4*)((const float*)x + xbase +
                                        ((size_t)c << 12) + posbase + pl4);
            v[0] = f.x; v[1] = f.y; v[2] = f.z; v[3] = f.w;
        }
        float gv = gS[c];
        float* row = xs + (c >> 6) * 4304 + (c & 63) * 67;
        #pragma unroll
        for (int e = 0; e < 4; ++e) {
            ssq[e] += v[e] * v[e];
            row[pl4 + e] = v[e] * gv;
        }
    }
    #pragma unroll
    for (int e = 0; e < 4; ++e) red2[crow * 64 + pl4 + e] = ssq[e];
    __syncthreads();
    if (t < 64) {
        float tot = 0.f;
        #pragma unroll
        for (int j = 0; j < 16; ++j) tot += red2[j * 64 + t];
        sS[t] = 16.0f / fmaxf(sqrtf(tot), 1e-12f);
    }
    __syncthreads();
    const int pr = t >> 2, c0 = (t & 3) * 64;
    const float sc = sS[pr];
    const float* base = xs + (t & 3) * 4304 + pr;
    unsigned short* dst = &xn[(size_t)(p0 + pr) * 256 + c0];
    #pragma unroll
    for (int q = 0; q < 4; ++q) {
        unsigned short tmp[16];
        #pragma unroll
        for (int j = 0; j < 16; ++j)
            tmp[j] = f2bs(base[(q * 16 + j) * 67] * sc);
        *(uint4*)(dst + q * 16)     = ((uint4*)tmp)[0];
        *(uint4*)(dst + q * 16 + 8) = ((uint4*)tmp)[1];
    }
}
__global__ __launch_bounds__(256) void k_norm_xn(
        const void* __restrict__ x, const void* __restrict__ g,
        unsigned short* __restrict__ xn, const int* __restrict__ flag)
{
    __shared__ float smem[18560];
    if (flag[0]) norm_xn_body<true>(x, g, xn, smem);
    else         norm_xn_body<false>(x, g, xn, smem);
}

// ---------------------------------------------------------------- MFMA GEMM: C[m][n] = Am[m][k] · Bm[n][k]^T
template<int KTOT, bool BIAS, int OSTRIDE>
__global__ __launch_bounds__(256) void k_mfma(
        const bf16* __restrict__ Am, const bf16* __restrict__ Bm,
        const void* __restrict__ bias, bf16* __restrict__ C,
        const int* __restrict__ flag)
{
    __shared__ __align__(16) unsigned short As[128 * 32];
    __shared__ __align__(16) unsigned short Bs[128 * 32];
    const int tid = threadIdx.x;
    const int wv = tid >> 6, lane = tid & 63;
    const int quad = lane >> 4, l16 = lane & 15;
    const int wm = wv >> 1, wn = wv & 1;
    const int m0 = blockIdx.y * 128, n0 = blockIdx.x * 128;
    f32x4 acc[4][4] = {};
    const bf16* gA = Am + (size_t)(m0 + (tid >> 2)) * KTOT + (tid & 3) * 8;
    const bf16* gB = Bm + (size_t)(n0 + (tid >> 2)) * KTOT + (tid & 3) * 8;
    unsigned short* lA = As + wv * 512;
    unsigned short* lB = Bs + wv * 512;
    for (int k0 = 0; k0 < KTOT; k0 += 32) {
        gld16(gA + k0, lA);
        gld16(gA + (size_t)64 * KTOT + k0, lA + 2048);
        gld16(gB + k0, lB);
        gld16(gB + (size_t)64 * KTOT + k0, lB + 2048);
        __syncthreads();
        bf16x8 bfr[4];
        #pragma unroll
        for (int j = 0; j < 4; ++j)
            bfr[j] = *(const bf16x8*)&Bs[(wn * 64 + j * 16 + l16) * 32 + quad * 8];
        #pragma unroll
        for (int i = 0; i < 4; ++i) {
            bf16x8 af = *(const bf16x8*)&As[(wm * 64 + i * 16 + l16) * 32 + quad * 8];
            #pragma unroll
            for (int j = 0; j < 4; ++j)
                acc[i][j] = __builtin_amdgcn_mfma_f32_16x16x32_bf16(af, bfr[j], acc[i][j], 0, 0, 0);
        }
        __syncthreads();
    }
    bool bf = BIAS ? (flag[0] != 0) : false;
    #pragma unroll
    for (int i = 0; i < 4; ++i) {
        int row = m0 + wm * 64 + i * 16 + quad * 4;
        #pragma unroll
        for (int r = 0; r < 4; ++r) {
            float bv = BIAS ? ldf(bias, row + r, bf) : 0.0f;
            #pragma unroll
            for (int j = 0; j < 4; ++j) {
                int col = n0 + wn * 64 + j * 16 + l16;
                C[(size_t)(row + r) * OSTRIDE + col] = __float2bfloat16(acc[i][j][r] + bv);
            }
        }
    }
}

// ---------------------------------------------------------------- KV GEMM, A-resident pipelined
__global__ __launch_bounds__(512) void k_kvgemm(
        const bf16* __restrict__ Am, const bf16* __restrict__ Bm,
        bf16* __restrict__ C)
{
    __shared__ __align__(16) unsigned short As[128 * 256];      // 64 KiB
    __shared__ __align__(16) unsigned short Bs[2][64 * 256];    // 64 KiB
    const int t = threadIdx.x;
    const int w = t >> 6, lane = t & 63;
    const int quad = lane >> 4, l16 = lane & 15;
    const int wm = w >> 1, wn = w & 1;               // 4 x 2 waves over 128m x 64n
    const int p = blockIdx.x;
    const int xcd = p & 7, slot = p >> 3;
    const int chunk = xcd * 4 + (slot & 3);          // 0..31
    const int mt = slot >> 2;                        // 0..7
    const int m0 = mt * 128;
    const size_t cbase = (size_t)chunk * 2048;

    const int srow = t >> 5;                         // 0..15 per 16-row round
    const int sks  = (t & 31) ^ (srow & 7);          // pre-swizzled source slot

    #pragma unroll
    for (int q = 0; q < 8; ++q)
        gld16(Am + (size_t)(m0 + q * 16 + srow) * 256 + sks * 8,
              (char*)As + q * 8192 + w * 1024);
    #pragma unroll
    for (int q = 0; q < 4; ++q)
        gld16(Bm + (cbase + q * 16 + srow) * 256 + sks * 8,
              (char*)Bs[0] + q * 8192 + w * 1024);
    #pragma unroll
    for (int q = 0; q < 4; ++q)
        gld16(Bm + (cbase + 64 + q * 16 + srow) * 256 + sks * 8,
              (char*)Bs[1] + q * 8192 + w * 1024);

    asm volatile("s_waitcnt vmcnt(8)" ::: "memory");
    __builtin_amdgcn_s_barrier();
    asm volatile("" ::: "memory");

    bf16x8 af[2][8];
    #pragma unroll
    for (int i = 0; i < 2; ++i) {
        int row = wm * 32 + i * 16 + l16;
        #pragma unroll
        for (int kk = 0; kk < 8; ++kk)
            af[i][kk] = *(const bf16x8*)((const char*)As + row * 512 +
                         (((kk * 4 + quad) ^ (row & 7)) << 4));
    }

    for (int s = 0; s < 32; ++s) {
        if (s > 0) {
            asm volatile("" ::: "memory");
            __builtin_amdgcn_s_barrier();
            asm volatile("" ::: "memory");
            if (s + 1 < 32) {
                #pragma unroll
                for (int q = 0; q < 4; ++q)
                    gld16(Bm + (cbase + (size_t)(s + 1) * 64 + q * 16 + srow) * 256 + sks * 8,
                          (char*)Bs[(s + 1) & 1] + q * 8192 + w * 1024);
            }
        }
        if (s == 0)      asm volatile("s_waitcnt vmcnt(4)"  ::: "memory");
        else if (s < 31) asm volatile("s_waitcnt vmcnt(20)" ::: "memory");
        else             asm volatile("s_waitcnt vmcnt(16)" ::: "memory");
        __builtin_amdgcn_s_barrier();
        asm volatile("" ::: "memory");

        const unsigned short* Bbuf = Bs[s & 1];
        f32x4 acc[2][2] = {};
        #pragma unroll
        for (int kk = 0; kk < 8; ++kk) {
            bf16x8 bfr[2];
            #pragma unroll
            for (int j = 0; j < 2; ++j) {
                int row = wn * 32 + j * 16 + l16;
                bfr[j] = *(const bf16x8*)((const char*)Bbuf + row * 512 +
                          (((kk * 4 + quad) ^ (row & 7)) << 4));
            }
            #pragma unroll
            for (int i = 0; i < 2; ++i)
                #pragma unroll
                for (int j = 0; j < 2; ++j)
                    acc[i][j] = __builtin_amdgcn_mfma_f32_16x16x32_bf16(af[i][kk], bfr[j], acc[i][j], 0, 0, 0);
        }
        #pragma unroll
        for (int i = 0; i < 2; ++i) {
            #pragma unroll
            for (int r = 0; r < 4; ++r) {
                int row = m0 + wm * 32 + i * 16 + quad * 4 + r;
                size_t col = cbase + (size_t)s * 64 + wn * 32;
                #pragma unroll
                for (int j = 0; j < 2; ++j)
                    C[(size_t)row * PTOT + col + j * 16 + l16] = __float2bfloat16(acc[i][j][r]);
            }
        }
    }
}

// ---------------------------------------------------------------- fused Q GEMM + q-softmax + context apply (v3)
// Block = 1 head (64 Q-ch, A-resident) x 1024 positions in 32-pos slices.
// 72 KiB LDS -> 2 blocks/CU. XCD-grouped grid: 8 head-blocks of a chunk share L2.
// All LDS tiles slot-XOR swizzled (balanced 8 lanes per bank group).
__global__ __launch_bounds__(512, 4) void k_qapply(
        const bf16* __restrict__ xn, const bf16* __restrict__ wq,
        const unsigned short* __restrict__ ct_bf,
        unsigned short* __restrict__ oat_pe)
{
    __shared__ __align__(16) char smem[73728];
    unsigned short* As  = (unsigned short*)smem;            // [64][256] wq staging (dead after hoist)
    float*          S32 = (float*)smem;                     // [32][64] f32, slot-XOR
    unsigned short* qsm = (unsigned short*)(smem + 8192);   // [32][64] bf16, slot-XOR
    unsigned short* Bs  = (unsigned short*)(smem + 32768);  // [2][32][256] xn dbuf
    unsigned short* ctS = (unsigned short*)(smem + 65536);  // [64][64] e-XOR
    const int t = threadIdx.x;
    const int w = t >> 6, lane = t & 63;
    const int quad = lane >> 4, l16 = lane & 15;
    const int wm = w >> 1, wn = w & 1;                      // GEMM1: 4m(16ch) x 2n(16pos)
    const int pm = w >> 2, pn = w & 3;                      // PV: 2m(16pos) x 4n(16e)
    const int bid = blockIdx.x;
    const int h = (bid >> 3) & 7;                           // head
    const int c = (bid & 7) | ((bid >> 6) << 3);            // chunk 0..63
    const int n0 = h * HD;
    const size_t P0 = (size_t)c * 1024;
    const int b = (int)(P0 >> 12);
    const int srow = t >> 5, sks = (t & 31) ^ (srow & 7);

    // ---- prologue: wq A(4) + ct(1) + B0(2) + B1(2) ----
    #pragma unroll
    for (int q = 0; q < 4; ++q)
        gld16(wq + (size_t)(n0 + q * 16 + srow) * 256 + sks * 8,
              smem + q * 8192 + w * 1024);
    {
        int e = t >> 3, sl = t & 7;
        gld16(ct_bf + (size_t)(b * 8 + h) * 4096 + e * 64 + ((sl ^ (e & 7)) * 8),
              (char*)ctS + w * 1024);
    }
    #pragma unroll
    for (int q = 0; q < 2; ++q)
        gld16(xn + (P0 + q * 16 + srow) * 256 + sks * 8,
              (char*)Bs + q * 8192 + w * 1024);
    #pragma unroll
    for (int q = 0; q < 2; ++q)
        gld16(xn + (P0 + 32 + q * 16 + srow) * 256 + sks * 8,
              (char*)Bs + 16384 + q * 8192 + w * 1024);

    asm volatile("s_waitcnt vmcnt(4)" ::: "memory");   // A+ct landed; B0,B1 in flight
    __builtin_amdgcn_s_barrier();
    asm volatile("" ::: "memory");

    // hoist wq fragments; As region becomes S32/qsm
    bf16x8 af[8];
    {
        int row = wm * 16 + l16;
        #pragma unroll
        for (int kk = 0; kk < 8; ++kk)
            af[kk] = *(const bf16x8*)((const char*)As + row * 512 +
                      (((kk * 4 + quad) ^ (row & 7)) << 4));
    }

    // softmax mapping: 16 threads per position row, 4 ch each
    const int smp = t >> 4, smseg = t & 15;

    for (int s = 0; s < 32; ++s) {
        if (s > 0 && s + 1 < 32) {
            #pragma unroll
            for (int q = 0; q < 2; ++q)
                gld16(xn + (P0 + (size_t)(s + 1) * 32 + q * 16 + srow) * 256 + sks * 8,
                      (char*)Bs + ((s + 1) & 1) * 16384 + q * 8192 + w * 1024);
        }
        if (s == 0)      asm volatile("s_waitcnt vmcnt(2)" ::: "memory");
        else if (s < 31) asm volatile("s_waitcnt vmcnt(6)" ::: "memory");
        else             asm volatile("s_waitcnt vmcnt(4)" ::: "memory");
        __builtin_amdgcn_s_barrier();
        asm volatile("" ::: "memory");

        // ---- GEMM1: S[64 ch][32 pos] ----
        const char* Bbuf = (const char*)Bs + (s & 1) * 16384;
        f32x4 acc = {};
        #pragma unroll
        for (int kk = 0; kk < 8; ++kk) {
            int row = wn * 16 + l16;
            bf16x8 bfr = *(const bf16x8*)(Bbuf + row * 512 +
                          (((kk * 4 + quad) ^ (row & 7)) << 4));
            acc = __builtin_amdgcn_mfma_f32_16x16x32_bf16(af[kk], bfr, acc, 0, 0, 0);
        }
        // dump S: ch = wm*16+quad*4+r (contiguous 4), pos = wn*16+l16
        {
            int pos = wn * 16 + l16;
            int sl = (wm * 4 + quad) ^ (pos & 7);
            *(f32x4*)&S32[pos * 64 + sl * 4] = acc;
        }
        asm volatile("s_waitcnt lgkmcnt(0)" ::: "memory");
        __builtin_amdgcn_s_barrier();
        asm volatile("" ::: "memory");

        // ---- softmax: 16 thr/row, 4 ch each ----
        {
            f32x4 v = *(const f32x4*)&S32[smp * 64 + ((smseg ^ (smp & 7)) << 2)];
            float m = fmaxf(fmaxf(v[0], v[1]), fmaxf(v[2], v[3]));
            #pragma unroll
            for (int st = 1; st < 16; st <<= 1)
                m = fmaxf(m, __shfl_xor(m, st));
            float ev[4], sum = 0.f;
            #pragma unroll
            for (int e = 0; e < 4; ++e) { ev[e] = __expf(v[e] - m); sum += ev[e]; }
            #pragma unroll
            for (int st = 1; st < 16; st <<= 1)
                sum += __shfl_xor(sum, st);
            float inv = 0.125f / sum;
            unsigned short tmp[4];
            #pragma unroll
            for (int e = 0; e < 4; ++e) tmp[e] = f2bs(ev[e] * inv);
            *(ushort4*)&qsm[smp * 64 + (((smseg >> 1) ^ (smp & 7)) << 3) + (smseg & 1) * 4]
                = *(ushort4*)tmp;
        }
        asm volatile("s_waitcnt lgkmcnt(0)" ::: "memory");
        __builtin_amdgcn_s_barrier();
        asm volatile("" ::: "memory");

        // ---- PV: out[32 pos][64 e] ----
        f32x4 acc2 = {};
        #pragma unroll
        for (int kk = 0; kk < 2; ++kk) {
            int prow = pm * 16 + l16;
            bf16x8 a2 = *(const bf16x8*)&qsm[prow * 64 +
                         (((kk * 4 + quad) ^ (prow & 7)) << 3)];
            int e = pn * 16 + l16;
            bf16x8 b2 = *(const bf16x8*)&ctS[e * 64 +
                         (((kk * 4 + quad) ^ (e & 7)) << 3)];
            acc2 = __builtin_amdgcn_mfma_f32_16x16x32_bf16(a2, b2, acc2, 0, 0, 0);
        }
        #pragma unroll
        for (int r = 0; r < 4; ++r) {
            size_t prow = P0 + (size_t)s * 32 + pm * 16 + quad * 4 + r;
            oat_pe[prow * HID + n0 + pn * 16 + l16] = f2bs(acc2[r]);
        }
    }
}

// ---------------------------------------------------------------- k row stats (max, 1/sumexp) over n=4100
__global__ __launch_bounds__(256) void k_kstats(
        const bf16* __restrict__ kv, const void* __restrict__ memkv,
        float* __restrict__ rowmax, float* __restrict__ rowinv,
        const int* __restrict__ flag)
{
    bool bf = flag[0] != 0;
    int r = blockIdx.x;                 // b*512 + h*64 + d
    int b = r >> 9, hd = r & 511;
    const unsigned short* krow = (const unsigned short*)kv + (size_t)hd * PTOT + b * NPOS;
    int t = threadIdx.x;
    float vals[16];
    float m = -1e30f;
    #pragma unroll
    for (int i = 0; i < 16; ++i) {
        vals[i] = us2f(krow[t + (i << 8)]);
        m = fmaxf(m, vals[i]);
    }
    float mv = (t < 4) ? ldf(memkv, hd * 4 + t, bf) : -1e30f;
    m = fmaxf(m, mv);
    __shared__ float red[256];
    red[t] = m; __syncthreads();
    for (int s = 128; s > 0; s >>= 1) {
        if (t < s) red[t] = fmaxf(red[t], red[t + s]);
        __syncthreads();
    }
    float M = red[0]; __syncthreads();
    float sum = 0.f;
    #pragma unroll
    for (int i = 0; i < 16; ++i) sum += __expf(vals[i] - M);
    if (t < 4) sum += __expf(mv - M);
    red[t] = sum; __syncthreads();
    for (int s = 128; s > 0; s >>= 1) {
        if (t < s) red[t] += red[t + s];
        __syncthreads();
    }
    if (t == 0) { rowmax[r] = M; rowinv[r] = 1.0f / red[0]; }
}

// ---------------------------------------------------------------- context via MFMA (validated R5)
__global__ __launch_bounds__(256) void k_context_mfma(
        const bf16* __restrict__ kv, const void* __restrict__ memkv,
        const float* __restrict__ rowmax, const float* __restrict__ rowinv,
        float* __restrict__ ctpart, const int* __restrict__ flag)
{
    bool bf = flag[0] != 0;
    int bh = blockIdx.x, chunk = blockIdx.y;
    int b = bh >> 3, h = bh & 7;
    __shared__ __align__(16) unsigned short As[4][64 * 32];
    __shared__ __align__(16) unsigned short Bs[4][64 * 32];
    __shared__ float rmS[64], riS[64];
    const int tid = threadIdx.x;
    if (tid < 64) {
        rmS[tid] = rowmax[(b << 9) + (h << 6) + tid];
        riS[tid] = rowinv[(b << 9) + (h << 6) + tid];
    }
    __syncthreads();
    const int wv = tid >> 6, lane = tid & 63;
    const int quad = lane >> 4, l16 = lane & 15;
    const int wm = wv >> 1, wn = wv & 1;
    const int krow = tid >> 2, kseg = tid & 3;
    const float rm = rmS[krow], ri = riS[krow];
    const unsigned short* kbase = (const unsigned short*)kv + (size_t)(h * HD) * PTOT + b * NPOS + chunk * 1024;
    const unsigned short* vbase = (const unsigned short*)kv + (size_t)(HID + h * HD) * PTOT + b * NPOS + chunk * 1024;
    f32x4 acc[2][2] = {};
    for (int s = 0; s < 8; ++s) {
        int nb = s * 128;
        #pragma unroll
        for (int kk = 0; kk < 4; ++kk) {
            uint4 u = *(const uint4*)(kbase + (size_t)krow * PTOT + nb + kk * 32 + kseg * 8);
            unsigned short out[8];
            const unsigned short* us = (const unsigned short*)&u;
            #pragma unroll
            for (int e = 0; e < 8; ++e)
                out[e] = f2bs(__expf(us2f(us[e]) - rm) * ri);
            *(uint4*)&As[kk][krow * 32 + kseg * 8] = *(uint4*)out;
        }
        #pragma unroll
        for (int kk = 0; kk < 4; ++kk)
            gld16(vbase + (size_t)(wv * 16 + (lane >> 2)) * PTOT + nb + kk * 32 + (lane & 3) * 8,
                  &Bs[kk][wv * 512]);
        __syncthreads();
        #pragma unroll
        for (int kk = 0; kk < 4; ++kk) {
            bf16x8 bfr[2];
            #pragma unroll
            for (int j = 0; j < 2; ++j)
                bfr[j] = *(const bf16x8*)&Bs[kk][(wn * 32 + j * 16 + l16) * 32 + quad * 8];
            #pragma unroll
            for (int i = 0; i < 2; ++i) {
                bf16x8 af = *(const bf16x8*)&As[kk][(wm * 32 + i * 16 + l16) * 32 + quad * 8];
                #pragma unroll
                for (int j = 0; j < 2; ++j)
                    acc[i][j] = __builtin_amdgcn_mfma_f32_16x16x32_bf16(af, bfr[j], acc[i][j], 0, 0, 0);
            }
        }
        __syncthreads();
    }
    if (chunk == 0) {
        float mv[2][4];
        #pragma unroll
        for (int j = 0; j < 2; ++j) {
            int e = wn * 32 + j * 16 + l16;
            #pragma unroll
            for (int mm = 0; mm < 4; ++mm)
                mv[j][mm] = ldf(memkv, 2048 + ((h << 6) + e) * 4 + mm, bf);
        }
        #pragma unroll
        for (int i = 0; i < 2; ++i) {
            #pragma unroll
            for (int r = 0; r < 4; ++r) {
                int d = wm * 32 + i * 16 + quad * 4 + r;
                #pragma unroll
                for (int mm = 0; mm < 4; ++mm) {
                    float kw = __expf(ldf(memkv, ((h << 6) + d) * 4 + mm, bf) - rmS[d]) * riS[d];
                    #pragma unroll
                    for (int j = 0; j < 2; ++j)
                        acc[i][j][r] = fmaf(kw, mv[j][mm], acc[i][j][r]);
                }
            }
        }
    }
    float* outp = ctpart + (size_t)(chunk * 128 + bh) * 4096;
    #pragma unroll
    for (int i = 0; i < 2; ++i) {
        #pragma unroll
        for (int r = 0; r < 4; ++r) {
            int d = wm * 32 + i * 16 + quad * 4 + r;
            #pragma unroll
            for (int j = 0; j < 2; ++j) {
                int e = wn * 32 + j * 16 + l16;
                outp[d * 64 + e] = acc[i][j][r];
            }
        }
    }
}

// ---------------------------------------------------------------- sum ctpart chunks -> ct_bf [bh][e][d] bf16 (transposed)
__global__ __launch_bounds__(256) void k_ctsum(
        const float* __restrict__ ctpart, unsigned short* __restrict__ ct_bf)
{
    int bh = blockIdx.x, t = threadIdx.x;
    int i0 = t * 16;
    int e = i0 >> 6, d0 = i0 & 63;
    unsigned short tmp[16];
    #pragma unroll
    for (int j = 0; j < 16; ++j) {
        int d = d0 + j;
        float s = 0.f;
        #pragma unroll
        for (int c = 0; c < 4; ++c)
            s += ctpart[(size_t)(c * 128 + bh) * 4096 + d * 64 + e];
        tmp[j] = f2bs(s);
    }
    unsigned short* dst = ct_bf + (size_t)bh * 4096 + i0;
    *(uint4*)dst = ((uint4*)tmp)[0];
    *(uint4*)(dst + 8) = ((uint4*)tmp)[1];
}

// ---------------------------------------------------------------- rmsnorm(pre bf16) -> d_out [b][c][pos]
template<bool BF>
__device__ __forceinline__ void rmsout_body(const unsigned short* __restrict__ pre,
        const void* __restrict__ g, void* __restrict__ out, float* __restrict__ smem)
{
    float* gS   = smem;          // 256
    float* red2 = smem + 256;    // [16][64]
    float* sS   = smem + 1280;   // 64
    const int t = threadIdx.x;
    const int p0 = blockIdx.x * 64;
    const int b = p0 >> 12;
    const int posbase = p0 & 4095;
    gS[t] = ldf(g, t, BF);
    const int pl4 = (t & 15) * 4;
    const int crow = t >> 4;                 // 0..15
    const unsigned short* pbase = pre + p0 + pl4;
    ushort4 u[16];
    float ssq[4] = {0.f, 0.f, 0.f, 0.f};
    #pragma unroll
    for (int rr = 0; rr < 16; ++rr) {
        int c = rr * 16 + crow;
        u[rr] = *(const ushort4*)(pbase + (size_t)c * PTOT);
        float v0 = us2f(u[rr].x), v1 = us2f(u[rr].y), v2 = us2f(u[rr].z), v3 = us2f(u[rr].w);
        ssq[0] += v0 * v0; ssq[1] += v1 * v1; ssq[2] += v2 * v2; ssq[3] += v3 * v3;
    }
    #pragma unroll
    for (int e = 0; e < 4; ++e) red2[crow * 64 + pl4 + e] = ssq[e];
    __syncthreads();
    if (t < 64) {
        float tot = 0.f;
        #pragma unroll
        for (int j = 0; j < 16; ++j) tot += red2[j * 64 + t];
        sS[t] = 16.0f / fmaxf(sqrtf(tot), 1e-12f);
    }
    __syncthreads();
    const float s0 = sS[pl4], s1 = sS[pl4 + 1], s2 = sS[pl4 + 2], s3 = sS[pl4 + 3];
    #pragma unroll
    for (int rr = 0; rr < 16; ++rr) {
        int c = rr * 16 + crow;
        float gv = gS[c];
        float v0 = us2f(u[rr].x) * s0 * gv;
        float v1 = us2f(u[rr].y) * s1 * gv;
        float v2 = us2f(u[rr].z) * s2 * gv;
        float v3 = us2f(u[rr].w) * s3 * gv;
        size_t oi = ((size_t)(b * CIN + c) << 12) + posbase + pl4;
        if (BF) {
            ushort4 o;
            o.x = f2bs(v0); o.y = f2bs(v1); o.z = f2bs(v2); o.w = f2bs(v3);
            *(ushort4*)((unsigned short*)out + oi) = o;
        } else {
            float4 o; o.x = v0; o.y = v1; o.z = v2; o.w = v3;
            *(float4*)((float*)out + oi) = o;
        }
    }
}
__global__ __launch_bounds__(256) void k_rmsnorm_out(
        const unsigned short* __restrict__ pre, const void* __restrict__ g,
        void* __restrict__ out, const int* __restrict__ flag)
{
    __shared__ float smem[1344];
    if (flag[0]) rmsout_body<true>(pre, g, out, smem);
    else         rmsout_body<false>(pre, g, out, smem);
}

extern "C" void kernel_launch(void* const* d_in, const int* in_sizes, int n_in,
                              void* d_out, int out_size, void* d_ws, size_t ws_size,
                              hipStream_t stream) {
    const void* x     = d_in[0];
    const void* g_in  = d_in[1];
    const void* w_qkv = d_in[2];
    const void* memkv = d_in[3];
    const void* w_out = d_in[4];
    const void* b_out = d_in[5];
    const void* g_out = d_in[6];

    // ---- workspace: peak 128 MiB ----
    char* ws = (char*)d_ws;
    bf16*           kv     = (bf16*)ws;                        // [1024][65536] bf16: K 0..511, V 512..1023
    unsigned short* oat_pe = (unsigned short*)(ws + 67108864); // [65536][512] bf16, over dead V
    unsigned short* pre    = (unsigned short*)ws;              // [256][65536] bf16, over dead K
    int*            flagB  = (int*)(ws + 50331648);            // dead zone at relay time

    // ---- scratch in d_out (fp32 out = 67 MB; layout validated R3-R5) ----
    char* ob = (char*)d_out;
    float*          ctpart = (float*)ob;                        // 8 MiB  [4][128][64][64]
    float*          rowmax = (float*)(ob + 8388608);            // 32 KiB
    float*          rowinv = (float*)(ob + 8421376);            // 32 KiB
    int*            flagA  = (int*)(ob + 8454144);              // 4 B
    unsigned short* wq_b   = (unsigned short*)(ob + 9437184);   // 768 KiB
    unsigned short* wout_b = (unsigned short*)(ob + 10485760);  // 256 KiB
    unsigned short* ct_bf  = (unsigned short*)(ob + 11010048);  // 1 MiB [128][64 e][64 d]
    unsigned short* xn     = (unsigned short*)(ob + 12582912);  // [65536][256] bf16 = 32 MiB

    k_detect<<<1, 256, 0, stream>>>((const unsigned*)x, flagA);

    k_cvt<<<1536, 256, 0, stream>>>(w_qkv, wq_b, 1536 * 256, flagA);
    k_cvt<<<512, 256, 0, stream>>>(w_out, wout_b, 256 * 512, flagA);

    k_norm_xn<<<1024, 256, 0, stream>>>(x, g_in, xn, flagA);

    // K/V = w_qkv rows 512..1535: C[1024][PTOT], A-resident pipelined kernel
    k_kvgemm<<<256, 512, 0, stream>>>(
        (const bf16*)(wq_b + (size_t)512 * CIN), (const bf16*)xn, kv);

    k_kstats<<<8192, 256, 0, stream>>>(kv, memkv, rowmax, rowinv, flagA);

    dim3 gctx(128, 4);
    k_context_mfma<<<gctx, 256, 0, stream>>>(kv, memkv, rowmax, rowinv, ctpart, flagA);

    k_ctsum<<<128, 256, 0, stream>>>(ctpart, ct_bf);

    // fused: Q GEMM + q-softmax + ct apply -> oat_pe[p][512]  (1-head blocks, 2/CU)
    k_qapply<<<512, 512, 0, stream>>>(
        (const bf16*)xn, (const bf16*)wq_b, ct_bf, oat_pe);

    // pre[256][PTOT] = w_out[256][512] · oat_pe[p][512]^T + b_out
    dim3 go(512, 2);
    k_mfma<HID, true, PTOT><<<go, 256, 0, stream>>>(
        (const bf16*)wout_b, (const bf16*)oat_pe, b_out, (bf16*)pre, flagA);

    k_relay<<<1, 1, 0, stream>>>(flagA, flagB);

    k_rmsnorm_out<<<1024, 256, 0, stream>>>(pre, g_out, d_out, flagB);
}

// Round 6
// 329.716 us; speedup vs baseline: 1.2465x; 1.0211x over previous
//
#include <hip/hip_runtime.h>
#include <hip/hip_bf16.h>

typedef __hip_bfloat16 bf16;
typedef short bf16x8 __attribute__((ext_vector_type(8)));
typedef float f32x4 __attribute__((ext_vector_type(4)));

#define PTOT  65536   // b * h * w = 16 * 4096
#define NPOS  4096    // h * w
#define CIN   256
#define HID   512
#define HD    64

__device__ __forceinline__ float us2f(unsigned short u) {
    return __uint_as_float(((unsigned int)u) << 16);
}
__device__ __forceinline__ float ldf(const void* p, size_t i, bool bf) {
    return bf ? us2f(((const unsigned short*)p)[i]) : ((const float*)p)[i];
}
__device__ __forceinline__ unsigned short f2bs(float v) {
    __hip_bfloat16 h = __float2bfloat16(v);
    return *reinterpret_cast<unsigned short*>(&h);
}
// async global->LDS, 16 B per lane; lds dest must be wave-uniform base
__device__ __forceinline__ void gld16(const void* g, void* s) {
    __builtin_amdgcn_global_load_lds(
        (const __attribute__((address_space(1))) unsigned int*)g,
        (__attribute__((address_space(3))) unsigned int*)s, 16, 0, 0);
}

// ---------------------------------------------------------------- dtype detector
__global__ __launch_bounds__(256) void k_detect(const unsigned* __restrict__ x,
                                                int* __restrict__ flag) {
    int t = threadIdx.x;
    unsigned w = x[(size_t)t * 997];
    unsigned e7 = (w >> 8) & 0x7f;
    __shared__ int s[256];
    s[t] = (e7 >= 58 && e7 <= 66) ? 1 : 0;
    __syncthreads();
    for (int k = 128; k > 0; k >>= 1) { if (t < k) s[t] += s[t + k]; __syncthreads(); }
    if (t == 0) flag[0] = (s[0] >= 128) ? 1 : 0;
}

__global__ void k_relay(const int* __restrict__ src, int* __restrict__ dst) {
    dst[0] = src[0];
}

// ---------------------------------------------------------------- elementwise convert -> bf16
__global__ __launch_bounds__(256) void k_cvt(const void* __restrict__ src,
        unsigned short* __restrict__ dst, int n, const int* __restrict__ flag) {
    bool bf = flag[0] != 0;
    int i = blockIdx.x * 256 + threadIdx.x;
    if (i < n) dst[i] = f2bs(ldf(src, i, bf));
}

// ---------------------------------------------------------------- rmsnorm(x) -> xn bf16 [p][c] (c contiguous)
template<bool BF>
__device__ __forceinline__ void norm_xn_body(const void* __restrict__ x,
        const void* __restrict__ g, unsigned short* __restrict__ xn,
        float* __restrict__ smem)
{
    float* xs   = smem;            // 4 * 4304 floats
    float* gS   = smem + 17216;    // 256
    float* red2 = smem + 17472;    // [16][64]
    float* sS   = smem + 18496;    // 64
    const int t = threadIdx.x;
    const int p0 = blockIdx.x * 64;
    const int b = p0 >> 12;
    const int posbase = p0 & 4095;
    gS[t] = ldf(g, t, BF);
    __syncthreads();
    const int pl4 = (t & 15) * 4;
    const int crow = t >> 4;                 // 0..15
    const size_t xbase = ((size_t)b * CIN) << 12;
    float ssq[4] = {0.f, 0.f, 0.f, 0.f};
    #pragma unroll
    for (int rr = 0; rr < 16; ++rr) {
        int c = rr * 16 + crow;
        float v[4];
        if (BF) {
            ushort4 u = *(const ushort4*)((const unsigned short*)x + xbase +
                                          ((size_t)c << 12) + posbase + pl4);
            v[0] = us2f(u.x); v[1] = us2f(u.y); v[2] = us2f(u.z); v[3] = us2f(u.w);
        } else {
            float4 f = *(const float4*)((const float*)x + xbase +
                                        ((size_t)c << 12) + posbase + pl4);
            v[0] = f.x; v[1] = f.y; v[2] = f.z; v[3] = f.w;
        }
        float gv = gS[c];
        float* row = xs + (c >> 6) * 4304 + (c & 63) * 67;
        #pragma unroll
        for (int e = 0; e < 4; ++e) {
            ssq[e] += v[e] * v[e];
            row[pl4 + e] = v[e] * gv;
        }
    }
    #pragma unroll
    for (int e = 0; e < 4; ++e) red2[crow * 64 + pl4 + e] = ssq[e];
    __syncthreads();
    if (t < 64) {
        float tot = 0.f;
        #pragma unroll
        for (int j = 0; j < 16; ++j) tot += red2[j * 64 + t];
        sS[t] = 16.0f / fmaxf(sqrtf(tot), 1e-12f);
    }
    __syncthreads();
    const int pr = t >> 2, c0 = (t & 3) * 64;
    const float sc = sS[pr];
    const float* base = xs + (t & 3) * 4304 + pr;
    unsigned short* dst = &xn[(size_t)(p0 + pr) * 256 + c0];
    #pragma unroll
    for (int q = 0; q < 4; ++q) {
        unsigned short tmp[16];
        #pragma unroll
        for (int j = 0; j < 16; ++j)
            tmp[j] = f2bs(base[(q * 16 + j) * 67] * sc);
        *(uint4*)(dst + q * 16)     = ((uint4*)tmp)[0];
        *(uint4*)(dst + q * 16 + 8) = ((uint4*)tmp)[1];
    }
}
__global__ __launch_bounds__(256) void k_norm_xn(
        const void* __restrict__ x, const void* __restrict__ g,
        unsigned short* __restrict__ xn, const int* __restrict__ flag)
{
    __shared__ float smem[18560];
    if (flag[0]) norm_xn_body<true>(x, g, xn, smem);
    else         norm_xn_body<false>(x, g, xn, smem);
}

// ---------------------------------------------------------------- MFMA GEMM: C[m][n] = Am[m][k] · Bm[n][k]^T
template<int KTOT, bool BIAS, int OSTRIDE>
__global__ __launch_bounds__(256) void k_mfma(
        const bf16* __restrict__ Am, const bf16* __restrict__ Bm,
        const void* __restrict__ bias, bf16* __restrict__ C,
        const int* __restrict__ flag)
{
    __shared__ __align__(16) unsigned short As[128 * 32];
    __shared__ __align__(16) unsigned short Bs[128 * 32];
    const int tid = threadIdx.x;
    const int wv = tid >> 6, lane = tid & 63;
    const int quad = lane >> 4, l16 = lane & 15;
    const int wm = wv >> 1, wn = wv & 1;
    const int m0 = blockIdx.y * 128, n0 = blockIdx.x * 128;
    f32x4 acc[4][4] = {};
    const bf16* gA = Am + (size_t)(m0 + (tid >> 2)) * KTOT + (tid & 3) * 8;
    const bf16* gB = Bm + (size_t)(n0 + (tid >> 2)) * KTOT + (tid & 3) * 8;
    unsigned short* lA = As + wv * 512;
    unsigned short* lB = Bs + wv * 512;
    for (int k0 = 0; k0 < KTOT; k0 += 32) {
        gld16(gA + k0, lA);
        gld16(gA + (size_t)64 * KTOT + k0, lA + 2048);
        gld16(gB + k0, lB);
        gld16(gB + (size_t)64 * KTOT + k0, lB + 2048);
        __syncthreads();
        bf16x8 bfr[4];
        #pragma unroll
        for (int j = 0; j < 4; ++j)
            bfr[j] = *(const bf16x8*)&Bs[(wn * 64 + j * 16 + l16) * 32 + quad * 8];
        #pragma unroll
        for (int i = 0; i < 4; ++i) {
            bf16x8 af = *(const bf16x8*)&As[(wm * 64 + i * 16 + l16) * 32 + quad * 8];
            #pragma unroll
            for (int j = 0; j < 4; ++j)
                acc[i][j] = __builtin_amdgcn_mfma_f32_16x16x32_bf16(af, bfr[j], acc[i][j], 0, 0, 0);
        }
        __syncthreads();
    }
    bool bf = BIAS ? (flag[0] != 0) : false;
    #pragma unroll
    for (int i = 0; i < 4; ++i) {
        int row = m0 + wm * 64 + i * 16 + quad * 4;
        #pragma unroll
        for (int r = 0; r < 4; ++r) {
            float bv = BIAS ? ldf(bias, row + r, bf) : 0.0f;
            #pragma unroll
            for (int j = 0; j < 4; ++j) {
                int col = n0 + wn * 64 + j * 16 + l16;
                C[(size_t)(row + r) * OSTRIDE + col] = __float2bfloat16(acc[i][j][r] + bv);
            }
        }
    }
}

// ---------------------------------------------------------------- KV GEMM, A-resident pipelined
__global__ __launch_bounds__(512) void k_kvgemm(
        const bf16* __restrict__ Am, const bf16* __restrict__ Bm,
        bf16* __restrict__ C)
{
    __shared__ __align__(16) unsigned short As[128 * 256];      // 64 KiB
    __shared__ __align__(16) unsigned short Bs[2][64 * 256];    // 64 KiB
    const int t = threadIdx.x;
    const int w = t >> 6, lane = t & 63;
    const int quad = lane >> 4, l16 = lane & 15;
    const int wm = w >> 1, wn = w & 1;               // 4 x 2 waves over 128m x 64n
    const int p = blockIdx.x;
    const int xcd = p & 7, slot = p >> 3;
    const int chunk = xcd * 4 + (slot & 3);          // 0..31
    const int mt = slot >> 2;                        // 0..7
    const int m0 = mt * 128;
    const size_t cbase = (size_t)chunk * 2048;

    const int srow = t >> 5;                         // 0..15 per 16-row round
    const int sks  = (t & 31) ^ (srow & 7);          // pre-swizzled source slot

    #pragma unroll
    for (int q = 0; q < 8; ++q)
        gld16(Am + (size_t)(m0 + q * 16 + srow) * 256 + sks * 8,
              (char*)As + q * 8192 + w * 1024);
    #pragma unroll
    for (int q = 0; q < 4; ++q)
        gld16(Bm + (cbase + q * 16 + srow) * 256 + sks * 8,
              (char*)Bs[0] + q * 8192 + w * 1024);
    #pragma unroll
    for (int q = 0; q < 4; ++q)
        gld16(Bm + (cbase + 64 + q * 16 + srow) * 256 + sks * 8,
              (char*)Bs[1] + q * 8192 + w * 1024);

    asm volatile("s_waitcnt vmcnt(8)" ::: "memory");
    __builtin_amdgcn_s_barrier();
    asm volatile("" ::: "memory");

    bf16x8 af[2][8];
    #pragma unroll
    for (int i = 0; i < 2; ++i) {
        int row = wm * 32 + i * 16 + l16;
        #pragma unroll
        for (int kk = 0; kk < 8; ++kk)
            af[i][kk] = *(const bf16x8*)((const char*)As + row * 512 +
                         (((kk * 4 + quad) ^ (row & 7)) << 4));
    }

    for (int s = 0; s < 32; ++s) {
        if (s > 0) {
            asm volatile("" ::: "memory");
            __builtin_amdgcn_s_barrier();
            asm volatile("" ::: "memory");
            if (s + 1 < 32) {
                #pragma unroll
                for (int q = 0; q < 4; ++q)
                    gld16(Bm + (cbase + (size_t)(s + 1) * 64 + q * 16 + srow) * 256 + sks * 8,
                          (char*)Bs[(s + 1) & 1] + q * 8192 + w * 1024);
            }
        }
        if (s == 0)      asm volatile("s_waitcnt vmcnt(4)"  ::: "memory");
        else if (s < 31) asm volatile("s_waitcnt vmcnt(20)" ::: "memory");
        else             asm volatile("s_waitcnt vmcnt(16)" ::: "memory");
        __builtin_amdgcn_s_barrier();
        asm volatile("" ::: "memory");

        const unsigned short* Bbuf = Bs[s & 1];
        f32x4 acc[2][2] = {};
        #pragma unroll
        for (int kk = 0; kk < 8; ++kk) {
            bf16x8 bfr[2];
            #pragma unroll
            for (int j = 0; j < 2; ++j) {
                int row = wn * 32 + j * 16 + l16;
                bfr[j] = *(const bf16x8*)((const char*)Bbuf + row * 512 +
                          (((kk * 4 + quad) ^ (row & 7)) << 4));
            }
            #pragma unroll
            for (int i = 0; i < 2; ++i)
                #pragma unroll
                for (int j = 0; j < 2; ++j)
                    acc[i][j] = __builtin_amdgcn_mfma_f32_16x16x32_bf16(af[i][kk], bfr[j], acc[i][j], 0, 0, 0);
        }
        #pragma unroll
        for (int i = 0; i < 2; ++i) {
            #pragma unroll
            for (int r = 0; r < 4; ++r) {
                int row = m0 + wm * 32 + i * 16 + quad * 4 + r;
                size_t col = cbase + (size_t)s * 64 + wn * 32;
                #pragma unroll
                for (int j = 0; j < 2; ++j)
                    C[(size_t)row * PTOT + col + j * 16 + l16] = __float2bfloat16(acc[i][j][r]);
            }
        }
    }
}

// ---------------------------------------------------------------- fused Q GEMM + q-softmax + context apply (v4)
// Transposed GEMM1 (A=xn pos rows, B=wq ch rows) -> S[pos][ch]: softmax over ch is
// in-register (4 regs x 16 lanes, shfl_xor<16). qsm LDS transpose is wave-self-local
// (same wave writes & reads its 16pos x 64ch tile) -> NO intra-slice barriers.
// Block = 2 heads x 1024 pos, 16 x 64-pos slices, counted vmcnt (kvgemm discipline).
// LDS 160 KiB: wq[0,64K) qsm[64K,80K) ct[80K,96K) xn dbuf[96K,160K).
__global__ __launch_bounds__(512, 2) void k_qapply(
        const bf16* __restrict__ xn, const bf16* __restrict__ wq,
        const unsigned short* __restrict__ ct_bf,
        unsigned short* __restrict__ oat_pe)
{
    __shared__ __align__(16) char smem[163840];
    const int t = threadIdx.x;
    const int w = t >> 6, lane = t & 63;
    const int quad = lane >> 4, l16 = lane & 15;
    const int wm = w >> 1, wn = w & 1;              // 4 pos-blocks x 2 heads
    const int bid = blockIdx.x;
    const int hp = (bid >> 3) & 3;                  // head pair
    const int c  = (bid & 7) | ((bid >> 5) << 3);   // chunk 0..63 (1024 pos), XCD-grouped
    const int n0 = hp * 128;
    const size_t P0 = (size_t)c * 1024;
    const int b = c >> 2;
    const int srow = t >> 5, sks = (t & 31) ^ (srow & 7);

    // ---- prologue: ct(2) wq(8) B0(4) B1(4) ----
    #pragma unroll
    for (int k = 0; k < 2; ++k) {
        int u = k * 512 + t;
        int hh = u >> 9, rem = u & 511, e = rem >> 3, sl = rem & 7;
        gld16(ct_bf + (size_t)(b * 8 + hp * 2 + hh) * 4096 + e * 64 + ((sl ^ (e & 7)) * 8),
              smem + 81920 + k * 8192 + w * 1024);
    }
    #pragma unroll
    for (int q = 0; q < 8; ++q)
        gld16(wq + (size_t)(n0 + q * 16 + srow) * 256 + sks * 8,
              smem + q * 8192 + w * 1024);
    #pragma unroll
    for (int q = 0; q < 4; ++q)
        gld16(xn + (P0 + q * 16 + srow) * 256 + sks * 8,
              smem + 98304 + q * 8192 + w * 1024);
    #pragma unroll
    for (int q = 0; q < 4; ++q)
        gld16(xn + (P0 + 64 + q * 16 + srow) * 256 + sks * 8,
              smem + 131072 + q * 8192 + w * 1024);

    asm volatile("s_waitcnt vmcnt(8)" ::: "memory");   // ct + wq landed; B0,B1 in flight
    __builtin_amdgcn_s_barrier();
    asm volatile("" ::: "memory");

    // hoist wq fragments of own head (region never rewritten -> no barrier after)
    bf16x8 wqf[4][8];
    #pragma unroll
    for (int j = 0; j < 4; ++j) {
        int row = wn * 64 + j * 16 + l16;
        #pragma unroll
        for (int kk = 0; kk < 8; ++kk)
            wqf[j][kk] = *(const bf16x8*)(smem + row * 512 +
                          (((kk * 4 + quad) ^ (row & 7)) << 4));
    }

    unsigned short* qsm = (unsigned short*)(smem + 65536);   // [64][128] slot-XOR

    for (int s = 0; s < 16; ++s) {
        if (s > 0) {
            asm volatile("" ::: "memory");
            __builtin_amdgcn_s_barrier();            // all waves done with slice s-1
            asm volatile("" ::: "memory");
            if (s + 1 < 16) {
                #pragma unroll
                for (int q = 0; q < 4; ++q)
                    gld16(xn + (P0 + (size_t)(s + 1) * 64 + q * 16 + srow) * 256 + sks * 8,
                          smem + 98304 + ((s + 1) & 1) * 32768 + q * 8192 + w * 1024);
            }
        }
        // counted waits: need B(s); in flight = B(s+1)(4) + stores s-1 (16)
        if (s == 0)      asm volatile("s_waitcnt vmcnt(4)"  ::: "memory");
        else if (s < 15) asm volatile("s_waitcnt vmcnt(20)" ::: "memory");
        else             asm volatile("s_waitcnt vmcnt(16)" ::: "memory");
        __builtin_amdgcn_s_barrier();
        asm volatile("" ::: "memory");

        // ---- GEMM1 (transposed): S[16 pos (wm)][64 ch (head wn)] ----
        const char* Bbuf = smem + 98304 + (s & 1) * 32768;
        f32x4 acc[4] = {};
        #pragma unroll
        for (int kk = 0; kk < 8; ++kk) {
            int row = wm * 16 + l16;
            bf16x8 xf = *(const bf16x8*)(Bbuf + row * 512 +
                          (((kk * 4 + quad) ^ (row & 7)) << 4));
            #pragma unroll
            for (int j = 0; j < 4; ++j)
                acc[j] = __builtin_amdgcn_mfma_f32_16x16x32_bf16(xf, wqf[j][kk], acc[j], 0, 0, 0);
        }

        // ---- in-register softmax over ch (j regs x l16 lanes), 4 pos rows ----
        #pragma unroll
        for (int r = 0; r < 4; ++r) {
            float m = fmaxf(fmaxf(acc[0][r], acc[1][r]), fmaxf(acc[2][r], acc[3][r]));
            m = fmaxf(m, __shfl_xor(m, 1));
            m = fmaxf(m, __shfl_xor(m, 2));
            m = fmaxf(m, __shfl_xor(m, 4));
            m = fmaxf(m, __shfl_xor(m, 8));
            float ev[4], sum = 0.f;
            #pragma unroll
            for (int j = 0; j < 4; ++j) { ev[j] = __expf(acc[j][r] - m); sum += ev[j]; }
            sum += __shfl_xor(sum, 1);
            sum += __shfl_xor(sum, 2);
            sum += __shfl_xor(sum, 4);
            sum += __shfl_xor(sum, 8);
            float inv = 0.125f / sum;
            int pos = wm * 16 + quad * 4 + r;
            #pragma unroll
            for (int j = 0; j < 4; ++j) {
                int ch = wn * 64 + j * 16 + l16;
                qsm[pos * 128 + (((ch >> 3) ^ (pos & 7)) << 3) + (ch & 7)] = f2bs(ev[j] * inv);
            }
        }

        // ---- PV: out[16 pos][64 e]; qsm reads are wave-self-local (no barrier) ----
        f32x4 acc2[4] = {};
        #pragma unroll
        for (int kk = 0; kk < 2; ++kk) {
            int row = wm * 16 + l16;
            bf16x8 qf = *(const bf16x8*)(smem + 65536 + row * 256 +
                         (((wn * 8 + kk * 4 + quad) ^ (row & 7)) << 4));
            #pragma unroll
            for (int j = 0; j < 4; ++j) {
                int e = j * 16 + l16;
                bf16x8 cf = *(const bf16x8*)(smem + 81920 + wn * 8192 + e * 128 +
                             (((kk * 4 + quad) ^ (e & 7)) << 4));
                acc2[j] = __builtin_amdgcn_mfma_f32_16x16x32_bf16(qf, cf, acc2[j], 0, 0, 0);
            }
        }
        #pragma unroll
        for (int j = 0; j < 4; ++j)
            #pragma unroll
            for (int r = 0; r < 4; ++r) {
                size_t prow = P0 + (size_t)s * 64 + wm * 16 + quad * 4 + r;
                oat_pe[prow * HID + n0 + wn * 64 + j * 16 + l16] = f2bs(acc2[j][r]);
            }
    }
}

// ---------------------------------------------------------------- k row stats (max, 1/sumexp) over n=4100
__global__ __launch_bounds__(256) void k_kstats(
        const bf16* __restrict__ kv, const void* __restrict__ memkv,
        float* __restrict__ rowmax, float* __restrict__ rowinv,
        const int* __restrict__ flag)
{
    bool bf = flag[0] != 0;
    int r = blockIdx.x;                 // b*512 + h*64 + d
    int b = r >> 9, hd = r & 511;
    const unsigned short* krow = (const unsigned short*)kv + (size_t)hd * PTOT + b * NPOS;
    int t = threadIdx.x;
    float vals[16];
    float m = -1e30f;
    #pragma unroll
    for (int i = 0; i < 16; ++i) {
        vals[i] = us2f(krow[t + (i << 8)]);
        m = fmaxf(m, vals[i]);
    }
    float mv = (t < 4) ? ldf(memkv, hd * 4 + t, bf) : -1e30f;
    m = fmaxf(m, mv);
    __shared__ float red[256];
    red[t] = m; __syncthreads();
    for (int s = 128; s > 0; s >>= 1) {
        if (t < s) red[t] = fmaxf(red[t], red[t + s]);
        __syncthreads();
    }
    float M = red[0]; __syncthreads();
    float sum = 0.f;
    #pragma unroll
    for (int i = 0; i < 16; ++i) sum += __expf(vals[i] - M);
    if (t < 4) sum += __expf(mv - M);
    red[t] = sum; __syncthreads();
    for (int s = 128; s > 0; s >>= 1) {
        if (t < s) red[t] += red[t + s];
        __syncthreads();
    }
    if (t == 0) { rowmax[r] = M; rowinv[r] = 1.0f / red[0]; }
}

// ---------------------------------------------------------------- context via MFMA (validated R5)
__global__ __launch_bounds__(256) void k_context_mfma(
        const bf16* __restrict__ kv, const void* __restrict__ memkv,
        const float* __restrict__ rowmax, const float* __restrict__ rowinv,
        float* __restrict__ ctpart, const int* __restrict__ flag)
{
    bool bf = flag[0] != 0;
    int bh = blockIdx.x, chunk = blockIdx.y;
    int b = bh >> 3, h = bh & 7;
    __shared__ __align__(16) unsigned short As[4][64 * 32];
    __shared__ __align__(16) unsigned short Bs[4][64 * 32];
    __shared__ float rmS[64], riS[64];
    const int tid = threadIdx.x;
    if (tid < 64) {
        rmS[tid] = rowmax[(b << 9) + (h << 6) + tid];
        riS[tid] = rowinv[(b << 9) + (h << 6) + tid];
    }
    __syncthreads();
    const int wv = tid >> 6, lane = tid & 63;
    const int quad = lane >> 4, l16 = lane & 15;
    const int wm = wv >> 1, wn = wv & 1;
    const int krow = tid >> 2, kseg = tid & 3;
    const float rm = rmS[krow], ri = riS[krow];
    const unsigned short* kbase = (const unsigned short*)kv + (size_t)(h * HD) * PTOT + b * NPOS + chunk * 1024;
    const unsigned short* vbase = (const unsigned short*)kv + (size_t)(HID + h * HD) * PTOT + b * NPOS + chunk * 1024;
    f32x4 acc[2][2] = {};
    for (int s = 0; s < 8; ++s) {
        int nb = s * 128;
        #pragma unroll
        for (int kk = 0; kk < 4; ++kk) {
            uint4 u = *(const uint4*)(kbase + (size_t)krow * PTOT + nb + kk * 32 + kseg * 8);
            unsigned short out[8];
            const unsigned short* us = (const unsigned short*)&u;
            #pragma unroll
            for (int e = 0; e < 8; ++e)
                out[e] = f2bs(__expf(us2f(us[e]) - rm) * ri);
            *(uint4*)&As[kk][krow * 32 + kseg * 8] = *(uint4*)out;
        }
        #pragma unroll
        for (int kk = 0; kk < 4; ++kk)
            gld16(vbase + (size_t)(wv * 16 + (lane >> 2)) * PTOT + nb + kk * 32 + (lane & 3) * 8,
                  &Bs[kk][wv * 512]);
        __syncthreads();
        #pragma unroll
        for (int kk = 0; kk < 4; ++kk) {
            bf16x8 bfr[2];
            #pragma unroll
            for (int j = 0; j < 2; ++j)
                bfr[j] = *(const bf16x8*)&Bs[kk][(wn * 32 + j * 16 + l16) * 32 + quad * 8];
            #pragma unroll
            for (int i = 0; i < 2; ++i) {
                bf16x8 af = *(const bf16x8*)&As[kk][(wm * 32 + i * 16 + l16) * 32 + quad * 8];
                #pragma unroll
                for (int j = 0; j < 2; ++j)
                    acc[i][j] = __builtin_amdgcn_mfma_f32_16x16x32_bf16(af, bfr[j], acc[i][j], 0, 0, 0);
            }
        }
        __syncthreads();
    }
    if (chunk == 0) {
        float mv[2][4];
        #pragma unroll
        for (int j = 0; j < 2; ++j) {
            int e = wn * 32 + j * 16 + l16;
            #pragma unroll
            for (int mm = 0; mm < 4; ++mm)
                mv[j][mm] = ldf(memkv, 2048 + ((h << 6) + e) * 4 + mm, bf);
        }
        #pragma unroll
        for (int i = 0; i < 2; ++i) {
            #pragma unroll
            for (int r = 0; r < 4; ++r) {
                int d = wm * 32 + i * 16 + quad * 4 + r;
                #pragma unroll
                for (int mm = 0; mm < 4; ++mm) {
                    float kw = __expf(ldf(memkv, ((h << 6) + d) * 4 + mm, bf) - rmS[d]) * riS[d];
                    #pragma unroll
                    for (int j = 0; j < 2; ++j)
                        acc[i][j][r] = fmaf(kw, mv[j][mm], acc[i][j][r]);
                }
            }
        }
    }
    float* outp = ctpart + (size_t)(chunk * 128 + bh) * 4096;
    #pragma unroll
    for (int i = 0; i < 2; ++i) {
        #pragma unroll
        for (int r = 0; r < 4; ++r) {
            int d = wm * 32 + i * 16 + quad * 4 + r;
            #pragma unroll
            for (int j = 0; j < 2; ++j) {
                int e = wn * 32 + j * 16 + l16;
                outp[d * 64 + e] = acc[i][j][r];
            }
        }
    }
}

// ---------------------------------------------------------------- sum ctpart chunks -> ct_bf [bh][e][d] bf16 (transposed)
__global__ __launch_bounds__(256) void k_ctsum(
        const float* __restrict__ ctpart, unsigned short* __restrict__ ct_bf)
{
    int bh = blockIdx.x, t = threadIdx.x;
    int i0 = t * 16;
    int e = i0 >> 6, d0 = i0 & 63;
    unsigned short tmp[16];
    #pragma unroll
    for (int j = 0; j < 16; ++j) {
        int d = d0 + j;
        float s = 0.f;
        #pragma unroll
        for (int c = 0; c < 4; ++c)
            s += ctpart[(size_t)(c * 128 + bh) * 4096 + d * 64 + e];
        tmp[j] = f2bs(s);
    }
    unsigned short* dst = ct_bf + (size_t)bh * 4096 + i0;
    *(uint4*)dst = ((uint4*)tmp)[0];
    *(uint4*)(dst + 8) = ((uint4*)tmp)[1];
}

// ---------------------------------------------------------------- rmsnorm(pre bf16) -> d_out [b][c][pos]
template<bool BF>
__device__ __forceinline__ void rmsout_body(const unsigned short* __restrict__ pre,
        const void* __restrict__ g, void* __restrict__ out, float* __restrict__ smem)
{
    float* gS   = smem;          // 256
    float* red2 = smem + 256;    // [16][64]
    float* sS   = smem + 1280;   // 64
    const int t = threadIdx.x;
    const int p0 = blockIdx.x * 64;
    const int b = p0 >> 12;
    const int posbase = p0 & 4095;
    gS[t] = ldf(g, t, BF);
    const int pl4 = (t & 15) * 4;
    const int crow = t >> 4;                 // 0..15
    const unsigned short* pbase = pre + p0 + pl4;
    ushort4 u[16];
    float ssq[4] = {0.f, 0.f, 0.f, 0.f};
    #pragma unroll
    for (int rr = 0; rr < 16; ++rr) {
        int c = rr * 16 + crow;
        u[rr] = *(const ushort4*)(pbase + (size_t)c * PTOT);
        float v0 = us2f(u[rr].x), v1 = us2f(u[rr].y), v2 = us2f(u[rr].z), v3 = us2f(u[rr].w);
        ssq[0] += v0 * v0; ssq[1] += v1 * v1; ssq[2] += v2 * v2; ssq[3] += v3 * v3;
    }
    #pragma unroll
    for (int e = 0; e < 4; ++e) red2[crow * 64 + pl4 + e] = ssq[e];
    __syncthreads();
    if (t < 64) {
        float tot = 0.f;
        #pragma unroll
        for (int j = 0; j < 16; ++j) tot += red2[j * 64 + t];
        sS[t] = 16.0f / fmaxf(sqrtf(tot), 1e-12f);
    }
    __syncthreads();
    const float s0 = sS[pl4], s1 = sS[pl4 + 1], s2 = sS[pl4 + 2], s3 = sS[pl4 + 3];
    #pragma unroll
    for (int rr = 0; rr < 16; ++rr) {
        int c = rr * 16 + crow;
        float gv = gS[c];
        float v0 = us2f(u[rr].x) * s0 * gv;
        float v1 = us2f(u[rr].y) * s1 * gv;
        float v2 = us2f(u[rr].z) * s2 * gv;
        float v3 = us2f(u[rr].w) * s3 * gv;
        size_t oi = ((size_t)(b * CIN + c) << 12) + posbase + pl4;
        if (BF) {
            ushort4 o;
            o.x = f2bs(v0); o.y = f2bs(v1); o.z = f2bs(v2); o.w = f2bs(v3);
            *(ushort4*)((unsigned short*)out + oi) = o;
        } else {
            float4 o; o.x = v0; o.y = v1; o.z = v2; o.w = v3;
            *(float4*)((float*)out + oi) = o;
        }
    }
}
__global__ __launch_bounds__(256) void k_rmsnorm_out(
        const unsigned short* __restrict__ pre, const void* __restrict__ g,
        void* __restrict__ out, const int* __restrict__ flag)
{
    __shared__ float smem[1344];
    if (flag[0]) rmsout_body<true>(pre, g, out, smem);
    else         rmsout_body<false>(pre, g, out, smem);
}

extern "C" void kernel_launch(void* const* d_in, const int* in_sizes, int n_in,
                              void* d_out, int out_size, void* d_ws, size_t ws_size,
                              hipStream_t stream) {
    const void* x     = d_in[0];
    const void* g_in  = d_in[1];
    const void* w_qkv = d_in[2];
    const void* memkv = d_in[3];
    const void* w_out = d_in[4];
    const void* b_out = d_in[5];
    const void* g_out = d_in[6];

    // ---- workspace: peak 128 MiB ----
    char* ws = (char*)d_ws;
    bf16*           kv     = (bf16*)ws;                        // [1024][65536] bf16: K 0..511, V 512..1023
    unsigned short* oat_pe = (unsigned short*)(ws + 67108864); // [65536][512] bf16, over dead V
    unsigned short* pre    = (unsigned short*)ws;              // [256][65536] bf16, over dead K
    int*            flagB  = (int*)(ws + 50331648);            // dead zone at relay time

    // ---- scratch in d_out (fp32 out = 67 MB; layout validated R3-R5) ----
    char* ob = (char*)d_out;
    float*          ctpart = (float*)ob;                        // 8 MiB  [4][128][64][64]
    float*          rowmax = (float*)(ob + 8388608);            // 32 KiB
    float*          rowinv = (float*)(ob + 8421376);            // 32 KiB
    int*            flagA  = (int*)(ob + 8454144);              // 4 B
    unsigned short* wq_b   = (unsigned short*)(ob + 9437184);   // 768 KiB
    unsigned short* wout_b = (unsigned short*)(ob + 10485760);  // 256 KiB
    unsigned short* ct_bf  = (unsigned short*)(ob + 11010048);  // 1 MiB [128][64 e][64 d]
    unsigned short* xn     = (unsigned short*)(ob + 12582912);  // [65536][256] bf16 = 32 MiB

    k_detect<<<1, 256, 0, stream>>>((const unsigned*)x, flagA);

    k_cvt<<<1536, 256, 0, stream>>>(w_qkv, wq_b, 1536 * 256, flagA);
    k_cvt<<<512, 256, 0, stream>>>(w_out, wout_b, 256 * 512, flagA);

    k_norm_xn<<<1024, 256, 0, stream>>>(x, g_in, xn, flagA);

    // K/V = w_qkv rows 512..1535: C[1024][PTOT], A-resident pipelined kernel
    k_kvgemm<<<256, 512, 0, stream>>>(
        (const bf16*)(wq_b + (size_t)512 * CIN), (const bf16*)xn, kv);

    k_kstats<<<8192, 256, 0, stream>>>(kv, memkv, rowmax, rowinv, flagA);

    dim3 gctx(128, 4);
    k_context_mfma<<<gctx, 256, 0, stream>>>(kv, memkv, rowmax, rowinv, ctpart, flagA);

    k_ctsum<<<128, 256, 0, stream>>>(ctpart, ct_bf);

    // fused: Q GEMM + in-reg q-softmax + ct apply -> oat_pe[p][512]
    k_qapply<<<256, 512, 0, stream>>>(
        (const bf16*)xn, (const bf16*)wq_b, ct_bf, oat_pe);

    // pre[256][PTOT] = w_out[256][512] · oat_pe[p][512]^T + b_out
    dim3 go(512, 2);
    k_mfma<HID, true, PTOT><<<go, 256, 0, stream>>>(
        (const bf16*)wout_b, (const bf16*)oat_pe, b_out, (bf16*)pre, flagA);

    k_relay<<<1, 1, 0, stream>>>(flagA, flagB);

    k_rmsnorm_out<<<1024, 256, 0, stream>>>(pre, g_out, d_out, flagB);
}

// Round 7
// 318.664 us; speedup vs baseline: 1.2898x; 1.0347x over previous
//
#include <hip/hip_runtime.h>
#include <hip/hip_bf16.h>

typedef __hip_bfloat16 bf16;
typedef short bf16x8 __attribute__((ext_vector_type(8)));
typedef float f32x4 __attribute__((ext_vector_type(4)));

#define PTOT  65536   // b * h * w = 16 * 4096
#define NPOS  4096    // h * w
#define CIN   256
#define HID   512
#define HD    64

__device__ __forceinline__ float us2f(unsigned short u) {
    return __uint_as_float(((unsigned int)u) << 16);
}
__device__ __forceinline__ float ldf(const void* p, size_t i, bool bf) {
    return bf ? us2f(((const unsigned short*)p)[i]) : ((const float*)p)[i];
}
__device__ __forceinline__ unsigned short f2bs(float v) {
    __hip_bfloat16 h = __float2bfloat16(v);
    return *reinterpret_cast<unsigned short*>(&h);
}
// async global->LDS, 16 B per lane; lds dest must be wave-uniform base
__device__ __forceinline__ void gld16(const void* g, void* s) {
    __builtin_amdgcn_global_load_lds(
        (const __attribute__((address_space(1))) unsigned int*)g,
        (__attribute__((address_space(3))) unsigned int*)s, 16, 0, 0);
}

// ---------------------------------------------------------------- dtype detector
__global__ __launch_bounds__(256) void k_detect(const unsigned* __restrict__ x,
                                                int* __restrict__ flag) {
    int t = threadIdx.x;
    unsigned w = x[(size_t)t * 997];
    unsigned e7 = (w >> 8) & 0x7f;
    __shared__ int s[256];
    s[t] = (e7 >= 58 && e7 <= 66) ? 1 : 0;
    __syncthreads();
    for (int k = 128; k > 0; k >>= 1) { if (t < k) s[t] += s[t + k]; __syncthreads(); }
    if (t == 0) flag[0] = (s[0] >= 128) ? 1 : 0;
}

__global__ void k_relay(const int* __restrict__ src, int* __restrict__ dst) {
    dst[0] = src[0];
}

// ---------------------------------------------------------------- elementwise convert -> bf16
__global__ __launch_bounds__(256) void k_cvt(const void* __restrict__ src,
        unsigned short* __restrict__ dst, int n, const int* __restrict__ flag) {
    bool bf = flag[0] != 0;
    int i = blockIdx.x * 256 + threadIdx.x;
    if (i < n) dst[i] = f2bs(ldf(src, i, bf));
}

// ---------------------------------------------------------------- rmsnorm(x) -> xn bf16 [p][c] (c contiguous)
template<bool BF>
__device__ __forceinline__ void norm_xn_body(const void* __restrict__ x,
        const void* __restrict__ g, unsigned short* __restrict__ xn,
        float* __restrict__ smem)
{
    float* xs   = smem;            // 4 * 4304 floats
    float* gS   = smem + 17216;    // 256
    float* red2 = smem + 17472;    // [16][64]
    float* sS   = smem + 18496;    // 64
    const int t = threadIdx.x;
    const int p0 = blockIdx.x * 64;
    const int b = p0 >> 12;
    const int posbase = p0 & 4095;
    gS[t] = ldf(g, t, BF);
    __syncthreads();
    const int pl4 = (t & 15) * 4;
    const int crow = t >> 4;                 // 0..15
    const size_t xbase = ((size_t)b * CIN) << 12;
    float ssq[4] = {0.f, 0.f, 0.f, 0.f};
    #pragma unroll
    for (int rr = 0; rr < 16; ++rr) {
        int c = rr * 16 + crow;
        float v[4];
        if (BF) {
            ushort4 u = *(const ushort4*)((const unsigned short*)x + xbase +
                                          ((size_t)c << 12) + posbase + pl4);
            v[0] = us2f(u.x); v[1] = us2f(u.y); v[2] = us2f(u.z); v[3] = us2f(u.w);
        } else {
            float4 f = *(const float4*)((const float*)x + xbase +
                                        ((size_t)c << 12) + posbase + pl4);
            v[0] = f.x; v[1] = f.y; v[2] = f.z; v[3] = f.w;
        }
        float gv = gS[c];
        float* row = xs + (c >> 6) * 4304 + (c & 63) * 67;
        #pragma unroll
        for (int e = 0; e < 4; ++e) {
            ssq[e] += v[e] * v[e];
            row[pl4 + e] = v[e] * gv;
        }
    }
    #pragma unroll
    for (int e = 0; e < 4; ++e) red2[crow * 64 + pl4 + e] = ssq[e];
    __syncthreads();
    if (t < 64) {
        float tot = 0.f;
        #pragma unroll
        for (int j = 0; j < 16; ++j) tot += red2[j * 64 + t];
        sS[t] = 16.0f / fmaxf(sqrtf(tot), 1e-12f);
    }
    __syncthreads();
    const int pr = t >> 2, c0 = (t & 3) * 64;
    const float sc = sS[pr];
    const float* base = xs + (t & 3) * 4304 + pr;
    unsigned short* dst = &xn[(size_t)(p0 + pr) * 256 + c0];
    #pragma unroll
    for (int q = 0; q < 4; ++q) {
        unsigned short tmp[16];
        #pragma unroll
        for (int j = 0; j < 16; ++j)
            tmp[j] = f2bs(base[(q * 16 + j) * 67] * sc);
        *(uint4*)(dst + q * 16)     = ((uint4*)tmp)[0];
        *(uint4*)(dst + q * 16 + 8) = ((uint4*)tmp)[1];
    }
}
__global__ __launch_bounds__(256) void k_norm_xn(
        const void* __restrict__ x, const void* __restrict__ g,
        unsigned short* __restrict__ xn, const int* __restrict__ flag)
{
    __shared__ float smem[18560];
    if (flag[0]) norm_xn_body<true>(x, g, xn, smem);
    else         norm_xn_body<false>(x, g, xn, smem);
}

// ---------------------------------------------------------------- MFMA GEMM: C[m][n] = Am[m][k] · Bm[n][k]^T
template<int KTOT, bool BIAS, int OSTRIDE>
__global__ __launch_bounds__(256) void k_mfma(
        const bf16* __restrict__ Am, const bf16* __restrict__ Bm,
        const void* __restrict__ bias, bf16* __restrict__ C,
        const int* __restrict__ flag)
{
    __shared__ __align__(16) unsigned short As[128 * 32];
    __shared__ __align__(16) unsigned short Bs[128 * 32];
    const int tid = threadIdx.x;
    const int wv = tid >> 6, lane = tid & 63;
    const int quad = lane >> 4, l16 = lane & 15;
    const int wm = wv >> 1, wn = wv & 1;
    const int m0 = blockIdx.y * 128, n0 = blockIdx.x * 128;
    f32x4 acc[4][4] = {};
    const bf16* gA = Am + (size_t)(m0 + (tid >> 2)) * KTOT + (tid & 3) * 8;
    const bf16* gB = Bm + (size_t)(n0 + (tid >> 2)) * KTOT + (tid & 3) * 8;
    unsigned short* lA = As + wv * 512;
    unsigned short* lB = Bs + wv * 512;
    for (int k0 = 0; k0 < KTOT; k0 += 32) {
        gld16(gA + k0, lA);
        gld16(gA + (size_t)64 * KTOT + k0, lA + 2048);
        gld16(gB + k0, lB);
        gld16(gB + (size_t)64 * KTOT + k0, lB + 2048);
        __syncthreads();
        bf16x8 bfr[4];
        #pragma unroll
        for (int j = 0; j < 4; ++j)
            bfr[j] = *(const bf16x8*)&Bs[(wn * 64 + j * 16 + l16) * 32 + quad * 8];
        #pragma unroll
        for (int i = 0; i < 4; ++i) {
            bf16x8 af = *(const bf16x8*)&As[(wm * 64 + i * 16 + l16) * 32 + quad * 8];
            #pragma unroll
            for (int j = 0; j < 4; ++j)
                acc[i][j] = __builtin_amdgcn_mfma_f32_16x16x32_bf16(af, bfr[j], acc[i][j], 0, 0, 0);
        }
        __syncthreads();
    }
    bool bf = BIAS ? (flag[0] != 0) : false;
    #pragma unroll
    for (int i = 0; i < 4; ++i) {
        int row = m0 + wm * 64 + i * 16 + quad * 4;
        #pragma unroll
        for (int r = 0; r < 4; ++r) {
            float bv = BIAS ? ldf(bias, row + r, bf) : 0.0f;
            #pragma unroll
            for (int j = 0; j < 4; ++j) {
                int col = n0 + wn * 64 + j * 16 + l16;
                C[(size_t)(row + r) * OSTRIDE + col] = __float2bfloat16(acc[i][j][r] + bv);
            }
        }
    }
}

// ---------------------------------------------------------------- KV GEMM v2: A-resident, LDS-recycled, 2 blocks/CU
// C[1024][PTOT] = Am[1024][256] · Bm[PTOT][256]^T.
// Phase 1: stage A (128ch x 256k = 64 KiB) -> hoist to af regs -> region dies.
// Phase 2: same 64 KiB becomes the B double-buffer (2 x 64pos x 256k x 2B).
// Block = 128 ch x 1024 pos (16 x 64-pos slices), counted vmcnt, 64 KiB LDS.
__global__ __launch_bounds__(512, 4) void k_kvgemm(
        const bf16* __restrict__ Am, const bf16* __restrict__ Bm,
        bf16* __restrict__ C)
{
    __shared__ __align__(16) char smem[65536];
    const int t = threadIdx.x;
    const int w = t >> 6, lane = t & 63;
    const int quad = lane >> 4, l16 = lane & 15;
    const int wm = w >> 1, wn = w & 1;               // 4 x 2 waves over 128m x 64n
    const int bid = blockIdx.x;
    const int c  = (bid & 7) | ((bid >> 6) << 3);    // chunk 0..63 (1024 pos), XCD-grouped
    const int mt = (bid >> 3) & 7;                   // m-tile 0..7
    const int m0 = mt * 128;
    const size_t cbase = (size_t)c * 1024;

    const int srow = t >> 5;                         // 0..15 per 16-row round
    const int sks  = (t & 31) ^ (srow & 7);          // pre-swizzled source slot

    // ---- phase 1: stage A into [0,64K), hoist, then region is recycled ----
    #pragma unroll
    for (int q = 0; q < 8; ++q)
        gld16(Am + (size_t)(m0 + q * 16 + srow) * 256 + sks * 8,
              smem + q * 8192 + w * 1024);
    asm volatile("s_waitcnt vmcnt(0)" ::: "memory");
    __builtin_amdgcn_s_barrier();
    asm volatile("" ::: "memory");

    bf16x8 af[2][8];
    #pragma unroll
    for (int i = 0; i < 2; ++i) {
        int row = wm * 32 + i * 16 + l16;
        #pragma unroll
        for (int kk = 0; kk < 8; ++kk)
            af[i][kk] = *(const bf16x8*)(smem + row * 512 +
                         (((kk * 4 + quad) ^ (row & 7)) << 4));
    }
    asm volatile("s_waitcnt lgkmcnt(0)" ::: "memory");
    __builtin_amdgcn_s_barrier();                    // all waves done reading A
    asm volatile("" ::: "memory");

    // ---- phase 2: B double-buffer in the recycled region ----
    #pragma unroll
    for (int q = 0; q < 4; ++q)
        gld16(Bm + (cbase + q * 16 + srow) * 256 + sks * 8,
              smem + q * 8192 + w * 1024);
    #pragma unroll
    for (int q = 0; q < 4; ++q)
        gld16(Bm + (cbase + 64 + q * 16 + srow) * 256 + sks * 8,
              smem + 32768 + q * 8192 + w * 1024);

    for (int s = 0; s < 16; ++s) {
        if (s > 0) {
            asm volatile("" ::: "memory");
            __builtin_amdgcn_s_barrier();            // prev compute done: buf free
            asm volatile("" ::: "memory");
            if (s + 1 < 16) {
                #pragma unroll
                for (int q = 0; q < 4; ++q)
                    gld16(Bm + (cbase + (size_t)(s + 1) * 64 + q * 16 + srow) * 256 + sks * 8,
                          smem + ((s + 1) & 1) * 32768 + q * 8192 + w * 1024);
            }
        }
        // counted waits: need B(s); newer in flight = B(s+1) gld (4) + stores (16)
        if (s == 0)      asm volatile("s_waitcnt vmcnt(4)"  ::: "memory");
        else if (s < 15) asm volatile("s_waitcnt vmcnt(20)" ::: "memory");
        else             asm volatile("s_waitcnt vmcnt(16)" ::: "memory");
        __builtin_amdgcn_s_barrier();
        asm volatile("" ::: "memory");

        const char* Bbuf = smem + (s & 1) * 32768;
        f32x4 acc[2][2] = {};
        #pragma unroll
        for (int kk = 0; kk < 8; ++kk) {
            bf16x8 bfr[2];
            #pragma unroll
            for (int j = 0; j < 2; ++j) {
                int row = wn * 32 + j * 16 + l16;
                bfr[j] = *(const bf16x8*)(Bbuf + row * 512 +
                          (((kk * 4 + quad) ^ (row & 7)) << 4));
            }
            #pragma unroll
            for (int i = 0; i < 2; ++i)
                #pragma unroll
                for (int j = 0; j < 2; ++j)
                    acc[i][j] = __builtin_amdgcn_mfma_f32_16x16x32_bf16(af[i][kk], bfr[j], acc[i][j], 0, 0, 0);
        }
        #pragma unroll
        for (int i = 0; i < 2; ++i) {
            #pragma unroll
            for (int r = 0; r < 4; ++r) {
                int row = m0 + wm * 32 + i * 16 + quad * 4 + r;
                size_t col = cbase + (size_t)s * 64 + wn * 32;
                #pragma unroll
                for (int j = 0; j < 2; ++j)
                    C[(size_t)row * PTOT + col + j * 16 + l16] = __float2bfloat16(acc[i][j][r]);
            }
        }
    }
}

// ---------------------------------------------------------------- fused Q GEMM + q-softmax + context apply (v4)
// Transposed GEMM1 (A=xn pos rows, B=wq ch rows) -> S[pos][ch]: softmax over ch is
// in-register (4 regs x 16 lanes, shfl_xor<16). qsm LDS transpose is wave-self-local
// (same wave writes & reads its 16pos x 64ch tile) -> NO intra-slice barriers.
// Block = 2 heads x 1024 pos, 16 x 64-pos slices, counted vmcnt (kvgemm discipline).
// LDS 160 KiB: wq[0,64K) qsm[64K,80K) ct[80K,96K) xn dbuf[96K,160K).
__global__ __launch_bounds__(512, 2) void k_qapply(
        const bf16* __restrict__ xn, const bf16* __restrict__ wq,
        const unsigned short* __restrict__ ct_bf,
        unsigned short* __restrict__ oat_pe)
{
    __shared__ __align__(16) char smem[163840];
    const int t = threadIdx.x;
    const int w = t >> 6, lane = t & 63;
    const int quad = lane >> 4, l16 = lane & 15;
    const int wm = w >> 1, wn = w & 1;              // 4 pos-blocks x 2 heads
    const int bid = blockIdx.x;
    const int hp = (bid >> 3) & 3;                  // head pair
    const int c  = (bid & 7) | ((bid >> 5) << 3);   // chunk 0..63 (1024 pos), XCD-grouped
    const int n0 = hp * 128;
    const size_t P0 = (size_t)c * 1024;
    const int b = c >> 2;
    const int srow = t >> 5, sks = (t & 31) ^ (srow & 7);

    // ---- prologue: ct(2) wq(8) B0(4) B1(4) ----
    #pragma unroll
    for (int k = 0; k < 2; ++k) {
        int u = k * 512 + t;
        int hh = u >> 9, rem = u & 511, e = rem >> 3, sl = rem & 7;
        gld16(ct_bf + (size_t)(b * 8 + hp * 2 + hh) * 4096 + e * 64 + ((sl ^ (e & 7)) * 8),
              smem + 81920 + k * 8192 + w * 1024);
    }
    #pragma unroll
    for (int q = 0; q < 8; ++q)
        gld16(wq + (size_t)(n0 + q * 16 + srow) * 256 + sks * 8,
              smem + q * 8192 + w * 1024);
    #pragma unroll
    for (int q = 0; q < 4; ++q)
        gld16(xn + (P0 + q * 16 + srow) * 256 + sks * 8,
              smem + 98304 + q * 8192 + w * 1024);
    #pragma unroll
    for (int q = 0; q < 4; ++q)
        gld16(xn + (P0 + 64 + q * 16 + srow) * 256 + sks * 8,
              smem + 131072 + q * 8192 + w * 1024);

    asm volatile("s_waitcnt vmcnt(8)" ::: "memory");   // ct + wq landed; B0,B1 in flight
    __builtin_amdgcn_s_barrier();
    asm volatile("" ::: "memory");

    // hoist wq fragments of own head (region never rewritten -> no barrier after)
    bf16x8 wqf[4][8];
    #pragma unroll
    for (int j = 0; j < 4; ++j) {
        int row = wn * 64 + j * 16 + l16;
        #pragma unroll
        for (int kk = 0; kk < 8; ++kk)
            wqf[j][kk] = *(const bf16x8*)(smem + row * 512 +
                          (((kk * 4 + quad) ^ (row & 7)) << 4));
    }

    unsigned short* qsm = (unsigned short*)(smem + 65536);   // [64][128] slot-XOR

    for (int s = 0; s < 16; ++s) {
        if (s > 0) {
            asm volatile("" ::: "memory");
            __builtin_amdgcn_s_barrier();            // all waves done with slice s-1
            asm volatile("" ::: "memory");
            if (s + 1 < 16) {
                #pragma unroll
                for (int q = 0; q < 4; ++q)
                    gld16(xn + (P0 + (size_t)(s + 1) * 64 + q * 16 + srow) * 256 + sks * 8,
                          smem + 98304 + ((s + 1) & 1) * 32768 + q * 8192 + w * 1024);
            }
        }
        // counted waits: need B(s); in flight = B(s+1)(4) + stores s-1 (16)
        if (s == 0)      asm volatile("s_waitcnt vmcnt(4)"  ::: "memory");
        else if (s < 15) asm volatile("s_waitcnt vmcnt(20)" ::: "memory");
        else             asm volatile("s_waitcnt vmcnt(16)" ::: "memory");
        __builtin_amdgcn_s_barrier();
        asm volatile("" ::: "memory");

        // ---- GEMM1 (transposed): S[16 pos (wm)][64 ch (head wn)] ----
        const char* Bbuf = smem + 98304 + (s & 1) * 32768;
        f32x4 acc[4] = {};
        #pragma unroll
        for (int kk = 0; kk < 8; ++kk) {
            int row = wm * 16 + l16;
            bf16x8 xf = *(const bf16x8*)(Bbuf + row * 512 +
                          (((kk * 4 + quad) ^ (row & 7)) << 4));
            #pragma unroll
            for (int j = 0; j < 4; ++j)
                acc[j] = __builtin_amdgcn_mfma_f32_16x16x32_bf16(xf, wqf[j][kk], acc[j], 0, 0, 0);
        }

        // ---- in-register softmax over ch (j regs x l16 lanes), 4 pos rows ----
        #pragma unroll
        for (int r = 0; r < 4; ++r) {
            float m = fmaxf(fmaxf(acc[0][r], acc[1][r]), fmaxf(acc[2][r], acc[3][r]));
            m = fmaxf(m, __shfl_xor(m, 1));
            m = fmaxf(m, __shfl_xor(m, 2));
            m = fmaxf(m, __shfl_xor(m, 4));
            m = fmaxf(m, __shfl_xor(m, 8));
            float ev[4], sum = 0.f;
            #pragma unroll
            for (int j = 0; j < 4; ++j) { ev[j] = __expf(acc[j][r] - m); sum += ev[j]; }
            sum += __shfl_xor(sum, 1);
            sum += __shfl_xor(sum, 2);
            sum += __shfl_xor(sum, 4);
            sum += __shfl_xor(sum, 8);
            float inv = 0.125f / sum;
            int pos = wm * 16 + quad * 4 + r;
            #pragma unroll
            for (int j = 0; j < 4; ++j) {
                int ch = wn * 64 + j * 16 + l16;
                qsm[pos * 128 + (((ch >> 3) ^ (pos & 7)) << 3) + (ch & 7)] = f2bs(ev[j] * inv);
            }
        }

        // ---- PV: out[16 pos][64 e]; qsm reads are wave-self-local (no barrier) ----
        f32x4 acc2[4] = {};
        #pragma unroll
        for (int kk = 0; kk < 2; ++kk) {
            int row = wm * 16 + l16;
            bf16x8 qf = *(const bf16x8*)(smem + 65536 + row * 256 +
                         (((wn * 8 + kk * 4 + quad) ^ (row & 7)) << 4));
            #pragma unroll
            for (int j = 0; j < 4; ++j) {
                int e = j * 16 + l16;
                bf16x8 cf = *(const bf16x8*)(smem + 81920 + wn * 8192 + e * 128 +
                             (((kk * 4 + quad) ^ (e & 7)) << 4));
                acc2[j] = __builtin_amdgcn_mfma_f32_16x16x32_bf16(qf, cf, acc2[j], 0, 0, 0);
            }
        }
        #pragma unroll
        for (int j = 0; j < 4; ++j)
            #pragma unroll
            for (int r = 0; r < 4; ++r) {
                size_t prow = P0 + (size_t)s * 64 + wm * 16 + quad * 4 + r;
                oat_pe[prow * HID + n0 + wn * 64 + j * 16 + l16] = f2bs(acc2[j][r]);
            }
    }
}

// ---------------------------------------------------------------- k row stats (max, 1/sumexp) over n=4100
__global__ __launch_bounds__(256) void k_kstats(
        const bf16* __restrict__ kv, const void* __restrict__ memkv,
        float* __restrict__ rowmax, float* __restrict__ rowinv,
        const int* __restrict__ flag)
{
    bool bf = flag[0] != 0;
    int r = blockIdx.x;                 // b*512 + h*64 + d
    int b = r >> 9, hd = r & 511;
    const unsigned short* krow = (const unsigned short*)kv + (size_t)hd * PTOT + b * NPOS;
    int t = threadIdx.x;
    float vals[16];
    float m = -1e30f;
    #pragma unroll
    for (int i = 0; i < 16; ++i) {
        vals[i] = us2f(krow[t + (i << 8)]);
        m = fmaxf(m, vals[i]);
    }
    float mv = (t < 4) ? ldf(memkv, hd * 4 + t, bf) : -1e30f;
    m = fmaxf(m, mv);
    __shared__ float red[256];
    red[t] = m; __syncthreads();
    for (int s = 128; s > 0; s >>= 1) {
        if (t < s) red[t] = fmaxf(red[t], red[t + s]);
        __syncthreads();
    }
    float M = red[0]; __syncthreads();
    float sum = 0.f;
    #pragma unroll
    for (int i = 0; i < 16; ++i) sum += __expf(vals[i] - M);
    if (t < 4) sum += __expf(mv - M);
    red[t] = sum; __syncthreads();
    for (int s = 128; s > 0; s >>= 1) {
        if (t < s) red[t] += red[t + s];
        __syncthreads();
    }
    if (t == 0) { rowmax[r] = M; rowinv[r] = 1.0f / red[0]; }
}

// ---------------------------------------------------------------- context via MFMA (validated R5)
__global__ __launch_bounds__(256) void k_context_mfma(
        const bf16* __restrict__ kv, const void* __restrict__ memkv,
        const float* __restrict__ rowmax, const float* __restrict__ rowinv,
        float* __restrict__ ctpart, const int* __restrict__ flag)
{
    bool bf = flag[0] != 0;
    int bh = blockIdx.x, chunk = blockIdx.y;
    int b = bh >> 3, h = bh & 7;
    __shared__ __align__(16) unsigned short As[4][64 * 32];
    __shared__ __align__(16) unsigned short Bs[4][64 * 32];
    __shared__ float rmS[64], riS[64];
    const int tid = threadIdx.x;
    if (tid < 64) {
        rmS[tid] = rowmax[(b << 9) + (h << 6) + tid];
        riS[tid] = rowinv[(b << 9) + (h << 6) + tid];
    }
    __syncthreads();
    const int wv = tid >> 6, lane = tid & 63;
    const int quad = lane >> 4, l16 = lane & 15;
    const int wm = wv >> 1, wn = wv & 1;
    const int krow = tid >> 2, kseg = tid & 3;
    const float rm = rmS[krow], ri = riS[krow];
    const unsigned short* kbase = (const unsigned short*)kv + (size_t)(h * HD) * PTOT + b * NPOS + chunk * 1024;
    const unsigned short* vbase = (const unsigned short*)kv + (size_t)(HID + h * HD) * PTOT + b * NPOS + chunk * 1024;
    f32x4 acc[2][2] = {};
    for (int s = 0; s < 8; ++s) {
        int nb = s * 128;
        #pragma unroll
        for (int kk = 0; kk < 4; ++kk) {
            uint4 u = *(const uint4*)(kbase + (size_t)krow * PTOT + nb + kk * 32 + kseg * 8);
            unsigned short out[8];
            const unsigned short* us = (const unsigned short*)&u;
            #pragma unroll
            for (int e = 0; e < 8; ++e)
                out[e] = f2bs(__expf(us2f(us[e]) - rm) * ri);
            *(uint4*)&As[kk][krow * 32 + kseg * 8] = *(uint4*)out;
        }
        #pragma unroll
        for (int kk = 0; kk < 4; ++kk)
            gld16(vbase + (size_t)(wv * 16 + (lane >> 2)) * PTOT + nb + kk * 32 + (lane & 3) * 8,
                  &Bs[kk][wv * 512]);
        __syncthreads();
        #pragma unroll
        for (int kk = 0; kk < 4; ++kk) {
            bf16x8 bfr[2];
            #pragma unroll
            for (int j = 0; j < 2; ++j)
                bfr[j] = *(const bf16x8*)&Bs[kk][(wn * 32 + j * 16 + l16) * 32 + quad * 8];
            #pragma unroll
            for (int i = 0; i < 2; ++i) {
                bf16x8 af = *(const bf16x8*)&As[kk][(wm * 32 + i * 16 + l16) * 32 + quad * 8];
                #pragma unroll
                for (int j = 0; j < 2; ++j)
                    acc[i][j] = __builtin_amdgcn_mfma_f32_16x16x32_bf16(af, bfr[j], acc[i][j], 0, 0, 0);
            }
        }
        __syncthreads();
    }
    if (chunk == 0) {
        float mv[2][4];
        #pragma unroll
        for (int j = 0; j < 2; ++j) {
            int e = wn * 32 + j * 16 + l16;
            #pragma unroll
            for (int mm = 0; mm < 4; ++mm)
                mv[j][mm] = ldf(memkv, 2048 + ((h << 6) + e) * 4 + mm, bf);
        }
        #pragma unroll
        for (int i = 0; i < 2; ++i) {
            #pragma unroll
            for (int r = 0; r < 4; ++r) {
                int d = wm * 32 + i * 16 + quad * 4 + r;
                #pragma unroll
                for (int mm = 0; mm < 4; ++mm) {
                    float kw = __expf(ldf(memkv, ((h << 6) + d) * 4 + mm, bf) - rmS[d]) * riS[d];
                    #pragma unroll
                    for (int j = 0; j < 2; ++j)
                        acc[i][j][r] = fmaf(kw, mv[j][mm], acc[i][j][r]);
                }
            }
        }
    }
    float* outp = ctpart + (size_t)(chunk * 128 + bh) * 4096;
    #pragma unroll
    for (int i = 0; i < 2; ++i) {
        #pragma unroll
        for (int r = 0; r < 4; ++r) {
            int d = wm * 32 + i * 16 + quad * 4 + r;
            #pragma unroll
            for (int j = 0; j < 2; ++j) {
                int e = wn * 32 + j * 16 + l16;
                outp[d * 64 + e] = acc[i][j][r];
            }
        }
    }
}

// ---------------------------------------------------------------- sum ctpart chunks -> ct_bf [bh][e][d] bf16 (transposed)
__global__ __launch_bounds__(256) void k_ctsum(
        const float* __restrict__ ctpart, unsigned short* __restrict__ ct_bf)
{
    int bh = blockIdx.x, t = threadIdx.x;
    int i0 = t * 16;
    int e = i0 >> 6, d0 = i0 & 63;
    unsigned short tmp[16];
    #pragma unroll
    for (int j = 0; j < 16; ++j) {
        int d = d0 + j;
        float s = 0.f;
        #pragma unroll
        for (int c = 0; c < 4; ++c)
            s += ctpart[(size_t)(c * 128 + bh) * 4096 + d * 64 + e];
        tmp[j] = f2bs(s);
    }
    unsigned short* dst = ct_bf + (size_t)bh * 4096 + i0;
    *(uint4*)dst = ((uint4*)tmp)[0];
    *(uint4*)(dst + 8) = ((uint4*)tmp)[1];
}

// ---------------------------------------------------------------- rmsnorm(pre bf16) -> d_out [b][c][pos]
template<bool BF>
__device__ __forceinline__ void rmsout_body(const unsigned short* __restrict__ pre,
        const void* __restrict__ g, void* __restrict__ out, float* __restrict__ smem)
{
    float* gS   = smem;          // 256
    float* red2 = smem + 256;    // [16][64]
    float* sS   = smem + 1280;   // 64
    const int t = threadIdx.x;
    const int p0 = blockIdx.x * 64;
    const int b = p0 >> 12;
    const int posbase = p0 & 4095;
    gS[t] = ldf(g, t, BF);
    const int pl4 = (t & 15) * 4;
    const int crow = t >> 4;                 // 0..15
    const unsigned short* pbase = pre + p0 + pl4;
    ushort4 u[16];
    float ssq[4] = {0.f, 0.f, 0.f, 0.f};
    #pragma unroll
    for (int rr = 0; rr < 16; ++rr) {
        int c = rr * 16 + crow;
        u[rr] = *(const ushort4*)(pbase + (size_t)c * PTOT);
        float v0 = us2f(u[rr].x), v1 = us2f(u[rr].y), v2 = us2f(u[rr].z), v3 = us2f(u[rr].w);
        ssq[0] += v0 * v0; ssq[1] += v1 * v1; ssq[2] += v2 * v2; ssq[3] += v3 * v3;
    }
    #pragma unroll
    for (int e = 0; e < 4; ++e) red2[crow * 64 + pl4 + e] = ssq[e];
    __syncthreads();
    if (t < 64) {
        float tot = 0.f;
        #pragma unroll
        for (int j = 0; j < 16; ++j) tot += red2[j * 64 + t];
        sS[t] = 16.0f / fmaxf(sqrtf(tot), 1e-12f);
    }
    __syncthreads();
    const float s0 = sS[pl4], s1 = sS[pl4 + 1], s2 = sS[pl4 + 2], s3 = sS[pl4 + 3];
    #pragma unroll
    for (int rr = 0; rr < 16; ++rr) {
        int c = rr * 16 + crow;
        float gv = gS[c];
        float v0 = us2f(u[rr].x) * s0 * gv;
        float v1 = us2f(u[rr].y) * s1 * gv;
        float v2 = us2f(u[rr].z) * s2 * gv;
        float v3 = us2f(u[rr].w) * s3 * gv;
        size_t oi = ((size_t)(b * CIN + c) << 12) + posbase + pl4;
        if (BF) {
            ushort4 o;
            o.x = f2bs(v0); o.y = f2bs(v1); o.z = f2bs(v2); o.w = f2bs(v3);
            *(ushort4*)((unsigned short*)out + oi) = o;
        } else {
            float4 o; o.x = v0; o.y = v1; o.z = v2; o.w = v3;
            *(float4*)((float*)out + oi) = o;
        }
    }
}
__global__ __launch_bounds__(256) void k_rmsnorm_out(
        const unsigned short* __restrict__ pre, const void* __restrict__ g,
        void* __restrict__ out, const int* __restrict__ flag)
{
    __shared__ float smem[1344];
    if (flag[0]) rmsout_body<true>(pre, g, out, smem);
    else         rmsout_body<false>(pre, g, out, smem);
}

extern "C" void kernel_launch(void* const* d_in, const int* in_sizes, int n_in,
                              void* d_out, int out_size, void* d_ws, size_t ws_size,
                              hipStream_t stream) {
    const void* x     = d_in[0];
    const void* g_in  = d_in[1];
    const void* w_qkv = d_in[2];
    const void* memkv = d_in[3];
    const void* w_out = d_in[4];
    const void* b_out = d_in[5];
    const void* g_out = d_in[6];

    // ---- workspace: peak 128 MiB ----
    char* ws = (char*)d_ws;
    bf16*           kv     = (bf16*)ws;                        // [1024][65536] bf16: K 0..511, V 512..1023
    unsigned short* oat_pe = (unsigned short*)(ws + 67108864); // [65536][512] bf16, over dead V
    unsigned short* pre    = (unsigned short*)ws;              // [256][65536] bf16, over dead K
    int*            flagB  = (int*)(ws + 50331648);            // dead zone at relay time

    // ---- scratch in d_out (fp32 out = 67 MB; layout validated R3-R5) ----
    char* ob = (char*)d_out;
    float*          ctpart = (float*)ob;                        // 8 MiB  [4][128][64][64]
    float*          rowmax = (float*)(ob + 8388608);            // 32 KiB
    float*          rowinv = (float*)(ob + 8421376);            // 32 KiB
    int*            flagA  = (int*)(ob + 8454144);              // 4 B
    unsigned short* wq_b   = (unsigned short*)(ob + 9437184);   // 768 KiB
    unsigned short* wout_b = (unsigned short*)(ob + 10485760);  // 256 KiB
    unsigned short* ct_bf  = (unsigned short*)(ob + 11010048);  // 1 MiB [128][64 e][64 d]
    unsigned short* xn     = (unsigned short*)(ob + 12582912);  // [65536][256] bf16 = 32 MiB

    k_detect<<<1, 256, 0, stream>>>((const unsigned*)x, flagA);

    k_cvt<<<1536, 256, 0, stream>>>(w_qkv, wq_b, 1536 * 256, flagA);
    k_cvt<<<512, 256, 0, stream>>>(w_out, wout_b, 256 * 512, flagA);

    k_norm_xn<<<1024, 256, 0, stream>>>(x, g_in, xn, flagA);

    // K/V = w_qkv rows 512..1535: C[1024][PTOT], LDS-recycled 2-blocks/CU kernel
    k_kvgemm<<<512, 512, 0, stream>>>(
        (const bf16*)(wq_b + (size_t)512 * CIN), (const bf16*)xn, kv);

    k_kstats<<<8192, 256, 0, stream>>>(kv, memkv, rowmax, rowinv, flagA);

    dim3 gctx(128, 4);
    k_context_mfma<<<gctx, 256, 0, stream>>>(kv, memkv, rowmax, rowinv, ctpart, flagA);

    k_ctsum<<<128, 256, 0, stream>>>(ctpart, ct_bf);

    // fused: Q GEMM + in-reg q-softmax + ct apply -> oat_pe[p][512]
    k_qapply<<<256, 512, 0, stream>>>(
        (const bf16*)xn, (const bf16*)wq_b, ct_bf, oat_pe);

    // pre[256][PTOT] = w_out[256][512] · oat_pe[p][512]^T + b_out
    dim3 go(512, 2);
    k_mfma<HID, true, PTOT><<<go, 256, 0, stream>>>(
        (const bf16*)wout_b, (const bf16*)oat_pe, b_out, (bf16*)pre, flagA);

    k_relay<<<1, 1, 0, stream>>>(flagA, flagB);

    k_rmsnorm_out<<<1024, 256, 0, stream>>>(pre, g_out, d_out, flagB);
}